// Round 1
// baseline (4700.141 us; speedup 1.0000x reference)
//
#include <hip/hip_runtime.h>
#include <cmath>

#define DEVINL __device__ __forceinline__

constexpr int Bb   = 2;
constexpr int Ss   = 2048;
constexpr int S1   = 2049;
constexpr int DIN  = 1024;
constexpr int Dd   = 512;
constexpr int Hh   = 8;
constexpr int FF   = 2048;
constexpr int Ee   = 6;
constexpr int NCc  = 2;
constexpr int CAP  = 341;
constexpr int NTOK = Bb * Ss;     // 4096
constexpr int RR   = Bb * S1;     // 4098
constexpr int MOE_ROWS = Bb * CAP; // 682

DEVINL float geluf(float x) { return 0.5f * x * (1.0f + erff(x * 0.7071067811865476f)); }

DEVINL float wsum(float v) {
#pragma unroll
  for (int off = 32; off; off >>= 1) v += __shfl_xor(v, off);
  return v;
}
DEVINL float wmax(float v) {
#pragma unroll
  for (int off = 32; off; off >>= 1) v = fmaxf(v, __shfl_xor(v, off));
  return v;
}
// block=256 reduction, broadcast result to all threads
DEVINL float bsum(float v, float* red) {
  v = wsum(v);
  int w = threadIdx.x >> 6;
  if ((threadIdx.x & 63) == 0) red[w] = v;
  __syncthreads();
  float r = red[0] + red[1] + red[2] + red[3];
  __syncthreads();
  return r;
}

// ---------------- labels: cosine-sim argmax over 4 protos -------------------
__global__ __launch_bounds__(256) void labels_kernel(const float* __restrict__ x,
                                                     const float* __restrict__ protos,
                                                     int* __restrict__ lbl) {
  int t = blockIdx.x * 4 + (threadIdx.x >> 6);
  int lane = threadIdx.x & 63;
  if (t >= NTOK) return;
  const float* xr = x + (size_t)t * DIN;
  float xv[16];
  float ss = 0.f;
#pragma unroll
  for (int i = 0; i < 16; ++i) { xv[i] = xr[lane + 64 * i]; ss += xv[i] * xv[i]; }
  ss = wsum(ss);
  float nx = sqrtf(ss) + 1e-8f;
  float best = -2e30f; int bi = 0;
  for (int p = 0; p < 4; ++p) {
    const float* pr = protos + (size_t)p * DIN;
    float dp = 0.f, pp = 0.f;
#pragma unroll
    for (int i = 0; i < 16; ++i) { float v = pr[lane + 64 * i]; dp += v * xv[i]; pp += v * v; }
    dp = wsum(dp); pp = wsum(pp);
    float sim = dp / (nx * (sqrtf(pp) + 1e-8f));
    if (sim > best) { best = sim; bi = p; }
  }
  if (lane == 0) lbl[t] = bi;
}

// ---------------- generic tiled fp32 GEMM ----------------------------------
// C(MxN) = act(A(MxK) @ B + bias) + res ; B is KxN (TRANSB=0) or NxK (TRANSB=1)
template <bool TRANSB, bool ACT>
__global__ __launch_bounds__(256) void gemm_kernel(const float* __restrict__ A, int lda,
                                                   const float* __restrict__ Bw, int ldb,
                                                   const float* __restrict__ bias,
                                                   const float* __restrict__ res,
                                                   float* __restrict__ C, int ldc,
                                                   int M, int N, int K) {
  __shared__ float As[16][68];
  __shared__ float Bs[16][68];
  const int tid = threadIdx.x;
  const int bm = blockIdx.x * 64, bn = blockIdx.y * 64;
  const int ty = tid >> 4, tx = tid & 15;
  const int arow = tid >> 2, a4 = (tid & 3) << 2;
  float acc[4][4] = {};
  for (int k0 = 0; k0 < K; k0 += 16) {
    float4 av = make_float4(0.f, 0.f, 0.f, 0.f);
    if (bm + arow < M) av = *(const float4*)(A + (size_t)(bm + arow) * lda + k0 + a4);
    As[a4 + 0][arow] = av.x; As[a4 + 1][arow] = av.y;
    As[a4 + 2][arow] = av.z; As[a4 + 3][arow] = av.w;
    if (!TRANSB) {
      const int brow = tid >> 4, b4 = (tid & 15) << 2;
      float4 bv = *(const float4*)(Bw + (size_t)(k0 + brow) * ldb + bn + b4);
      Bs[brow][b4 + 0] = bv.x; Bs[brow][b4 + 1] = bv.y;
      Bs[brow][b4 + 2] = bv.z; Bs[brow][b4 + 3] = bv.w;
    } else {
      const int nrow = tid >> 2, b4 = (tid & 3) << 2;
      float4 bv = *(const float4*)(Bw + (size_t)(bn + nrow) * ldb + k0 + b4);
      Bs[b4 + 0][nrow] = bv.x; Bs[b4 + 1][nrow] = bv.y;
      Bs[b4 + 2][nrow] = bv.z; Bs[b4 + 3][nrow] = bv.w;
    }
    __syncthreads();
#pragma unroll
    for (int kk = 0; kk < 16; ++kk) {
      float ar[4], br[4];
#pragma unroll
      for (int i = 0; i < 4; ++i) ar[i] = As[kk][ty * 4 + i];
#pragma unroll
      for (int j = 0; j < 4; ++j) br[j] = Bs[kk][tx * 4 + j];
#pragma unroll
      for (int i = 0; i < 4; ++i)
#pragma unroll
        for (int j = 0; j < 4; ++j) acc[i][j] += ar[i] * br[j];
    }
    __syncthreads();
  }
#pragma unroll
  for (int i = 0; i < 4; ++i) {
    int row = bm + ty * 4 + i;
    if (row < M) {
      size_t base = (size_t)row * ldc + bn + tx * 4;
      float v[4];
#pragma unroll
      for (int j = 0; j < 4; ++j) {
        float t = acc[i][j];
        if (bias) t += bias[bn + tx * 4 + j];
        if (ACT) t = geluf(t);
        if (res) t += res[base + j];
        v[j] = t;
      }
      *(float4*)(C + base) = make_float4(v[0], v[1], v[2], v[3]);
    }
  }
}

// ---------------- assemble h = concat(cls, fc1_out) -------------------------
__global__ __launch_bounds__(256) void assemble_kernel(const float* __restrict__ fc1out,
                                                       const float* __restrict__ cls,
                                                       float* __restrict__ h) {
  size_t i = (size_t)blockIdx.x * 256 + threadIdx.x;
  if (i >= (size_t)RR * Dd) return;
  int r = (int)(i >> 9), d = (int)(i & 511);
  int b = r / S1, sl = r - b * S1;
  float v = (sl == 0) ? cls[d] : fc1out[((size_t)(b * Ss + sl - 1) << 9) + d];
  h[i] = v;
}

__global__ __launch_bounds__(256) void copy_kernel(const float* __restrict__ src,
                                                   float* __restrict__ dst) {
  size_t i = (size_t)blockIdx.x * 256 + threadIdx.x;
  if (i < (size_t)RR * Dd) dst[i] = src[i];
}

// ---------------- LayerNorm (optionally + add) ------------------------------
template <int NPT>
__global__ __launch_bounds__(256) void ln_kernel(const float* __restrict__ in,
                                                 const float* __restrict__ addv,
                                                 const float* __restrict__ g,
                                                 const float* __restrict__ bvec,
                                                 float* __restrict__ out) {
  constexpr int N = NPT * 256;
  __shared__ float red[8];
  size_t base = (size_t)blockIdx.x * N;
  int tid = threadIdx.x;
  float x[NPT];
  float s1 = 0.f, s2 = 0.f;
#pragma unroll
  for (int j = 0; j < NPT; ++j) {
    x[j] = in[base + tid + j * 256];
    s1 += x[j]; s2 += x[j] * x[j];
  }
  s1 = bsum(s1, red);
  s2 = bsum(s2, red);
  float mean = s1 * (1.0f / N);
  float var = s2 * (1.0f / N) - mean * mean;
  float rstd = rsqrtf(var + 1e-5f);
#pragma unroll
  for (int j = 0; j < NPT; ++j) {
    int col = tid + j * 256;
    float v = (x[j] - mean) * rstd * g[col] + bvec[col];
    if (addv) v += addv[base + col];
    out[base + col] = v;
  }
}

// ---------------- flash attention (fp32), 1 wave per (b,h,q) ----------------
__global__ __launch_bounds__(256) void attn_kernel(const float* __restrict__ qkv,
                                                   float* __restrict__ o) {
  __shared__ float Ksh[64][65];
  __shared__ float Vsh[64][65];
  __shared__ float qsh[4][64];
  const int tid = threadIdx.x;
  const int w = tid >> 6, lane = tid & 63;
  const int hh = blockIdx.y, b = blockIdx.z;
  const int q = blockIdx.x * 4 + w;
  const size_t rbase = (size_t)b * S1 * (3 * Dd);
  {
    int rs = tid >> 6, dq = tid & 63;
    int qr = blockIdx.x * 4 + rs;
    qsh[rs][dq] = (qr < S1) ? qkv[rbase + (size_t)qr * (3 * Dd) + hh * 64 + dq] : 0.f;
  }
  __syncthreads();
  float qreg[64];
#pragma unroll
  for (int d = 0; d < 64; ++d) qreg[d] = qsh[w][d];

  float m = -1e30f, l = 0.f;
  float oa[64];
#pragma unroll
  for (int d = 0; d < 64; ++d) oa[d] = 0.f;

  const int kr = tid >> 2, d0 = (tid & 3) << 4;
  for (int c = 0; c < 33; ++c) {
    int key = c * 64 + kr;
    bool kvalid = key < S1;
    const float* kp = qkv + rbase + (size_t)key * (3 * Dd) + Dd + hh * 64 + d0;
#pragma unroll
    for (int j = 0; j < 4; ++j) {
      float4 k4 = kvalid ? *(const float4*)(kp + j * 4) : make_float4(0.f, 0.f, 0.f, 0.f);
      float4 v4 = kvalid ? *(const float4*)(kp + Dd + j * 4) : make_float4(0.f, 0.f, 0.f, 0.f);
      Ksh[kr][d0 + j * 4 + 0] = k4.x; Ksh[kr][d0 + j * 4 + 1] = k4.y;
      Ksh[kr][d0 + j * 4 + 2] = k4.z; Ksh[kr][d0 + j * 4 + 3] = k4.w;
      Vsh[kr][d0 + j * 4 + 0] = v4.x; Vsh[kr][d0 + j * 4 + 1] = v4.y;
      Vsh[kr][d0 + j * 4 + 2] = v4.z; Vsh[kr][d0 + j * 4 + 3] = v4.w;
    }
    __syncthreads();
    if (q < S1) {
      int key2 = c * 64 + lane;
      float s0 = 0.f, s1 = 0.f, s2 = 0.f, s3 = 0.f;
#pragma unroll
      for (int d = 0; d < 64; d += 4) {
        s0 += qreg[d + 0] * Ksh[lane][d + 0];
        s1 += qreg[d + 1] * Ksh[lane][d + 1];
        s2 += qreg[d + 2] * Ksh[lane][d + 2];
        s3 += qreg[d + 3] * Ksh[lane][d + 3];
      }
      float sv = ((s0 + s1) + (s2 + s3)) * 0.125f;
      if (key2 >= S1) sv = -1e30f;
      float mn = fmaxf(m, sv);
      float fac = __expf(m - mn);
      float p = __expf(sv - mn);
      l = l * fac + p;
#pragma unroll
      for (int d = 0; d < 64; ++d) oa[d] = oa[d] * fac + p * Vsh[lane][d];
      m = mn;
    }
    __syncthreads();
  }
  if (q < S1) {
    float M = wmax(m);
    float sc = __expf(m - M);
    float L = wsum(l * sc);
    float inv = 1.0f / L;
#pragma unroll
    for (int d = 0; d < 64; ++d) oa[d] *= sc;
    float outv = 0.f;
#pragma unroll
    for (int d = 0; d < 64; ++d) {
      float v = wsum(oa[d]);
      if (lane == d) outv = v;
    }
    o[(size_t)(b * S1 + q) * Dd + hh * 64 + lane] = outv * inv;
  }
}

// ---------------- gate softmax + top1 routing info --------------------------
__global__ __launch_bounds__(256) void gate_kernel(const float* __restrict__ h2,
                                                   const float* __restrict__ gw,
                                                   float* __restrict__ gate_out,
                                                   float* __restrict__ topp,
                                                   int* __restrict__ idx) {
  int t = blockIdx.x * 4 + (threadIdx.x >> 6);
  int lane = threadIdx.x & 63;
  if (t >= NTOK) return;
  int b = t >> 11, s = t & (Ss - 1);
  const float* hr = h2 + (size_t)(b * S1 + s + 1) * Dd;
  float acc[6] = {};
#pragma unroll
  for (int i = 0; i < 8; ++i) {
    int d = lane + i * 64;
    float xv = hr[d];
    const float* g = gw + (size_t)d * Ee;
#pragma unroll
    for (int e = 0; e < 6; ++e) acc[e] += xv * g[e];
  }
#pragma unroll
  for (int e = 0; e < 6; ++e) acc[e] = wsum(acc[e]);
  if (lane == 0) {
    float mx = acc[0];
#pragma unroll
    for (int e = 1; e < 6; ++e) mx = fmaxf(mx, acc[e]);
    float ex[6], sum = 0.f;
#pragma unroll
    for (int e = 0; e < 6; ++e) { ex[e] = __expf(acc[e] - mx); sum += ex[e]; }
    float invs = 1.0f / sum;
    int best = 0; float bp = ex[0];
#pragma unroll
    for (int e = 1; e < 6; ++e) { if (ex[e] > bp) { bp = ex[e]; best = e; } }
#pragma unroll
    for (int e = 0; e < 6; ++e) gate_out[(size_t)t * Ee + e] = ex[e] * invs;
    topp[t] = bp * invs;
    idx[t] = best;
  }
}

// ---------------- capacity-limited top-1 router (serial per batch) ----------
__global__ void route_kernel(const int* __restrict__ idx, int* __restrict__ list,
                             int* __restrict__ cnt) {
  int b = threadIdx.x;
  if (b >= Bb) return;
  int c[Ee];
#pragma unroll
  for (int e = 0; e < Ee; ++e) c[e] = 0;
  for (int s = 0; s < Ss; ++s) {
    int t = b * Ss + s;
    int e = idx[t];
    if (c[e] < CAP) list[e * MOE_ROWS + b * CAP + c[e]] = t;
    c[e]++;
  }
#pragma unroll
  for (int e = 0; e < Ee; ++e) cnt[e * Bb + b] = (c[e] < CAP) ? c[e] : CAP;
}

// ---------------- MoE expert FFN (gathered GEMMs) ---------------------------
__global__ __launch_bounds__(256) void moe_ffn1_kernel(const float* __restrict__ h2,
                                                       const float* __restrict__ w1all,
                                                       const float* __restrict__ b1all,
                                                       const int* __restrict__ list,
                                                       const int* __restrict__ cnt,
                                                       float* __restrict__ hid) {
  __shared__ float As[16][68];
  __shared__ float Bs[16][68];
  const int e = blockIdx.z;
  const int c0 = cnt[e * 2 + 0], c1 = cnt[e * 2 + 1];
  const int tid = threadIdx.x;
  const int bm = blockIdx.x * 64, bn = blockIdx.y * 64;
  const int ty = tid >> 4, tx = tid & 15;
  const float* w1 = w1all + (size_t)e * Dd * FF;
  const int arow = tid >> 2, a4 = (tid & 3) << 2;
  int r = bm + arow;
  bool aval = (r < CAP) ? (r < c0) : ((r - CAP) < c1);
  size_t abase = 0;
  if (aval) {
    int tok = list[e * MOE_ROWS + r];
    int b = tok >> 11, s = tok & (Ss - 1);
    abase = (size_t)(b * S1 + s + 1) * Dd;
  }
  float acc[4][4] = {};
  for (int k0 = 0; k0 < Dd; k0 += 16) {
    float4 av = make_float4(0.f, 0.f, 0.f, 0.f);
    if (aval) av = *(const float4*)(h2 + abase + k0 + a4);
    As[a4 + 0][arow] = av.x; As[a4 + 1][arow] = av.y;
    As[a4 + 2][arow] = av.z; As[a4 + 3][arow] = av.w;
    {
      const int brow = tid >> 4, b4 = (tid & 15) << 2;
      float4 bv = *(const float4*)(w1 + (size_t)(k0 + brow) * FF + bn + b4);
      Bs[brow][b4 + 0] = bv.x; Bs[brow][b4 + 1] = bv.y;
      Bs[brow][b4 + 2] = bv.z; Bs[brow][b4 + 3] = bv.w;
    }
    __syncthreads();
#pragma unroll
    for (int kk = 0; kk < 16; ++kk) {
      float ar[4], br[4];
#pragma unroll
      for (int i = 0; i < 4; ++i) ar[i] = As[kk][ty * 4 + i];
#pragma unroll
      for (int j = 0; j < 4; ++j) br[j] = Bs[kk][tx * 4 + j];
#pragma unroll
      for (int i = 0; i < 4; ++i)
#pragma unroll
        for (int j = 0; j < 4; ++j) acc[i][j] += ar[i] * br[j];
    }
    __syncthreads();
  }
#pragma unroll
  for (int i = 0; i < 4; ++i) {
    int r2 = bm + ty * 4 + i;
    bool v2 = (r2 < CAP) ? (r2 < c0) : ((r2 - CAP) < c1);
    if (v2) {
      size_t base = ((size_t)e * MOE_ROWS + r2) * FF + bn + tx * 4;
      float v[4];
#pragma unroll
      for (int j = 0; j < 4; ++j) v[j] = geluf(acc[i][j] + b1all[e * FF + bn + tx * 4 + j]);
      *(float4*)(hid + base) = make_float4(v[0], v[1], v[2], v[3]);
    }
  }
}

__global__ __launch_bounds__(256) void moe_ffn2_kernel(const float* __restrict__ hid,
                                                       const float* __restrict__ w2all,
                                                       const float* __restrict__ b2all,
                                                       const int* __restrict__ list,
                                                       const int* __restrict__ cnt,
                                                       const float* __restrict__ topp,
                                                       float* __restrict__ out) {
  __shared__ float As[16][68];
  __shared__ float Bs[16][68];
  const int e = blockIdx.z;
  const int c0 = cnt[e * 2 + 0], c1 = cnt[e * 2 + 1];
  const int tid = threadIdx.x;
  const int bm = blockIdx.x * 64, bn = blockIdx.y * 64;
  const int ty = tid >> 4, tx = tid & 15;
  const float* w2 = w2all + (size_t)e * FF * Dd;
  const int arow = tid >> 2, a4 = (tid & 3) << 2;
  int r = bm + arow;
  bool aval = (r < CAP) ? (r < c0) : ((r - CAP) < c1);
  size_t abase = ((size_t)e * MOE_ROWS + r) * FF;
  float acc[4][4] = {};
  for (int k0 = 0; k0 < FF; k0 += 16) {
    float4 av = make_float4(0.f, 0.f, 0.f, 0.f);
    if (aval) av = *(const float4*)(hid + abase + k0 + a4);
    As[a4 + 0][arow] = av.x; As[a4 + 1][arow] = av.y;
    As[a4 + 2][arow] = av.z; As[a4 + 3][arow] = av.w;
    {
      const int brow = tid >> 4, b4 = (tid & 15) << 2;
      float4 bv = *(const float4*)(w2 + (size_t)(k0 + brow) * Dd + bn + b4);
      Bs[brow][b4 + 0] = bv.x; Bs[brow][b4 + 1] = bv.y;
      Bs[brow][b4 + 2] = bv.z; Bs[brow][b4 + 3] = bv.w;
    }
    __syncthreads();
#pragma unroll
    for (int kk = 0; kk < 16; ++kk) {
      float ar[4], br[4];
#pragma unroll
      for (int i = 0; i < 4; ++i) ar[i] = As[kk][ty * 4 + i];
#pragma unroll
      for (int j = 0; j < 4; ++j) br[j] = Bs[kk][tx * 4 + j];
#pragma unroll
      for (int i = 0; i < 4; ++i)
#pragma unroll
        for (int j = 0; j < 4; ++j) acc[i][j] += ar[i] * br[j];
    }
    __syncthreads();
  }
#pragma unroll
  for (int i = 0; i < 4; ++i) {
    int r2 = bm + ty * 4 + i;
    bool v2 = (r2 < CAP) ? (r2 < c0) : ((r2 - CAP) < c1);
    if (v2) {
      int tok = list[e * MOE_ROWS + r2];
      int b = tok >> 11, s = tok & (Ss - 1);
      float tp = topp[tok];
      size_t obase = (size_t)(b * S1 + s + 1) * Dd + bn + tx * 4;
      float4 cur = *(const float4*)(out + obase);
      cur.x += tp * (acc[i][0] + b2all[e * Dd + bn + tx * 4 + 0]);
      cur.y += tp * (acc[i][1] + b2all[e * Dd + bn + tx * 4 + 1]);
      cur.z += tp * (acc[i][2] + b2all[e * Dd + bn + tx * 4 + 2]);
      cur.w += tp * (acc[i][3] + b2all[e * Dd + bn + tx * 4 + 3]);
      *(float4*)(out + obase) = cur;
    }
  }
}

// ---------------- cls-token sub-LN FFN (2 rows total) -----------------------
__global__ __launch_bounds__(256) void cls_ffn_kernel(const float* __restrict__ h2,
                                                      const float* __restrict__ w1,
                                                      const float* __restrict__ b1,
                                                      const float* __restrict__ lg,
                                                      const float* __restrict__ lb,
                                                      const float* __restrict__ w2,
                                                      const float* __restrict__ b2,
                                                      float* __restrict__ outbuf) {
  __shared__ float hrow[Dd];
  __shared__ float hid[FF];
  __shared__ float red[8];
  int b = blockIdx.x, tid = threadIdx.x;
  const float* hr = h2 + (size_t)(b * S1) * Dd;
  hrow[tid] = hr[tid];
  hrow[tid + 256] = hr[tid + 256];
  __syncthreads();
  float hv[8];
  float s1 = 0.f, s2 = 0.f;
#pragma unroll
  for (int j = 0; j < 8; ++j) {
    int col = tid + j * 256;
    float acc = b1[col];
    for (int d = 0; d < Dd; ++d) acc += hrow[d] * w1[(size_t)d * FF + col];
    acc = geluf(acc);
    hv[j] = acc; s1 += acc; s2 += acc * acc;
  }
  s1 = bsum(s1, red);
  s2 = bsum(s2, red);
  float mean = s1 * (1.0f / FF);
  float var = s2 * (1.0f / FF) - mean * mean;
  float rstd = rsqrtf(var + 1e-5f);
#pragma unroll
  for (int j = 0; j < 8; ++j) {
    int col = tid + j * 256;
    hid[col] = (hv[j] - mean) * rstd * lg[col] + lb[col];
  }
  __syncthreads();
#pragma unroll
  for (int j = 0; j < 2; ++j) {
    int col = tid + j * 256;
    float acc = b2[col];
    for (int k = 0; k < FF; ++k) acc += hid[k] * w2[(size_t)k * Dd + col];
    outbuf[(size_t)(b * S1) * Dd + col] += acc;
  }
}

// ---------------- loss ------------------------------------------------------
__global__ __launch_bounds__(256) void loss_part_kernel(const float* __restrict__ gate,
                                                        const int* __restrict__ lbl,
                                                        float* __restrict__ part) {
  __shared__ float red[8];
  int t = blockIdx.x * 256 + threadIdx.x;
  float v = 0.f;
  if (t < NTOK) {
    const float* p = gate + (size_t)t * Ee;
    float sum = p[0] + p[1] + p[2] + p[3];
    float pl = p[lbl[t]];
    v = -logf(pl / sum + 1e-9f);
  }
  v = bsum(v, red);
  if (threadIdx.x == 0) part[blockIdx.x] = v;
}

__global__ void loss_final_kernel(const float* __restrict__ part, float* __restrict__ out) {
  if (threadIdx.x == 0) {
    float s = 0.f;
    for (int i = 0; i < 16; ++i) s += part[i];
    out[NTOK * Ee + Bb * NCc] = s / (float)NTOK;
  }
}

// ---------------- final LN + logits ----------------------------------------
__global__ __launch_bounds__(256) void final_head_kernel(const float* __restrict__ h,
                                                         const float* __restrict__ g,
                                                         const float* __restrict__ bvec,
                                                         const float* __restrict__ w,
                                                         const float* __restrict__ fb,
                                                         float* __restrict__ out) {
  __shared__ float red[8];
  int b = blockIdx.x, tid = threadIdx.x;
  const float* hr = h + (size_t)(b * S1) * Dd;
  float x0 = hr[tid], x1 = hr[tid + 256];
  float s1 = bsum(x0 + x1, red);
  float s2 = bsum(x0 * x0 + x1 * x1, red);
  float mean = s1 * (1.0f / Dd);
  float var = s2 * (1.0f / Dd) - mean * mean;
  float rstd = rsqrtf(var + 1e-5f);
  float p0 = (x0 - mean) * rstd * g[tid] + bvec[tid];
  float p1 = (x1 - mean) * rstd * g[tid + 256] + bvec[tid + 256];
  float l0 = p0 * w[tid * 2 + 0] + p1 * w[(tid + 256) * 2 + 0];
  float l1 = p0 * w[tid * 2 + 1] + p1 * w[(tid + 256) * 2 + 1];
  l0 = bsum(l0, red);
  l1 = bsum(l1, red);
  if (tid == 0) {
    out[NTOK * Ee + b * NCc + 0] = l0 + fb[0];
    out[NTOK * Ee + b * NCc + 1] = l1 + fb[1];
  }
}

// ============================================================================
extern "C" void kernel_launch(void* const* d_in, const int* in_sizes, int n_in,
                              void* d_out, int out_size, void* d_ws, size_t ws_size,
                              hipStream_t stream) {
  (void)in_sizes; (void)n_in; (void)out_size; (void)ws_size;
  const float* x       = (const float*)d_in[0];
  const float* protos  = (const float*)d_in[1];
  const float* cls_tok = (const float*)d_in[2];
  const float* fc1_w   = (const float*)d_in[3];
  const float* fc1_b   = (const float*)d_in[4];
  const float* a0_in_w = (const float*)d_in[5];
  const float* a0_in_b = (const float*)d_in[6];
  const float* a0_out_w= (const float*)d_in[7];
  const float* a0_out_b= (const float*)d_in[8];
  const float* n1g0    = (const float*)d_in[9];
  const float* n1b0    = (const float*)d_in[10];
  const float* n2g0    = (const float*)d_in[11];
  const float* n2b0    = (const float*)d_in[12];
  const float* a1_in_w = (const float*)d_in[13];
  const float* a1_in_b = (const float*)d_in[14];
  const float* a1_out_w= (const float*)d_in[15];
  const float* a1_out_b= (const float*)d_in[16];
  const float* n1g1    = (const float*)d_in[17];
  const float* n1b1    = (const float*)d_in[18];
  const float* n2g1    = (const float*)d_in[19];
  const float* n2b1    = (const float*)d_in[20];
  const float* cw1     = (const float*)d_in[21];
  const float* cb1     = (const float*)d_in[22];
  const float* clg     = (const float*)d_in[23];
  const float* clb     = (const float*)d_in[24];
  const float* cw2     = (const float*)d_in[25];
  const float* cb2     = (const float*)d_in[26];
  const float* gate_w  = (const float*)d_in[27];
  const float* ew1     = (const float*)d_in[28];
  const float* eb1     = (const float*)d_in[29];
  const float* ew2     = (const float*)d_in[30];
  const float* eb2     = (const float*)d_in[31];
  const float* fw1     = (const float*)d_in[32];
  const float* fb1     = (const float*)d_in[33];
  const float* flg     = (const float*)d_in[34];
  const float* flb     = (const float*)d_in[35];
  const float* fw2     = (const float*)d_in[36];
  const float* fb2     = (const float*)d_in[37];
  const float* ng      = (const float*)d_in[38];
  const float* nb      = (const float*)d_in[39];
  const float* fc2_w   = (const float*)d_in[40];
  const float* fc2_b   = (const float*)d_in[41];
  float* out = (float*)d_out;

  float* w = (float*)d_ws;
  size_t off = 0;
  float* BUF0 = w + off; off += (size_t)RR * Dd;
  float* BUF1 = w + off; off += (size_t)RR * Dd;
  float* BUF2 = w + off; off += (size_t)RR * Dd;
  float* BIG  = w + off; off += (size_t)RR * FF;   // qkv (RR*1536) / moe hid / ffn hid
  float* TOPP = w + off; off += NTOK;
  float* PART = w + off; off += 64;
  int* LBL  = (int*)(w + off); off += NTOK;
  int* IDX  = (int*)(w + off); off += NTOK;
  int* LIST = (int*)(w + off); off += Ee * MOE_ROWS;
  int* CNT  = (int*)(w + off); off += Ee * Bb;

  const int elem_grid = (RR * Dd + 255) / 256;

  // 1. labels
  labels_kernel<<<NTOK / 4, 256, 0, stream>>>(x, protos, LBL);
  // 2. fc1: (4096x1024)@(1024x512)+b -> BUF1
  gemm_kernel<false, false><<<dim3(64, 8), 256, 0, stream>>>(
      x, DIN, fc1_w, Dd, fc1_b, nullptr, BUF1, Dd, NTOK, Dd, DIN);
  // 3. h = concat(cls, fc1out) -> BUF0
  assemble_kernel<<<elem_grid, 256, 0, stream>>>(BUF1, cls_tok, BUF0);

  // ---- layer 0 attention ----
  gemm_kernel<true, false><<<dim3(65, 24), 256, 0, stream>>>(
      BUF0, Dd, a0_in_w, Dd, a0_in_b, nullptr, BIG, 3 * Dd, RR, 3 * Dd, Dd);
  attn_kernel<<<dim3(513, Hh, Bb), 256, 0, stream>>>(BIG, BUF1);
  gemm_kernel<true, false><<<dim3(65, 8), 256, 0, stream>>>(
      BUF1, Dd, a0_out_w, Dd, a0_out_b, nullptr, BUF2, Dd, RR, Dd, Dd);
  // h = LN(h,n1) + attn -> BUF1 ; h = LN(BUF1,n2) -> BUF0
  ln_kernel<2><<<RR, 256, 0, stream>>>(BUF0, BUF2, n1g0, n1b0, BUF1);
  ln_kernel<2><<<RR, 256, 0, stream>>>(BUF1, nullptr, n2g0, n2b0, BUF0);

  // ---- h_res copy, cls ffn, moe ----
  copy_kernel<<<elem_grid, 256, 0, stream>>>(BUF0, BUF2);
  cls_ffn_kernel<<<Bb, 256, 0, stream>>>(BUF0, cw1, cb1, clg, clb, cw2, cb2, BUF2);
  gate_kernel<<<NTOK / 4, 256, 0, stream>>>(BUF0, gate_w, out, TOPP, IDX);
  route_kernel<<<1, 64, 0, stream>>>(IDX, LIST, CNT);
  moe_ffn1_kernel<<<dim3(11, 32, Ee), 256, 0, stream>>>(BUF0, ew1, eb1, LIST, CNT, BIG);
  moe_ffn2_kernel<<<dim3(11, 8, Ee), 256, 0, stream>>>(BIG, ew2, eb2, LIST, CNT, TOPP, BUF2);
  loss_part_kernel<<<16, 256, 0, stream>>>(out, LBL, PART);
  loss_final_kernel<<<1, 64, 0, stream>>>(PART, out);

  // ---- layer 1 attention ----
  gemm_kernel<true, false><<<dim3(65, 24), 256, 0, stream>>>(
      BUF2, Dd, a1_in_w, Dd, a1_in_b, nullptr, BIG, 3 * Dd, RR, 3 * Dd, Dd);
  attn_kernel<<<dim3(513, Hh, Bb), 256, 0, stream>>>(BIG, BUF1);
  gemm_kernel<true, false><<<dim3(65, 8), 256, 0, stream>>>(
      BUF1, Dd, a1_out_w, Dd, a1_out_b, nullptr, BUF0, Dd, RR, Dd, Dd);
  ln_kernel<2><<<RR, 256, 0, stream>>>(BUF2, BUF0, n1g1, n1b1, BUF1);
  ln_kernel<2><<<RR, 256, 0, stream>>>(BUF1, nullptr, n2g1, n2b1, BUF2);

  // ---- layer 1 FFN (sub-LN) with residual ----
  gemm_kernel<false, true><<<dim3(65, 32), 256, 0, stream>>>(
      BUF2, Dd, fw1, FF, fb1, nullptr, BIG, FF, RR, FF, Dd);
  ln_kernel<8><<<RR, 256, 0, stream>>>(BIG, nullptr, flg, flb, BIG);
  gemm_kernel<false, false><<<dim3(65, 8), 256, 0, stream>>>(
      BIG, FF, fw2, Dd, fb2, BUF2, BUF0, Dd, RR, Dd, FF);

  // ---- head ----
  final_head_kernel<<<Bb, 256, 0, stream>>>(BUF0, ng, nb, fc2_w, fc2_b, out);
}

// Round 2
// 1900.438 us; speedup vs baseline: 2.4732x; 2.4732x over previous
//
#include <hip/hip_runtime.h>
#include <cmath>

#define DEVINL __device__ __forceinline__

constexpr int Bb   = 2;
constexpr int Ss   = 2048;
constexpr int S1   = 2049;
constexpr int DIN  = 1024;
constexpr int Dd   = 512;
constexpr int Hh   = 8;
constexpr int FF   = 2048;
constexpr int Ee   = 6;
constexpr int NCc  = 2;
constexpr int CAP  = 341;
constexpr int NTOK = Bb * Ss;     // 4096
constexpr int RR   = Bb * S1;     // 4098
constexpr int MOE_ROWS = Bb * CAP; // 682

typedef __attribute__((ext_vector_type(4))) float f32x4;
typedef __attribute__((ext_vector_type(8))) short bf16x8;

DEVINL float geluf(float x) { return 0.5f * x * (1.0f + erff(x * 0.7071067811865476f)); }

DEVINL unsigned short f2bf(float f) {
  unsigned int u = __float_as_uint(f);
  u += 0x7FFFu + ((u >> 16) & 1u);
  return (unsigned short)(u >> 16);
}

DEVINL float wsum(float v) {
#pragma unroll
  for (int off = 32; off; off >>= 1) v += __shfl_xor(v, off);
  return v;
}
// block=256 reduction, broadcast result to all threads
DEVINL float bsum(float v, float* red) {
  v = wsum(v);
  int w = threadIdx.x >> 6;
  if ((threadIdx.x & 63) == 0) red[w] = v;
  __syncthreads();
  float r = red[0] + red[1] + red[2] + red[3];
  __syncthreads();
  return r;
}

// ---------------- labels: cosine-sim argmax over 4 protos -------------------
__global__ __launch_bounds__(256) void labels_kernel(const float* __restrict__ x,
                                                     const float* __restrict__ protos,
                                                     int* __restrict__ lbl) {
  int t = blockIdx.x * 4 + (threadIdx.x >> 6);
  int lane = threadIdx.x & 63;
  if (t >= NTOK) return;
  const float* xr = x + (size_t)t * DIN;
  float xv[16];
  float ss = 0.f;
#pragma unroll
  for (int i = 0; i < 16; ++i) { xv[i] = xr[lane + 64 * i]; ss += xv[i] * xv[i]; }
  ss = wsum(ss);
  float nx = sqrtf(ss) + 1e-8f;
  float best = -2e30f; int bi = 0;
  for (int p = 0; p < 4; ++p) {
    const float* pr = protos + (size_t)p * DIN;
    float dp = 0.f, pp = 0.f;
#pragma unroll
    for (int i = 0; i < 16; ++i) { float v = pr[lane + 64 * i]; dp += v * xv[i]; pp += v * v; }
    dp = wsum(dp); pp = wsum(pp);
    float sim = dp / (nx * (sqrtf(pp) + 1e-8f));
    if (sim > best) { best = sim; bi = p; }
  }
  if (lane == 0) lbl[t] = bi;
}

// ---------------- generic tiled fp32 GEMM ----------------------------------
// C(MxN) = act(A(MxK) @ B + bias) + res ; B is KxN (TRANSB=0) or NxK (TRANSB=1)
template <bool TRANSB, bool ACT>
__global__ __launch_bounds__(256) void gemm_kernel(const float* __restrict__ A, int lda,
                                                   const float* __restrict__ Bw, int ldb,
                                                   const float* __restrict__ bias,
                                                   const float* __restrict__ res,
                                                   float* __restrict__ C, int ldc,
                                                   int M, int N, int K) {
  __shared__ float As[16][68];
  __shared__ float Bs[16][68];
  const int tid = threadIdx.x;
  const int bm = blockIdx.x * 64, bn = blockIdx.y * 64;
  const int ty = tid >> 4, tx = tid & 15;
  const int arow = tid >> 2, a4 = (tid & 3) << 2;
  float acc[4][4] = {};
  for (int k0 = 0; k0 < K; k0 += 16) {
    float4 av = make_float4(0.f, 0.f, 0.f, 0.f);
    if (bm + arow < M) av = *(const float4*)(A + (size_t)(bm + arow) * lda + k0 + a4);
    As[a4 + 0][arow] = av.x; As[a4 + 1][arow] = av.y;
    As[a4 + 2][arow] = av.z; As[a4 + 3][arow] = av.w;
    if (!TRANSB) {
      const int brow = tid >> 4, b4 = (tid & 15) << 2;
      float4 bv = *(const float4*)(Bw + (size_t)(k0 + brow) * ldb + bn + b4);
      Bs[brow][b4 + 0] = bv.x; Bs[brow][b4 + 1] = bv.y;
      Bs[brow][b4 + 2] = bv.z; Bs[brow][b4 + 3] = bv.w;
    } else {
      const int nrow = tid >> 2, b4 = (tid & 3) << 2;
      float4 bv = *(const float4*)(Bw + (size_t)(bn + nrow) * ldb + k0 + b4);
      Bs[b4 + 0][nrow] = bv.x; Bs[b4 + 1][nrow] = bv.y;
      Bs[b4 + 2][nrow] = bv.z; Bs[b4 + 3][nrow] = bv.w;
    }
    __syncthreads();
#pragma unroll
    for (int kk = 0; kk < 16; ++kk) {
      float ar[4], br[4];
#pragma unroll
      for (int i = 0; i < 4; ++i) ar[i] = As[kk][ty * 4 + i];
#pragma unroll
      for (int j = 0; j < 4; ++j) br[j] = Bs[kk][tx * 4 + j];
#pragma unroll
      for (int i = 0; i < 4; ++i)
#pragma unroll
        for (int j = 0; j < 4; ++j) acc[i][j] += ar[i] * br[j];
    }
    __syncthreads();
  }
#pragma unroll
  for (int i = 0; i < 4; ++i) {
    int row = bm + ty * 4 + i;
    if (row < M) {
      size_t base = (size_t)row * ldc + bn + tx * 4;
      float v[4];
#pragma unroll
      for (int j = 0; j < 4; ++j) {
        float t = acc[i][j];
        if (bias) t += bias[bn + tx * 4 + j];
        if (ACT) t = geluf(t);
        if (res) t += res[base + j];
        v[j] = t;
      }
      *(float4*)(C + base) = make_float4(v[0], v[1], v[2], v[3]);
    }
  }
}

// ---------------- assemble h = concat(cls, fc1_out) -------------------------
__global__ __launch_bounds__(256) void assemble_kernel(const float* __restrict__ fc1out,
                                                       const float* __restrict__ cls,
                                                       float* __restrict__ h) {
  size_t i = (size_t)blockIdx.x * 256 + threadIdx.x;
  if (i >= (size_t)RR * Dd) return;
  int r = (int)(i >> 9), d = (int)(i & 511);
  int b = r / S1, sl = r - b * S1;
  float v = (sl == 0) ? cls[d] : fc1out[((size_t)(b * Ss + sl - 1) << 9) + d];
  h[i] = v;
}

__global__ __launch_bounds__(256) void copy_kernel(const float* __restrict__ src,
                                                   float* __restrict__ dst) {
  size_t i = (size_t)blockIdx.x * 256 + threadIdx.x;
  if (i < (size_t)RR * Dd) dst[i] = src[i];
}

// ---------------- LayerNorm (optionally + add) ------------------------------
template <int NPT>
__global__ __launch_bounds__(256) void ln_kernel(const float* __restrict__ in,
                                                 const float* __restrict__ addv,
                                                 const float* __restrict__ g,
                                                 const float* __restrict__ bvec,
                                                 float* __restrict__ out) {
  constexpr int N = NPT * 256;
  __shared__ float red[8];
  size_t base = (size_t)blockIdx.x * N;
  int tid = threadIdx.x;
  float x[NPT];
  float s1 = 0.f, s2 = 0.f;
#pragma unroll
  for (int j = 0; j < NPT; ++j) {
    x[j] = in[base + tid + j * 256];
    s1 += x[j]; s2 += x[j] * x[j];
  }
  s1 = bsum(s1, red);
  s2 = bsum(s2, red);
  float mean = s1 * (1.0f / N);
  float var = s2 * (1.0f / N) - mean * mean;
  float rstd = rsqrtf(var + 1e-5f);
#pragma unroll
  for (int j = 0; j < NPT; ++j) {
    int col = tid + j * 256;
    float v = (x[j] - mean) * rstd * g[col] + bvec[col];
    if (addv) v += addv[base + col];
    out[base + col] = v;
  }
}

// ---------------- MFMA bf16 flash attention ---------------------------------
// One workgroup (4 waves) handles 64 q-rows for one (b,h).
// Wave w owns q-rows [qblk + w*16, +16). K/V chunks of 64 keys staged in LDS.
// mfma_f32_16x16x32_bf16 layouts:
//   A: lane l holds A[l&15][(l>>4)*8 + j], j=0..7
//   B: lane l holds B[(l>>4)*8 + j][l&15]
//   C/D: lane l reg r holds D[(l>>4)*4 + r][l&15]   (m89-verified)
__global__ __launch_bounds__(256) void attn_mfma_kernel(const float* __restrict__ qkv,
                                                        float* __restrict__ o) {
  __shared__ unsigned short Ksh[64 * 64];   // [k][d], XOR-swizzled by (k&7)<<4
  __shared__ unsigned short Vt[64 * 64];    // [d][k], XOR-swizzled by (d&7)<<4
  __shared__ unsigned short Psh[4 * 16 * 64]; // per-wave [q][k], swizzled by (q&7)<<4
  const int tid = threadIdx.x;
  const int w = tid >> 6, l = tid & 63;
  const int l15 = l & 15, lg = l >> 4;
  const int hh = blockIdx.y, b = blockIdx.z;
  const int qblk = blockIdx.x * 64;
  const size_t rbase = (size_t)b * S1 * 1536;

  // --- Q fragments (A-layout), pre-scaled by 1/sqrt(dh)=0.125 (exact) ------
  bf16x8 aq[2];
  {
    int qr = qblk + w * 16 + l15;
    bool qv = qr < S1;
    const float* qp = qkv + rbase + (size_t)qr * 1536 + hh * 64;
#pragma unroll
    for (int dc = 0; dc < 2; ++dc) {
      float f[8];
      if (qv) {
        *(float4*)&f[0] = *(const float4*)(qp + dc * 32 + lg * 8);
        *(float4*)&f[4] = *(const float4*)(qp + dc * 32 + lg * 8 + 4);
      } else {
#pragma unroll
        for (int j = 0; j < 8; ++j) f[j] = 0.f;
      }
#pragma unroll
      for (int j = 0; j < 8; ++j) aq[dc][j] = (short)f2bf(f[j] * 0.125f);
    }
  }

  f32x4 ovac[4];
#pragma unroll
  for (int dt = 0; dt < 4; ++dt) ovac[dt] = (f32x4){0.f, 0.f, 0.f, 0.f};
  float m_r[4], l_r[4];
#pragma unroll
  for (int r = 0; r < 4; ++r) { m_r[r] = -1e30f; l_r[r] = 0.f; }

  const int sk_k = tid >> 2, sk_d0 = (tid & 3) * 16;      // K staging: row, d-chunk
  const int sv_k0 = (tid & 31) * 2, sv_d0 = (tid >> 5) * 8; // V staging: key pair, d-chunk

  for (int c = 0; c < 33; ++c) {
    // ---- stage K (row-major bf16, swizzled) ----
    {
      int key = c * 64 + sk_k;
      float f[16];
      if (key < S1) {
        const float* kp = qkv + rbase + (size_t)key * 1536 + 512 + hh * 64 + sk_d0;
        *(float4*)&f[0]  = *(const float4*)(kp + 0);
        *(float4*)&f[4]  = *(const float4*)(kp + 4);
        *(float4*)&f[8]  = *(const float4*)(kp + 8);
        *(float4*)&f[12] = *(const float4*)(kp + 12);
      } else {
#pragma unroll
        for (int j = 0; j < 16; ++j) f[j] = 0.f;
      }
      bf16x8 lo, hi;
#pragma unroll
      for (int j = 0; j < 8; ++j) { lo[j] = (short)f2bf(f[j]); hi[j] = (short)f2bf(f[8 + j]); }
      const int rswz = (sk_k & 7) << 4;
      *(bf16x8*)((char*)Ksh + (((sk_k * 64 + sk_d0) * 2) ^ rswz)) = lo;
      *(bf16x8*)((char*)Ksh + (((sk_k * 64 + sk_d0 + 8) * 2) ^ rswz)) = hi;
    }
    // ---- stage V transposed ([d][k], pair-packed b32 writes, swizzled) ----
    {
      int key0 = c * 64 + sv_k0;
      const float* vp = qkv + rbase + (size_t)key0 * 1536 + 1024 + hh * 64 + sv_d0;
      float fa[8], fb[8];
      if (key0 < S1) {
        *(float4*)&fa[0] = *(const float4*)(vp);
        *(float4*)&fa[4] = *(const float4*)(vp + 4);
      } else {
#pragma unroll
        for (int j = 0; j < 8; ++j) fa[j] = 0.f;
      }
      if (key0 + 1 < S1) {
        *(float4*)&fb[0] = *(const float4*)(vp + 1536);
        *(float4*)&fb[4] = *(const float4*)(vp + 1536 + 4);
      } else {
#pragma unroll
        for (int j = 0; j < 8; ++j) fb[j] = 0.f;
      }
#pragma unroll
      for (int i = 0; i < 8; ++i) {
        unsigned int pk = (unsigned int)f2bf(fa[i]) | ((unsigned int)f2bf(fb[i]) << 16);
        int d = sv_d0 + i;
        *(unsigned int*)((char*)Vt + (((d * 64 + sv_k0) * 2) ^ ((d & 7) << 4))) = pk;
      }
    }
    __syncthreads();

    // ---- S = Q K^T (16q x 64k per wave) ----
    f32x4 s[4];
#pragma unroll
    for (int kt = 0; kt < 4; ++kt) {
      f32x4 acc = (f32x4){0.f, 0.f, 0.f, 0.f};
      const int krow = kt * 16 + l15;
      const int rswz = (krow & 7) << 4;
#pragma unroll
      for (int dc = 0; dc < 2; ++dc) {
        bf16x8 kb = *(const bf16x8*)((const char*)Ksh + (((krow * 64 + dc * 32 + lg * 8) * 2) ^ rswz));
        acc = __builtin_amdgcn_mfma_f32_16x16x32_bf16(aq[dc], kb, acc, 0, 0, 0);
      }
      if (c * 64 + kt * 16 + l15 >= S1) acc = (f32x4){-1e30f, -1e30f, -1e30f, -1e30f};
      s[kt] = acc;
    }

    // ---- online softmax (row stats lane-distributed over 16-lane groups) --
    float mx[4];
#pragma unroll
    for (int r = 0; r < 4; ++r)
      mx[r] = fmaxf(fmaxf(s[0][r], s[1][r]), fmaxf(s[2][r], s[3][r]));
#pragma unroll
    for (int off = 1; off < 16; off <<= 1)
#pragma unroll
      for (int r = 0; r < 4; ++r) mx[r] = fmaxf(mx[r], __shfl_xor(mx[r], off));
    float fac[4], rs[4];
#pragma unroll
    for (int r = 0; r < 4; ++r) {
      float mn = fmaxf(m_r[r], mx[r]);
      fac[r] = __expf(m_r[r] - mn);
      m_r[r] = mn;
      rs[r] = 0.f;
    }
#pragma unroll
    for (int kt = 0; kt < 4; ++kt)
#pragma unroll
      for (int r = 0; r < 4; ++r) {
        float p = __expf(s[kt][r] - m_r[r]);
        s[kt][r] = p;
        rs[r] += p;
      }
#pragma unroll
    for (int off = 1; off < 16; off <<= 1)
#pragma unroll
      for (int r = 0; r < 4; ++r) rs[r] += __shfl_xor(rs[r], off);
#pragma unroll
    for (int r = 0; r < 4; ++r) l_r[r] = l_r[r] * fac[r] + rs[r];

    // ---- write P (bf16) to per-wave LDS, C-layout -> A-layout round-trip --
    {
      char* pb = (char*)Psh + w * 2048;
#pragma unroll
      for (int kt = 0; kt < 4; ++kt)
#pragma unroll
        for (int r = 0; r < 4; ++r) {
          int q = lg * 4 + r;
          *(unsigned short*)(pb + (((q * 64 + kt * 16 + l15) * 2) ^ ((q & 7) << 4))) =
              f2bf(s[kt][r]);
        }
    }

    // ---- rescale O ----
#pragma unroll
    for (int dt = 0; dt < 4; ++dt)
#pragma unroll
      for (int r = 0; r < 4; ++r) ovac[dt][r] *= fac[r];

    // ---- O += P @ V ----
    {
      const char* pb = (const char*)Psh + w * 2048;
      const int pswz = (l15 & 7) << 4;
#pragma unroll
      for (int kh = 0; kh < 2; ++kh) {
        bf16x8 pa = *(const bf16x8*)(pb + (((l15 * 64 + kh * 32 + lg * 8) * 2) ^ pswz));
#pragma unroll
        for (int dt = 0; dt < 4; ++dt) {
          bf16x8 vb = *(const bf16x8*)((const char*)Vt +
                        ((((dt * 16 + l15) * 64 + kh * 32 + lg * 8) * 2) ^ pswz));
          ovac[dt] = __builtin_amdgcn_mfma_f32_16x16x32_bf16(pa, vb, ovac[dt], 0, 0, 0);
        }
      }
    }
    __syncthreads();
  }

  // ---- finalize: O /= l, store ----
  float inv[4];
#pragma unroll
  for (int r = 0; r < 4; ++r) inv[r] = 1.0f / l_r[r];
#pragma unroll
  for (int r = 0; r < 4; ++r) {
    int qq = qblk + w * 16 + lg * 4 + r;
    if (qq < S1) {
      float* orow = o + (size_t)(b * S1 + qq) * Dd + hh * 64;
#pragma unroll
      for (int dt = 0; dt < 4; ++dt) orow[dt * 16 + l15] = ovac[dt][r] * inv[r];
    }
  }
}

// ---------------- gate softmax + top1 routing info --------------------------
__global__ __launch_bounds__(256) void gate_kernel(const float* __restrict__ h2,
                                                   const float* __restrict__ gw,
                                                   float* __restrict__ gate_out,
                                                   float* __restrict__ topp,
                                                   int* __restrict__ idx) {
  int t = blockIdx.x * 4 + (threadIdx.x >> 6);
  int lane = threadIdx.x & 63;
  if (t >= NTOK) return;
  int b = t >> 11, s = t & (Ss - 1);
  const float* hr = h2 + (size_t)(b * S1 + s + 1) * Dd;
  float acc[6] = {};
#pragma unroll
  for (int i = 0; i < 8; ++i) {
    int d = lane + i * 64;
    float xv = hr[d];
    const float* g = gw + (size_t)d * Ee;
#pragma unroll
    for (int e = 0; e < 6; ++e) acc[e] += xv * g[e];
  }
#pragma unroll
  for (int e = 0; e < 6; ++e) acc[e] = wsum(acc[e]);
  if (lane == 0) {
    float mx = acc[0];
#pragma unroll
    for (int e = 1; e < 6; ++e) mx = fmaxf(mx, acc[e]);
    float ex[6], sum = 0.f;
#pragma unroll
    for (int e = 0; e < 6; ++e) { ex[e] = __expf(acc[e] - mx); sum += ex[e]; }
    float invs = 1.0f / sum;
    int best = 0; float bp = ex[0];
#pragma unroll
    for (int e = 1; e < 6; ++e) { if (ex[e] > bp) { bp = ex[e]; best = e; } }
#pragma unroll
    for (int e = 0; e < 6; ++e) gate_out[(size_t)t * Ee + e] = ex[e] * invs;
    topp[t] = bp * invs;
    idx[t] = best;
  }
}

// ---------------- capacity-limited top-1 router (serial per batch) ----------
__global__ void route_kernel(const int* __restrict__ idx, int* __restrict__ list,
                             int* __restrict__ cnt) {
  int b = threadIdx.x;
  if (b >= Bb) return;
  int c[Ee];
#pragma unroll
  for (int e = 0; e < Ee; ++e) c[e] = 0;
  for (int s = 0; s < Ss; ++s) {
    int t = b * Ss + s;
    int e = idx[t];
    if (c[e] < CAP) list[e * MOE_ROWS + b * CAP + c[e]] = t;
    c[e]++;
  }
#pragma unroll
  for (int e = 0; e < Ee; ++e) cnt[e * Bb + b] = (c[e] < CAP) ? c[e] : CAP;
}

// ---------------- MoE expert FFN (gathered GEMMs) ---------------------------
__global__ __launch_bounds__(256) void moe_ffn1_kernel(const float* __restrict__ h2,
                                                       const float* __restrict__ w1all,
                                                       const float* __restrict__ b1all,
                                                       const int* __restrict__ list,
                                                       const int* __restrict__ cnt,
                                                       float* __restrict__ hid) {
  __shared__ float As[16][68];
  __shared__ float Bs[16][68];
  const int e = blockIdx.z;
  const int c0 = cnt[e * 2 + 0], c1 = cnt[e * 2 + 1];
  const int tid = threadIdx.x;
  const int bm = blockIdx.x * 64, bn = blockIdx.y * 64;
  const int ty = tid >> 4, tx = tid & 15;
  const float* w1 = w1all + (size_t)e * Dd * FF;
  const int arow = tid >> 2, a4 = (tid & 3) << 2;
  int r = bm + arow;
  bool aval = (r < CAP) ? (r < c0) : ((r - CAP) < c1);
  size_t abase = 0;
  if (aval) {
    int tok = list[e * MOE_ROWS + r];
    int b = tok >> 11, s = tok & (Ss - 1);
    abase = (size_t)(b * S1 + s + 1) * Dd;
  }
  float acc[4][4] = {};
  for (int k0 = 0; k0 < Dd; k0 += 16) {
    float4 av = make_float4(0.f, 0.f, 0.f, 0.f);
    if (aval) av = *(const float4*)(h2 + abase + k0 + a4);
    As[a4 + 0][arow] = av.x; As[a4 + 1][arow] = av.y;
    As[a4 + 2][arow] = av.z; As[a4 + 3][arow] = av.w;
    {
      const int brow = tid >> 4, b4 = (tid & 15) << 2;
      float4 bv = *(const float4*)(w1 + (size_t)(k0 + brow) * FF + bn + b4);
      Bs[brow][b4 + 0] = bv.x; Bs[brow][b4 + 1] = bv.y;
      Bs[brow][b4 + 2] = bv.z; Bs[brow][b4 + 3] = bv.w;
    }
    __syncthreads();
#pragma unroll
    for (int kk = 0; kk < 16; ++kk) {
      float ar[4], br[4];
#pragma unroll
      for (int i = 0; i < 4; ++i) ar[i] = As[kk][ty * 4 + i];
#pragma unroll
      for (int j = 0; j < 4; ++j) br[j] = Bs[kk][tx * 4 + j];
#pragma unroll
      for (int i = 0; i < 4; ++i)
#pragma unroll
        for (int j = 0; j < 4; ++j) acc[i][j] += ar[i] * br[j];
    }
    __syncthreads();
  }
#pragma unroll
  for (int i = 0; i < 4; ++i) {
    int r2 = bm + ty * 4 + i;
    bool v2 = (r2 < CAP) ? (r2 < c0) : ((r2 - CAP) < c1);
    if (v2) {
      size_t base = ((size_t)e * MOE_ROWS + r2) * FF + bn + tx * 4;
      float v[4];
#pragma unroll
      for (int j = 0; j < 4; ++j) v[j] = geluf(acc[i][j] + b1all[e * FF + bn + tx * 4 + j]);
      *(float4*)(hid + base) = make_float4(v[0], v[1], v[2], v[3]);
    }
  }
}

__global__ __launch_bounds__(256) void moe_ffn2_kernel(const float* __restrict__ hid,
                                                       const float* __restrict__ w2all,
                                                       const float* __restrict__ b2all,
                                                       const int* __restrict__ list,
                                                       const int* __restrict__ cnt,
                                                       const float* __restrict__ topp,
                                                       float* __restrict__ out) {
  __shared__ float As[16][68];
  __shared__ float Bs[16][68];
  const int e = blockIdx.z;
  const int c0 = cnt[e * 2 + 0], c1 = cnt[e * 2 + 1];
  const int tid = threadIdx.x;
  const int bm = blockIdx.x * 64, bn = blockIdx.y * 64;
  const int ty = tid >> 4, tx = tid & 15;
  const float* w2 = w2all + (size_t)e * FF * Dd;
  const int arow = tid >> 2, a4 = (tid & 3) << 2;
  int r = bm + arow;
  bool aval = (r < CAP) ? (r < c0) : ((r - CAP) < c1);
  size_t abase = ((size_t)e * MOE_ROWS + r) * FF;
  float acc[4][4] = {};
  for (int k0 = 0; k0 < FF; k0 += 16) {
    float4 av = make_float4(0.f, 0.f, 0.f, 0.f);
    if (aval) av = *(const float4*)(hid + abase + k0 + a4);
    As[a4 + 0][arow] = av.x; As[a4 + 1][arow] = av.y;
    As[a4 + 2][arow] = av.z; As[a4 + 3][arow] = av.w;
    {
      const int brow = tid >> 4, b4 = (tid & 15) << 2;
      float4 bv = *(const float4*)(w2 + (size_t)(k0 + brow) * Dd + bn + b4);
      Bs[brow][b4 + 0] = bv.x; Bs[brow][b4 + 1] = bv.y;
      Bs[brow][b4 + 2] = bv.z; Bs[brow][b4 + 3] = bv.w;
    }
    __syncthreads();
#pragma unroll
    for (int kk = 0; kk < 16; ++kk) {
      float ar[4], br[4];
#pragma unroll
      for (int i = 0; i < 4; ++i) ar[i] = As[kk][ty * 4 + i];
#pragma unroll
      for (int j = 0; j < 4; ++j) br[j] = Bs[kk][tx * 4 + j];
#pragma unroll
      for (int i = 0; i < 4; ++i)
#pragma unroll
        for (int j = 0; j < 4; ++j) acc[i][j] += ar[i] * br[j];
    }
    __syncthreads();
  }
#pragma unroll
  for (int i = 0; i < 4; ++i) {
    int r2 = bm + ty * 4 + i;
    bool v2 = (r2 < CAP) ? (r2 < c0) : ((r2 - CAP) < c1);
    if (v2) {
      int tok = list[e * MOE_ROWS + r2];
      int b = tok >> 11, s = tok & (Ss - 1);
      float tp = topp[tok];
      size_t obase = (size_t)(b * S1 + s + 1) * Dd + bn + tx * 4;
      float4 cur = *(const float4*)(out + obase);
      cur.x += tp * (acc[i][0] + b2all[e * Dd + bn + tx * 4 + 0]);
      cur.y += tp * (acc[i][1] + b2all[e * Dd + bn + tx * 4 + 1]);
      cur.z += tp * (acc[i][2] + b2all[e * Dd + bn + tx * 4 + 2]);
      cur.w += tp * (acc[i][3] + b2all[e * Dd + bn + tx * 4 + 3]);
      *(float4*)(out + obase) = cur;
    }
  }
}

// ---------------- cls-token sub-LN FFN (2 rows total) -----------------------
__global__ __launch_bounds__(256) void cls_ffn_kernel(const float* __restrict__ h2,
                                                      const float* __restrict__ w1,
                                                      const float* __restrict__ b1,
                                                      const float* __restrict__ lg,
                                                      const float* __restrict__ lb,
                                                      const float* __restrict__ w2,
                                                      const float* __restrict__ b2,
                                                      float* __restrict__ outbuf) {
  __shared__ float hrow[Dd];
  __shared__ float hid[FF];
  __shared__ float red[8];
  int b = blockIdx.x, tid = threadIdx.x;
  const float* hr = h2 + (size_t)(b * S1) * Dd;
  hrow[tid] = hr[tid];
  hrow[tid + 256] = hr[tid + 256];
  __syncthreads();
  float hv[8];
  float s1 = 0.f, s2 = 0.f;
#pragma unroll
  for (int j = 0; j < 8; ++j) {
    int col = tid + j * 256;
    float acc = b1[col];
    for (int d = 0; d < Dd; ++d) acc += hrow[d] * w1[(size_t)d * FF + col];
    acc = geluf(acc);
    hv[j] = acc; s1 += acc; s2 += acc * acc;
  }
  s1 = bsum(s1, red);
  s2 = bsum(s2, red);
  float mean = s1 * (1.0f / FF);
  float var = s2 * (1.0f / FF) - mean * mean;
  float rstd = rsqrtf(var + 1e-5f);
#pragma unroll
  for (int j = 0; j < 8; ++j) {
    int col = tid + j * 256;
    hid[col] = (hv[j] - mean) * rstd * lg[col] + lb[col];
  }
  __syncthreads();
#pragma unroll
  for (int j = 0; j < 2; ++j) {
    int col = tid + j * 256;
    float acc = b2[col];
    for (int k = 0; k < FF; ++k) acc += hid[k] * w2[(size_t)k * Dd + col];
    outbuf[(size_t)(b * S1) * Dd + col] += acc;
  }
}

// ---------------- loss ------------------------------------------------------
__global__ __launch_bounds__(256) void loss_part_kernel(const float* __restrict__ gate,
                                                        const int* __restrict__ lbl,
                                                        float* __restrict__ part) {
  __shared__ float red[8];
  int t = blockIdx.x * 256 + threadIdx.x;
  float v = 0.f;
  if (t < NTOK) {
    const float* p = gate + (size_t)t * Ee;
    float sum = p[0] + p[1] + p[2] + p[3];
    float pl = p[lbl[t]];
    v = -logf(pl / sum + 1e-9f);
  }
  v = bsum(v, red);
  if (threadIdx.x == 0) part[blockIdx.x] = v;
}

__global__ void loss_final_kernel(const float* __restrict__ part, float* __restrict__ out) {
  if (threadIdx.x == 0) {
    float s = 0.f;
    for (int i = 0; i < 16; ++i) s += part[i];
    out[NTOK * Ee + Bb * NCc] = s / (float)NTOK;
  }
}

// ---------------- final LN + logits ----------------------------------------
__global__ __launch_bounds__(256) void final_head_kernel(const float* __restrict__ h,
                                                         const float* __restrict__ g,
                                                         const float* __restrict__ bvec,
                                                         const float* __restrict__ w,
                                                         const float* __restrict__ fb,
                                                         float* __restrict__ out) {
  __shared__ float red[8];
  int b = blockIdx.x, tid = threadIdx.x;
  const float* hr = h + (size_t)(b * S1) * Dd;
  float x0 = hr[tid], x1 = hr[tid + 256];
  float s1 = bsum(x0 + x1, red);
  float s2 = bsum(x0 * x0 + x1 * x1, red);
  float mean = s1 * (1.0f / Dd);
  float var = s2 * (1.0f / Dd) - mean * mean;
  float rstd = rsqrtf(var + 1e-5f);
  float p0 = (x0 - mean) * rstd * g[tid] + bvec[tid];
  float p1 = (x1 - mean) * rstd * g[tid + 256] + bvec[tid + 256];
  float l0 = p0 * w[tid * 2 + 0] + p1 * w[(tid + 256) * 2 + 0];
  float l1 = p0 * w[tid * 2 + 1] + p1 * w[(tid + 256) * 2 + 1];
  l0 = bsum(l0, red);
  l1 = bsum(l1, red);
  if (tid == 0) {
    out[NTOK * Ee + b * NCc + 0] = l0 + fb[0];
    out[NTOK * Ee + b * NCc + 1] = l1 + fb[1];
  }
}

// ============================================================================
extern "C" void kernel_launch(void* const* d_in, const int* in_sizes, int n_in,
                              void* d_out, int out_size, void* d_ws, size_t ws_size,
                              hipStream_t stream) {
  (void)in_sizes; (void)n_in; (void)out_size; (void)ws_size;
  const float* x       = (const float*)d_in[0];
  const float* protos  = (const float*)d_in[1];
  const float* cls_tok = (const float*)d_in[2];
  const float* fc1_w   = (const float*)d_in[3];
  const float* fc1_b   = (const float*)d_in[4];
  const float* a0_in_w = (const float*)d_in[5];
  const float* a0_in_b = (const float*)d_in[6];
  const float* a0_out_w= (const float*)d_in[7];
  const float* a0_out_b= (const float*)d_in[8];
  const float* n1g0    = (const float*)d_in[9];
  const float* n1b0    = (const float*)d_in[10];
  const float* n2g0    = (const float*)d_in[11];
  const float* n2b0    = (const float*)d_in[12];
  const float* a1_in_w = (const float*)d_in[13];
  const float* a1_in_b = (const float*)d_in[14];
  const float* a1_out_w= (const float*)d_in[15];
  const float* a1_out_b= (const float*)d_in[16];
  const float* n1g1    = (const float*)d_in[17];
  const float* n1b1    = (const float*)d_in[18];
  const float* n2g1    = (const float*)d_in[19];
  const float* n2b1    = (const float*)d_in[20];
  const float* cw1     = (const float*)d_in[21];
  const float* cb1     = (const float*)d_in[22];
  const float* clg     = (const float*)d_in[23];
  const float* clb     = (const float*)d_in[24];
  const float* cw2     = (const float*)d_in[25];
  const float* cb2     = (const float*)d_in[26];
  const float* gate_w  = (const float*)d_in[27];
  const float* ew1     = (const float*)d_in[28];
  const float* eb1     = (const float*)d_in[29];
  const float* ew2     = (const float*)d_in[30];
  const float* eb2     = (const float*)d_in[31];
  const float* fw1     = (const float*)d_in[32];
  const float* fb1     = (const float*)d_in[33];
  const float* flg     = (const float*)d_in[34];
  const float* flb     = (const float*)d_in[35];
  const float* fw2     = (const float*)d_in[36];
  const float* fb2     = (const float*)d_in[37];
  const float* ng      = (const float*)d_in[38];
  const float* nb      = (const float*)d_in[39];
  const float* fc2_w   = (const float*)d_in[40];
  const float* fc2_b   = (const float*)d_in[41];
  float* out = (float*)d_out;

  float* w = (float*)d_ws;
  size_t off = 0;
  float* BUF0 = w + off; off += (size_t)RR * Dd;
  float* BUF1 = w + off; off += (size_t)RR * Dd;
  float* BUF2 = w + off; off += (size_t)RR * Dd;
  float* BIG  = w + off; off += (size_t)RR * FF;   // qkv (RR*1536) / moe hid / ffn hid
  float* TOPP = w + off; off += NTOK;
  float* PART = w + off; off += 64;
  int* LBL  = (int*)(w + off); off += NTOK;
  int* IDX  = (int*)(w + off); off += NTOK;
  int* LIST = (int*)(w + off); off += Ee * MOE_ROWS;
  int* CNT  = (int*)(w + off); off += Ee * Bb;

  const int elem_grid = (RR * Dd + 255) / 256;

  // 1. labels
  labels_kernel<<<NTOK / 4, 256, 0, stream>>>(x, protos, LBL);
  // 2. fc1: (4096x1024)@(1024x512)+b -> BUF1
  gemm_kernel<false, false><<<dim3(64, 8), 256, 0, stream>>>(
      x, DIN, fc1_w, Dd, fc1_b, nullptr, BUF1, Dd, NTOK, Dd, DIN);
  // 3. h = concat(cls, fc1out) -> BUF0
  assemble_kernel<<<elem_grid, 256, 0, stream>>>(BUF1, cls_tok, BUF0);

  // ---- layer 0 attention ----
  gemm_kernel<true, false><<<dim3(65, 24), 256, 0, stream>>>(
      BUF0, Dd, a0_in_w, Dd, a0_in_b, nullptr, BIG, 3 * Dd, RR, 3 * Dd, Dd);
  attn_mfma_kernel<<<dim3(33, Hh, Bb), 256, 0, stream>>>(BIG, BUF1);
  gemm_kernel<true, false><<<dim3(65, 8), 256, 0, stream>>>(
      BUF1, Dd, a0_out_w, Dd, a0_out_b, nullptr, BUF2, Dd, RR, Dd, Dd);
  // h = LN(h,n1) + attn -> BUF1 ; h = LN(BUF1,n2) -> BUF0
  ln_kernel<2><<<RR, 256, 0, stream>>>(BUF0, BUF2, n1g0, n1b0, BUF1);
  ln_kernel<2><<<RR, 256, 0, stream>>>(BUF1, nullptr, n2g0, n2b0, BUF0);

  // ---- h_res copy, cls ffn, moe ----
  copy_kernel<<<elem_grid, 256, 0, stream>>>(BUF0, BUF2);
  cls_ffn_kernel<<<Bb, 256, 0, stream>>>(BUF0, cw1, cb1, clg, clb, cw2, cb2, BUF2);
  gate_kernel<<<NTOK / 4, 256, 0, stream>>>(BUF0, gate_w, out, TOPP, IDX);
  route_kernel<<<1, 64, 0, stream>>>(IDX, LIST, CNT);
  moe_ffn1_kernel<<<dim3(11, 32, Ee), 256, 0, stream>>>(BUF0, ew1, eb1, LIST, CNT, BIG);
  moe_ffn2_kernel<<<dim3(11, 8, Ee), 256, 0, stream>>>(BIG, ew2, eb2, LIST, CNT, TOPP, BUF2);
  loss_part_kernel<<<16, 256, 0, stream>>>(out, LBL, PART);
  loss_final_kernel<<<1, 64, 0, stream>>>(PART, out);

  // ---- layer 1 attention ----
  gemm_kernel<true, false><<<dim3(65, 24), 256, 0, stream>>>(
      BUF2, Dd, a1_in_w, Dd, a1_in_b, nullptr, BIG, 3 * Dd, RR, 3 * Dd, Dd);
  attn_mfma_kernel<<<dim3(33, Hh, Bb), 256, 0, stream>>>(BIG, BUF1);
  gemm_kernel<true, false><<<dim3(65, 8), 256, 0, stream>>>(
      BUF1, Dd, a1_out_w, Dd, a1_out_b, nullptr, BUF0, Dd, RR, Dd, Dd);
  ln_kernel<2><<<RR, 256, 0, stream>>>(BUF2, BUF0, n1g1, n1b1, BUF1);
  ln_kernel<2><<<RR, 256, 0, stream>>>(BUF1, nullptr, n2g1, n2b1, BUF2);

  // ---- layer 1 FFN (sub-LN) with residual ----
  gemm_kernel<false, true><<<dim3(65, 32), 256, 0, stream>>>(
      BUF2, Dd, fw1, FF, fb1, nullptr, BIG, FF, RR, FF, Dd);
  ln_kernel<8><<<RR, 256, 0, stream>>>(BIG, nullptr, flg, flb, BIG);
  gemm_kernel<false, false><<<dim3(65, 8), 256, 0, stream>>>(
      BIG, FF, fw2, Dd, fb2, BUF2, BUF0, Dd, RR, Dd, FF);

  // ---- head ----
  final_head_kernel<<<Bb, 256, 0, stream>>>(BUF0, ng, nb, fc2_w, fc2_b, out);
}

// Round 3
// 1105.713 us; speedup vs baseline: 4.2508x; 1.7187x over previous
//
#include <hip/hip_runtime.h>
#include <cmath>

#define DEVINL __device__ __forceinline__

constexpr int Bb   = 2;
constexpr int Ss   = 2048;
constexpr int S1   = 2049;
constexpr int DIN  = 1024;
constexpr int Dd   = 512;
constexpr int Hh   = 8;
constexpr int FF   = 2048;
constexpr int Ee   = 6;
constexpr int NCc  = 2;
constexpr int CAP  = 341;
constexpr int NTOK = Bb * Ss;     // 4096
constexpr int RR   = Bb * S1;     // 4098
constexpr int MOE_ROWS = Bb * CAP; // 682

typedef __attribute__((ext_vector_type(4))) float f32x4;
typedef __attribute__((ext_vector_type(8))) short bf16x8;

DEVINL float geluf(float x) { return 0.5f * x * (1.0f + erff(x * 0.7071067811865476f)); }

DEVINL unsigned short f2bf(float f) {
  unsigned int u = __float_as_uint(f);
  u += 0x7FFFu + ((u >> 16) & 1u);
  return (unsigned short)(u >> 16);
}

DEVINL float wsum(float v) {
#pragma unroll
  for (int off = 32; off; off >>= 1) v += __shfl_xor(v, off);
  return v;
}
// block=256 reduction, broadcast result to all threads
DEVINL float bsum(float v, float* red) {
  v = wsum(v);
  int w = threadIdx.x >> 6;
  if ((threadIdx.x & 63) == 0) red[w] = v;
  __syncthreads();
  float r = red[0] + red[1] + red[2] + red[3];
  __syncthreads();
  return r;
}

// ---------------- labels: cosine-sim argmax over 4 protos -------------------
__global__ __launch_bounds__(256) void labels_kernel(const float* __restrict__ x,
                                                     const float* __restrict__ protos,
                                                     int* __restrict__ lbl) {
  int t = blockIdx.x * 4 + (threadIdx.x >> 6);
  int lane = threadIdx.x & 63;
  if (t >= NTOK) return;
  const float* xr = x + (size_t)t * DIN;
  float xv[16];
  float ss = 0.f;
#pragma unroll
  for (int i = 0; i < 16; ++i) { xv[i] = xr[lane + 64 * i]; ss += xv[i] * xv[i]; }
  ss = wsum(ss);
  float nx = sqrtf(ss) + 1e-8f;
  float best = -2e30f; int bi = 0;
  for (int p = 0; p < 4; ++p) {
    const float* pr = protos + (size_t)p * DIN;
    float dp = 0.f, pp = 0.f;
#pragma unroll
    for (int i = 0; i < 16; ++i) { float v = pr[lane + 64 * i]; dp += v * xv[i]; pp += v * v; }
    dp = wsum(dp); pp = wsum(pp);
    float sim = dp / (nx * (sqrtf(pp) + 1e-8f));
    if (sim > best) { best = sim; bi = p; }
  }
  if (lane == 0) lbl[t] = bi;
}

// ================= bf16 MFMA GEMM =========================================
// C(MxN) = act(A@op(B) + bias) [+ res].  A fp32 MxK row-major (bf16-converted
// on stage).  BT=0: B is KxN row-major; BT=1: B is NxK row-major.
// Tile 128x128x64, 4 waves (2x2), each wave 64x64 via 4x4 frags of 16x16x32.
// LDS: As[m][k], Bs[n][k], 128B rows, XOR swizzle byte^=(row&7)<<4 (G4).
// mfma_f32_16x16x32_bf16 layouts (m89-verified, reused from attention):
//   A: lane l holds A[l&15][(l>>4)*8+j]; B: lane l holds op(B)[(l>>4)*8+j][l&15]
//   (Bs[n][k] staged so contiguous-k read gives the B fragment)
//   C/D: lane l reg r = C[(l>>4)*4+r][l&15]
template <bool BT, bool ACT>
__global__ __launch_bounds__(256) void mgemm_kernel(const float* __restrict__ A, int lda,
                                                    const float* __restrict__ Bw, int ldb,
                                                    const float* __restrict__ bias,
                                                    const float* __restrict__ res,
                                                    float* __restrict__ C, int ldc,
                                                    int M, int N, int K) {
  __shared__ unsigned short As[128 * 64];
  __shared__ unsigned short Bs[128 * 64];
  const int tid = threadIdx.x;
  const int l = tid & 63, l15 = l & 15, lg = l >> 4;
  const int wm = (tid >> 7), wn = (tid >> 6) & 1;
  const int bm = blockIdx.x * 128, bn = blockIdx.y * 128;

  f32x4 acc[4][4];
#pragma unroll
  for (int i = 0; i < 4; ++i)
#pragma unroll
    for (int j = 0; j < 4; ++j) acc[i][j] = (f32x4){0.f, 0.f, 0.f, 0.f};

  const int ar = tid >> 1, ac = (tid & 1) * 32;       // A/B(T) staging: row, col-chunk
  const int bkp = (tid & 31) * 2, bnc = (tid >> 5) * 16; // B(KxN) staging

  for (int k0 = 0; k0 < K; k0 += 64) {
    // ---- stage A (fp32 -> bf16) ----
    {
      float f[32];
      if (bm + ar < M) {
        const float* ap = A + (size_t)(bm + ar) * lda + k0 + ac;
#pragma unroll
        for (int i = 0; i < 8; ++i) *(float4*)&f[i * 4] = *(const float4*)(ap + i * 4);
      } else {
#pragma unroll
        for (int i = 0; i < 32; ++i) f[i] = 0.f;
      }
      const int rswz = (ar & 7) << 4;
#pragma unroll
      for (int i = 0; i < 4; ++i) {
        bf16x8 v;
#pragma unroll
        for (int j = 0; j < 8; ++j) v[j] = (short)f2bf(f[i * 8 + j]);
        *(bf16x8*)((char*)As + ((ar * 128 + (ac + i * 8) * 2) ^ rswz)) = v;
      }
    }
    // ---- stage B ----
    if (BT) {
      // B is NxK: Bs[n][k] = Bw[n][k], contiguous
      float f[32];
      const float* bp = Bw + (size_t)(bn + ar) * ldb + k0 + ac;
#pragma unroll
      for (int i = 0; i < 8; ++i) *(float4*)&f[i * 4] = *(const float4*)(bp + i * 4);
      const int rswz = (ar & 7) << 4;
#pragma unroll
      for (int i = 0; i < 4; ++i) {
        bf16x8 v;
#pragma unroll
        for (int j = 0; j < 8; ++j) v[j] = (short)f2bf(f[i * 8 + j]);
        *(bf16x8*)((char*)Bs + ((ar * 128 + (ac + i * 8) * 2) ^ rswz)) = v;
      }
    } else {
      // B is KxN: transpose-stage pairs of k (attention-V pattern)
      const float* bp = Bw + (size_t)(k0 + bkp) * ldb + bn + bnc;
      float fa[16], fb[16];
#pragma unroll
      for (int i = 0; i < 4; ++i) {
        *(float4*)&fa[i * 4] = *(const float4*)(bp + i * 4);
        *(float4*)&fb[i * 4] = *(const float4*)(bp + ldb + i * 4);
      }
#pragma unroll
      for (int i = 0; i < 16; ++i) {
        unsigned int pk = (unsigned int)f2bf(fa[i]) | ((unsigned int)f2bf(fb[i]) << 16);
        int n = bnc + i;
        *(unsigned int*)((char*)Bs + ((n * 128 + bkp * 2) ^ ((n & 7) << 4))) = pk;
      }
    }
    __syncthreads();

#pragma unroll
    for (int kc = 0; kc < 2; ++kc) {
      bf16x8 af[4], bfr[4];
#pragma unroll
      for (int mi = 0; mi < 4; ++mi) {
        int row = wm * 64 + mi * 16 + l15;
        af[mi] = *(const bf16x8*)((const char*)As +
                   ((row * 128 + (kc * 32 + lg * 8) * 2) ^ ((row & 7) << 4)));
      }
#pragma unroll
      for (int ni = 0; ni < 4; ++ni) {
        int row = wn * 64 + ni * 16 + l15;
        bfr[ni] = *(const bf16x8*)((const char*)Bs +
                   ((row * 128 + (kc * 32 + lg * 8) * 2) ^ ((row & 7) << 4)));
      }
#pragma unroll
      for (int mi = 0; mi < 4; ++mi)
#pragma unroll
        for (int ni = 0; ni < 4; ++ni)
          acc[mi][ni] = __builtin_amdgcn_mfma_f32_16x16x32_bf16(af[mi], bfr[ni], acc[mi][ni], 0, 0, 0);
    }
    __syncthreads();
  }

  // ---- epilogue ----
#pragma unroll
  for (int mi = 0; mi < 4; ++mi)
#pragma unroll
    for (int r = 0; r < 4; ++r) {
      int row = bm + wm * 64 + mi * 16 + lg * 4 + r;
      if (row < M) {
#pragma unroll
        for (int ni = 0; ni < 4; ++ni) {
          int col = bn + wn * 64 + ni * 16 + l15;
          float t = acc[mi][ni][r];
          if (bias) t += bias[col];
          if (ACT) t = geluf(t);
          if (res) t += res[(size_t)row * ldc + col];
          C[(size_t)row * ldc + col] = t;
        }
      }
    }
}

// ---- MoE variant 1: gathered-A GEMM, hid = gelu(h2[tok] @ w1[e] + b1[e]) ----
__global__ __launch_bounds__(256) void moe_mgemm1_kernel(const float* __restrict__ h2,
                                                         const float* __restrict__ w1all,
                                                         const float* __restrict__ b1all,
                                                         const int* __restrict__ list,
                                                         const int* __restrict__ cnt,
                                                         float* __restrict__ hid) {
  __shared__ unsigned short As[128 * 64];
  __shared__ unsigned short Bs[128 * 64];
  const int e = blockIdx.z;
  const int c0 = cnt[e * 2 + 0], c1 = cnt[e * 2 + 1];
  const float* Bw = w1all + (size_t)e * Dd * FF;
  const int tid = threadIdx.x;
  const int l = tid & 63, l15 = l & 15, lg = l >> 4;
  const int wm = (tid >> 7), wn = (tid >> 6) & 1;
  const int bm = blockIdx.x * 128, bn = blockIdx.y * 128;

  f32x4 acc[4][4];
#pragma unroll
  for (int i = 0; i < 4; ++i)
#pragma unroll
    for (int j = 0; j < 4; ++j) acc[i][j] = (f32x4){0.f, 0.f, 0.f, 0.f};

  const int ar = tid >> 1, ac = (tid & 1) * 32;
  const int bkp = (tid & 31) * 2, bnc = (tid >> 5) * 16;

  int r = bm + ar;
  bool aval = (r < MOE_ROWS) && ((r < CAP) ? (r < c0) : ((r - CAP) < c1));
  size_t abase = 0;
  if (aval) {
    int tok = list[e * MOE_ROWS + r];
    int b = tok >> 11, s = tok & (Ss - 1);
    abase = (size_t)(b * S1 + s + 1) * Dd;
  }

  for (int k0 = 0; k0 < Dd; k0 += 64) {
    {
      float f[32];
      if (aval) {
        const float* ap = h2 + abase + k0 + ac;
#pragma unroll
        for (int i = 0; i < 8; ++i) *(float4*)&f[i * 4] = *(const float4*)(ap + i * 4);
      } else {
#pragma unroll
        for (int i = 0; i < 32; ++i) f[i] = 0.f;
      }
      const int rswz = (ar & 7) << 4;
#pragma unroll
      for (int i = 0; i < 4; ++i) {
        bf16x8 v;
#pragma unroll
        for (int j = 0; j < 8; ++j) v[j] = (short)f2bf(f[i * 8 + j]);
        *(bf16x8*)((char*)As + ((ar * 128 + (ac + i * 8) * 2) ^ rswz)) = v;
      }
    }
    {
      const float* bp = Bw + (size_t)(k0 + bkp) * FF + bn + bnc;
      float fa[16], fb[16];
#pragma unroll
      for (int i = 0; i < 4; ++i) {
        *(float4*)&fa[i * 4] = *(const float4*)(bp + i * 4);
        *(float4*)&fb[i * 4] = *(const float4*)(bp + FF + i * 4);
      }
#pragma unroll
      for (int i = 0; i < 16; ++i) {
        unsigned int pk = (unsigned int)f2bf(fa[i]) | ((unsigned int)f2bf(fb[i]) << 16);
        int n = bnc + i;
        *(unsigned int*)((char*)Bs + ((n * 128 + bkp * 2) ^ ((n & 7) << 4))) = pk;
      }
    }
    __syncthreads();
#pragma unroll
    for (int kc = 0; kc < 2; ++kc) {
      bf16x8 af[4], bfr[4];
#pragma unroll
      for (int mi = 0; mi < 4; ++mi) {
        int row = wm * 64 + mi * 16 + l15;
        af[mi] = *(const bf16x8*)((const char*)As +
                   ((row * 128 + (kc * 32 + lg * 8) * 2) ^ ((row & 7) << 4)));
      }
#pragma unroll
      for (int ni = 0; ni < 4; ++ni) {
        int row = wn * 64 + ni * 16 + l15;
        bfr[ni] = *(const bf16x8*)((const char*)Bs +
                   ((row * 128 + (kc * 32 + lg * 8) * 2) ^ ((row & 7) << 4)));
      }
#pragma unroll
      for (int mi = 0; mi < 4; ++mi)
#pragma unroll
        for (int ni = 0; ni < 4; ++ni)
          acc[mi][ni] = __builtin_amdgcn_mfma_f32_16x16x32_bf16(af[mi], bfr[ni], acc[mi][ni], 0, 0, 0);
    }
    __syncthreads();
  }

#pragma unroll
  for (int mi = 0; mi < 4; ++mi)
#pragma unroll
    for (int rr = 0; rr < 4; ++rr) {
      int row = bm + wm * 64 + mi * 16 + lg * 4 + rr;
      bool v2 = (row < MOE_ROWS) && ((row < CAP) ? (row < c0) : ((row - CAP) < c1));
      if (v2) {
#pragma unroll
        for (int ni = 0; ni < 4; ++ni) {
          int col = bn + wn * 64 + ni * 16 + l15;
          hid[((size_t)e * MOE_ROWS + row) * FF + col] =
              geluf(acc[mi][ni][rr] + b1all[e * FF + col]);
        }
      }
    }
}

// ---- MoE variant 2: out[tok] += topp * (hid @ w2[e] + b2[e]) ----------------
__global__ __launch_bounds__(256) void moe_mgemm2_kernel(const float* __restrict__ hid,
                                                         const float* __restrict__ w2all,
                                                         const float* __restrict__ b2all,
                                                         const int* __restrict__ list,
                                                         const int* __restrict__ cnt,
                                                         const float* __restrict__ topp,
                                                         float* __restrict__ out) {
  __shared__ unsigned short As[128 * 64];
  __shared__ unsigned short Bs[128 * 64];
  const int e = blockIdx.z;
  const int c0 = cnt[e * 2 + 0], c1 = cnt[e * 2 + 1];
  const float* Bw = w2all + (size_t)e * FF * Dd;
  const int tid = threadIdx.x;
  const int l = tid & 63, l15 = l & 15, lg = l >> 4;
  const int wm = (tid >> 7), wn = (tid >> 6) & 1;
  const int bm = blockIdx.x * 128, bn = blockIdx.y * 128;

  f32x4 acc[4][4];
#pragma unroll
  for (int i = 0; i < 4; ++i)
#pragma unroll
    for (int j = 0; j < 4; ++j) acc[i][j] = (f32x4){0.f, 0.f, 0.f, 0.f};

  const int ar = tid >> 1, ac = (tid & 1) * 32;
  const int bkp = (tid & 31) * 2, bnc = (tid >> 5) * 16;

  int r = bm + ar;
  bool aval = (r < MOE_ROWS) && ((r < CAP) ? (r < c0) : ((r - CAP) < c1));
  size_t abase = ((size_t)e * MOE_ROWS + r) * FF;

  for (int k0 = 0; k0 < FF; k0 += 64) {
    {
      float f[32];
      if (aval) {
        const float* ap = hid + abase + k0 + ac;
#pragma unroll
        for (int i = 0; i < 8; ++i) *(float4*)&f[i * 4] = *(const float4*)(ap + i * 4);
      } else {
#pragma unroll
        for (int i = 0; i < 32; ++i) f[i] = 0.f;
      }
      const int rswz = (ar & 7) << 4;
#pragma unroll
      for (int i = 0; i < 4; ++i) {
        bf16x8 v;
#pragma unroll
        for (int j = 0; j < 8; ++j) v[j] = (short)f2bf(f[i * 8 + j]);
        *(bf16x8*)((char*)As + ((ar * 128 + (ac + i * 8) * 2) ^ rswz)) = v;
      }
    }
    {
      const float* bp = Bw + (size_t)(k0 + bkp) * Dd + bn + bnc;
      float fa[16], fb[16];
#pragma unroll
      for (int i = 0; i < 4; ++i) {
        *(float4*)&fa[i * 4] = *(const float4*)(bp + i * 4);
        *(float4*)&fb[i * 4] = *(const float4*)(bp + Dd + i * 4);
      }
#pragma unroll
      for (int i = 0; i < 16; ++i) {
        unsigned int pk = (unsigned int)f2bf(fa[i]) | ((unsigned int)f2bf(fb[i]) << 16);
        int n = bnc + i;
        *(unsigned int*)((char*)Bs + ((n * 128 + bkp * 2) ^ ((n & 7) << 4))) = pk;
      }
    }
    __syncthreads();
#pragma unroll
    for (int kc = 0; kc < 2; ++kc) {
      bf16x8 af[4], bfr[4];
#pragma unroll
      for (int mi = 0; mi < 4; ++mi) {
        int row = wm * 64 + mi * 16 + l15;
        af[mi] = *(const bf16x8*)((const char*)As +
                   ((row * 128 + (kc * 32 + lg * 8) * 2) ^ ((row & 7) << 4)));
      }
#pragma unroll
      for (int ni = 0; ni < 4; ++ni) {
        int row = wn * 64 + ni * 16 + l15;
        bfr[ni] = *(const bf16x8*)((const char*)Bs +
                   ((row * 128 + (kc * 32 + lg * 8) * 2) ^ ((row & 7) << 4)));
      }
#pragma unroll
      for (int mi = 0; mi < 4; ++mi)
#pragma unroll
        for (int ni = 0; ni < 4; ++ni)
          acc[mi][ni] = __builtin_amdgcn_mfma_f32_16x16x32_bf16(af[mi], bfr[ni], acc[mi][ni], 0, 0, 0);
    }
    __syncthreads();
  }

#pragma unroll
  for (int mi = 0; mi < 4; ++mi)
#pragma unroll
    for (int rr = 0; rr < 4; ++rr) {
      int row = bm + wm * 64 + mi * 16 + lg * 4 + rr;
      bool v2 = (row < MOE_ROWS) && ((row < CAP) ? (row < c0) : ((row - CAP) < c1));
      if (v2) {
        int tok = list[e * MOE_ROWS + row];
        int b = tok >> 11, s = tok & (Ss - 1);
        float tp = topp[tok];
#pragma unroll
        for (int ni = 0; ni < 4; ++ni) {
          int col = bn + wn * 64 + ni * 16 + l15;
          size_t oidx = (size_t)(b * S1 + s + 1) * Dd + col;
          out[oidx] += tp * (acc[mi][ni][rr] + b2all[e * Dd + col]);
        }
      }
    }
}

// ---------------- assemble h = concat(cls, fc1_out) -------------------------
__global__ __launch_bounds__(256) void assemble_kernel(const float* __restrict__ fc1out,
                                                       const float* __restrict__ cls,
                                                       float* __restrict__ h) {
  size_t i = (size_t)blockIdx.x * 256 + threadIdx.x;
  if (i >= (size_t)RR * Dd) return;
  int r = (int)(i >> 9), d = (int)(i & 511);
  int b = r / S1, sl = r - b * S1;
  float v = (sl == 0) ? cls[d] : fc1out[((size_t)(b * Ss + sl - 1) << 9) + d];
  h[i] = v;
}

__global__ __launch_bounds__(256) void copy_kernel(const float* __restrict__ src,
                                                   float* __restrict__ dst) {
  size_t i = (size_t)blockIdx.x * 256 + threadIdx.x;
  if (i < (size_t)RR * Dd) dst[i] = src[i];
}

// ---------------- LayerNorm (optionally + add) ------------------------------
template <int NPT>
__global__ __launch_bounds__(256) void ln_kernel(const float* __restrict__ in,
                                                 const float* __restrict__ addv,
                                                 const float* __restrict__ g,
                                                 const float* __restrict__ bvec,
                                                 float* __restrict__ out) {
  constexpr int N = NPT * 256;
  __shared__ float red[8];
  size_t base = (size_t)blockIdx.x * N;
  int tid = threadIdx.x;
  float x[NPT];
  float s1 = 0.f, s2 = 0.f;
#pragma unroll
  for (int j = 0; j < NPT; ++j) {
    x[j] = in[base + tid + j * 256];
    s1 += x[j]; s2 += x[j] * x[j];
  }
  s1 = bsum(s1, red);
  s2 = bsum(s2, red);
  float mean = s1 * (1.0f / N);
  float var = s2 * (1.0f / N) - mean * mean;
  float rstd = rsqrtf(var + 1e-5f);
#pragma unroll
  for (int j = 0; j < NPT; ++j) {
    int col = tid + j * 256;
    float v = (x[j] - mean) * rstd * g[col] + bvec[col];
    if (addv) v += addv[base + col];
    out[base + col] = v;
  }
}

// ---------------- MFMA bf16 flash attention ---------------------------------
__global__ __launch_bounds__(256) void attn_mfma_kernel(const float* __restrict__ qkv,
                                                        float* __restrict__ o) {
  __shared__ unsigned short Ksh[64 * 64];   // [k][d], XOR-swizzled by (k&7)<<4
  __shared__ unsigned short Vt[64 * 64];    // [d][k], XOR-swizzled by (d&7)<<4
  __shared__ unsigned short Psh[4 * 16 * 64]; // per-wave [q][k], swizzled by (q&7)<<4
  const int tid = threadIdx.x;
  const int w = tid >> 6, l = tid & 63;
  const int l15 = l & 15, lg = l >> 4;
  const int hh = blockIdx.y, b = blockIdx.z;
  const int qblk = blockIdx.x * 64;
  const size_t rbase = (size_t)b * S1 * 1536;

  bf16x8 aq[2];
  {
    int qr = qblk + w * 16 + l15;
    bool qv = qr < S1;
    const float* qp = qkv + rbase + (size_t)qr * 1536 + hh * 64;
#pragma unroll
    for (int dc = 0; dc < 2; ++dc) {
      float f[8];
      if (qv) {
        *(float4*)&f[0] = *(const float4*)(qp + dc * 32 + lg * 8);
        *(float4*)&f[4] = *(const float4*)(qp + dc * 32 + lg * 8 + 4);
      } else {
#pragma unroll
        for (int j = 0; j < 8; ++j) f[j] = 0.f;
      }
#pragma unroll
      for (int j = 0; j < 8; ++j) aq[dc][j] = (short)f2bf(f[j] * 0.125f);
    }
  }

  f32x4 ovac[4];
#pragma unroll
  for (int dt = 0; dt < 4; ++dt) ovac[dt] = (f32x4){0.f, 0.f, 0.f, 0.f};
  float m_r[4], l_r[4];
#pragma unroll
  for (int r = 0; r < 4; ++r) { m_r[r] = -1e30f; l_r[r] = 0.f; }

  const int sk_k = tid >> 2, sk_d0 = (tid & 3) * 16;
  const int sv_k0 = (tid & 31) * 2, sv_d0 = (tid >> 5) * 8;

  for (int c = 0; c < 33; ++c) {
    {
      int key = c * 64 + sk_k;
      float f[16];
      if (key < S1) {
        const float* kp = qkv + rbase + (size_t)key * 1536 + 512 + hh * 64 + sk_d0;
        *(float4*)&f[0]  = *(const float4*)(kp + 0);
        *(float4*)&f[4]  = *(const float4*)(kp + 4);
        *(float4*)&f[8]  = *(const float4*)(kp + 8);
        *(float4*)&f[12] = *(const float4*)(kp + 12);
      } else {
#pragma unroll
        for (int j = 0; j < 16; ++j) f[j] = 0.f;
      }
      bf16x8 lo, hi;
#pragma unroll
      for (int j = 0; j < 8; ++j) { lo[j] = (short)f2bf(f[j]); hi[j] = (short)f2bf(f[8 + j]); }
      const int rswz = (sk_k & 7) << 4;
      *(bf16x8*)((char*)Ksh + (((sk_k * 64 + sk_d0) * 2) ^ rswz)) = lo;
      *(bf16x8*)((char*)Ksh + (((sk_k * 64 + sk_d0 + 8) * 2) ^ rswz)) = hi;
    }
    {
      int key0 = c * 64 + sv_k0;
      const float* vp = qkv + rbase + (size_t)key0 * 1536 + 1024 + hh * 64 + sv_d0;
      float fa[8], fb[8];
      if (key0 < S1) {
        *(float4*)&fa[0] = *(const float4*)(vp);
        *(float4*)&fa[4] = *(const float4*)(vp + 4);
      } else {
#pragma unroll
        for (int j = 0; j < 8; ++j) fa[j] = 0.f;
      }
      if (key0 + 1 < S1) {
        *(float4*)&fb[0] = *(const float4*)(vp + 1536);
        *(float4*)&fb[4] = *(const float4*)(vp + 1536 + 4);
      } else {
#pragma unroll
        for (int j = 0; j < 8; ++j) fb[j] = 0.f;
      }
#pragma unroll
      for (int i = 0; i < 8; ++i) {
        unsigned int pk = (unsigned int)f2bf(fa[i]) | ((unsigned int)f2bf(fb[i]) << 16);
        int d = sv_d0 + i;
        *(unsigned int*)((char*)Vt + (((d * 64 + sv_k0) * 2) ^ ((d & 7) << 4))) = pk;
      }
    }
    __syncthreads();

    f32x4 s[4];
#pragma unroll
    for (int kt = 0; kt < 4; ++kt) {
      f32x4 acc = (f32x4){0.f, 0.f, 0.f, 0.f};
      const int krow = kt * 16 + l15;
      const int rswz = (krow & 7) << 4;
#pragma unroll
      for (int dc = 0; dc < 2; ++dc) {
        bf16x8 kb = *(const bf16x8*)((const char*)Ksh + (((krow * 64 + dc * 32 + lg * 8) * 2) ^ rswz));
        acc = __builtin_amdgcn_mfma_f32_16x16x32_bf16(aq[dc], kb, acc, 0, 0, 0);
      }
      if (c * 64 + kt * 16 + l15 >= S1) acc = (f32x4){-1e30f, -1e30f, -1e30f, -1e30f};
      s[kt] = acc;
    }

    float mx[4];
#pragma unroll
    for (int r = 0; r < 4; ++r)
      mx[r] = fmaxf(fmaxf(s[0][r], s[1][r]), fmaxf(s[2][r], s[3][r]));
#pragma unroll
    for (int off = 1; off < 16; off <<= 1)
#pragma unroll
      for (int r = 0; r < 4; ++r) mx[r] = fmaxf(mx[r], __shfl_xor(mx[r], off));
    float fac[4], rs[4];
#pragma unroll
    for (int r = 0; r < 4; ++r) {
      float mn = fmaxf(m_r[r], mx[r]);
      fac[r] = __expf(m_r[r] - mn);
      m_r[r] = mn;
      rs[r] = 0.f;
    }
#pragma unroll
    for (int kt = 0; kt < 4; ++kt)
#pragma unroll
      for (int r = 0; r < 4; ++r) {
        float p = __expf(s[kt][r] - m_r[r]);
        s[kt][r] = p;
        rs[r] += p;
      }
#pragma unroll
    for (int off = 1; off < 16; off <<= 1)
#pragma unroll
      for (int r = 0; r < 4; ++r) rs[r] += __shfl_xor(rs[r], off);
#pragma unroll
    for (int r = 0; r < 4; ++r) l_r[r] = l_r[r] * fac[r] + rs[r];

    {
      char* pb = (char*)Psh + w * 2048;
#pragma unroll
      for (int kt = 0; kt < 4; ++kt)
#pragma unroll
        for (int r = 0; r < 4; ++r) {
          int q = lg * 4 + r;
          *(unsigned short*)(pb + (((q * 64 + kt * 16 + l15) * 2) ^ ((q & 7) << 4))) =
              f2bf(s[kt][r]);
        }
    }

#pragma unroll
    for (int dt = 0; dt < 4; ++dt)
#pragma unroll
      for (int r = 0; r < 4; ++r) ovac[dt][r] *= fac[r];

    {
      const char* pb = (const char*)Psh + w * 2048;
      const int pswz = (l15 & 7) << 4;
#pragma unroll
      for (int kh = 0; kh < 2; ++kh) {
        bf16x8 pa = *(const bf16x8*)(pb + (((l15 * 64 + kh * 32 + lg * 8) * 2) ^ pswz));
#pragma unroll
        for (int dt = 0; dt < 4; ++dt) {
          bf16x8 vb = *(const bf16x8*)((const char*)Vt +
                        ((((dt * 16 + l15) * 64 + kh * 32 + lg * 8) * 2) ^ pswz));
          ovac[dt] = __builtin_amdgcn_mfma_f32_16x16x32_bf16(pa, vb, ovac[dt], 0, 0, 0);
        }
      }
    }
    __syncthreads();
  }

  float inv[4];
#pragma unroll
  for (int r = 0; r < 4; ++r) inv[r] = 1.0f / l_r[r];
#pragma unroll
  for (int r = 0; r < 4; ++r) {
    int qq = qblk + w * 16 + lg * 4 + r;
    if (qq < S1) {
      float* orow = o + (size_t)(b * S1 + qq) * Dd + hh * 64;
#pragma unroll
      for (int dt = 0; dt < 4; ++dt) orow[dt * 16 + l15] = ovac[dt][r] * inv[r];
    }
  }
}

// ---------------- gate softmax + top1 routing info --------------------------
__global__ __launch_bounds__(256) void gate_kernel(const float* __restrict__ h2,
                                                   const float* __restrict__ gw,
                                                   float* __restrict__ gate_out,
                                                   float* __restrict__ topp,
                                                   int* __restrict__ idx) {
  int t = blockIdx.x * 4 + (threadIdx.x >> 6);
  int lane = threadIdx.x & 63;
  if (t >= NTOK) return;
  int b = t >> 11, s = t & (Ss - 1);
  const float* hr = h2 + (size_t)(b * S1 + s + 1) * Dd;
  float acc[6] = {};
#pragma unroll
  for (int i = 0; i < 8; ++i) {
    int d = lane + i * 64;
    float xv = hr[d];
    const float* g = gw + (size_t)d * Ee;
#pragma unroll
    for (int e = 0; e < 6; ++e) acc[e] += xv * g[e];
  }
#pragma unroll
  for (int e = 0; e < 6; ++e) acc[e] = wsum(acc[e]);
  if (lane == 0) {
    float mx = acc[0];
#pragma unroll
    for (int e = 1; e < 6; ++e) mx = fmaxf(mx, acc[e]);
    float ex[6], sum = 0.f;
#pragma unroll
    for (int e = 0; e < 6; ++e) { ex[e] = __expf(acc[e] - mx); sum += ex[e]; }
    float invs = 1.0f / sum;
    int best = 0; float bp = ex[0];
#pragma unroll
    for (int e = 1; e < 6; ++e) { if (ex[e] > bp) { bp = ex[e]; best = e; } }
#pragma unroll
    for (int e = 0; e < 6; ++e) gate_out[(size_t)t * Ee + e] = ex[e] * invs;
    topp[t] = bp * invs;
    idx[t] = best;
  }
}

// ---------------- capacity-limited top-1 router (parallel scan) -------------
// One block per (expert, batch); rank = position among same-expert tokens in
// sequence order; keep if rank < CAP. Order preserved by contiguous chunks.
__global__ __launch_bounds__(256) void route_kernel(const int* __restrict__ idx,
                                                    int* __restrict__ list,
                                                    int* __restrict__ cnt) {
  __shared__ int cnts[256];
  __shared__ int tot;
  const int e = blockIdx.x, b = blockIdx.y;
  const int tid = threadIdx.x;
  const int s0 = tid * 8;
  int loc[8];
  int c = 0;
#pragma unroll
  for (int j = 0; j < 8; ++j) {
    int t = b * Ss + s0 + j;
    if (idx[t] == e) loc[c++] = t;
  }
  cnts[tid] = c;
  __syncthreads();
  if (tid == 0) {
    int run = 0;
    for (int i = 0; i < 256; ++i) { int v = cnts[i]; cnts[i] = run; run += v; }
    tot = run;
  }
  __syncthreads();
  int base = cnts[tid];
  for (int j = 0; j < c; ++j) {
    int pos = base + j;
    if (pos < CAP) list[e * MOE_ROWS + b * CAP + pos] = loc[j];
  }
  if (tid == 0) cnt[e * Bb + b] = (tot < CAP) ? tot : CAP;
}

// ---------------- cls-token sub-LN FFN (2 rows total) -----------------------
__global__ __launch_bounds__(256) void cls_ffn_kernel(const float* __restrict__ h2,
                                                      const float* __restrict__ w1,
                                                      const float* __restrict__ b1,
                                                      const float* __restrict__ lg,
                                                      const float* __restrict__ lb,
                                                      const float* __restrict__ w2,
                                                      const float* __restrict__ b2,
                                                      float* __restrict__ outbuf) {
  __shared__ float hrow[Dd];
  __shared__ float hid[FF];
  __shared__ float red[8];
  int b = blockIdx.x, tid = threadIdx.x;
  const float* hr = h2 + (size_t)(b * S1) * Dd;
  hrow[tid] = hr[tid];
  hrow[tid + 256] = hr[tid + 256];
  __syncthreads();
  float hv[8];
  float s1 = 0.f, s2 = 0.f;
#pragma unroll
  for (int j = 0; j < 8; ++j) {
    int col = tid + j * 256;
    float acc = b1[col];
    for (int d = 0; d < Dd; ++d) acc += hrow[d] * w1[(size_t)d * FF + col];
    acc = geluf(acc);
    hv[j] = acc; s1 += acc; s2 += acc * acc;
  }
  s1 = bsum(s1, red);
  s2 = bsum(s2, red);
  float mean = s1 * (1.0f / FF);
  float var = s2 * (1.0f / FF) - mean * mean;
  float rstd = rsqrtf(var + 1e-5f);
#pragma unroll
  for (int j = 0; j < 8; ++j) {
    int col = tid + j * 256;
    hid[col] = (hv[j] - mean) * rstd * lg[col] + lb[col];
  }
  __syncthreads();
#pragma unroll
  for (int j = 0; j < 2; ++j) {
    int col = tid + j * 256;
    float acc = b2[col];
    for (int k = 0; k < FF; ++k) acc += hid[k] * w2[(size_t)k * Dd + col];
    outbuf[(size_t)(b * S1) * Dd + col] += acc;
  }
}

// ---------------- loss ------------------------------------------------------
__global__ __launch_bounds__(256) void loss_part_kernel(const float* __restrict__ gate,
                                                        const int* __restrict__ lbl,
                                                        float* __restrict__ part) {
  __shared__ float red[8];
  int t = blockIdx.x * 256 + threadIdx.x;
  float v = 0.f;
  if (t < NTOK) {
    const float* p = gate + (size_t)t * Ee;
    float sum = p[0] + p[1] + p[2] + p[3];
    float pl = p[lbl[t]];
    v = -logf(pl / sum + 1e-9f);
  }
  v = bsum(v, red);
  if (threadIdx.x == 0) part[blockIdx.x] = v;
}

__global__ void loss_final_kernel(const float* __restrict__ part, float* __restrict__ out) {
  if (threadIdx.x == 0) {
    float s = 0.f;
    for (int i = 0; i < 16; ++i) s += part[i];
    out[NTOK * Ee + Bb * NCc] = s / (float)NTOK;
  }
}

// ---------------- final LN + logits ----------------------------------------
__global__ __launch_bounds__(256) void final_head_kernel(const float* __restrict__ h,
                                                         const float* __restrict__ g,
                                                         const float* __restrict__ bvec,
                                                         const float* __restrict__ w,
                                                         const float* __restrict__ fb,
                                                         float* __restrict__ out) {
  __shared__ float red[8];
  int b = blockIdx.x, tid = threadIdx.x;
  const float* hr = h + (size_t)(b * S1) * Dd;
  float x0 = hr[tid], x1 = hr[tid + 256];
  float s1 = bsum(x0 + x1, red);
  float s2 = bsum(x0 * x0 + x1 * x1, red);
  float mean = s1 * (1.0f / Dd);
  float var = s2 * (1.0f / Dd) - mean * mean;
  float rstd = rsqrtf(var + 1e-5f);
  float p0 = (x0 - mean) * rstd * g[tid] + bvec[tid];
  float p1 = (x1 - mean) * rstd * g[tid + 256] + bvec[tid + 256];
  float l0 = p0 * w[tid * 2 + 0] + p1 * w[(tid + 256) * 2 + 0];
  float l1 = p0 * w[tid * 2 + 1] + p1 * w[(tid + 256) * 2 + 1];
  l0 = bsum(l0, red);
  l1 = bsum(l1, red);
  if (tid == 0) {
    out[NTOK * Ee + b * NCc + 0] = l0 + fb[0];
    out[NTOK * Ee + b * NCc + 1] = l1 + fb[1];
  }
}

// ============================================================================
extern "C" void kernel_launch(void* const* d_in, const int* in_sizes, int n_in,
                              void* d_out, int out_size, void* d_ws, size_t ws_size,
                              hipStream_t stream) {
  (void)in_sizes; (void)n_in; (void)out_size; (void)ws_size;
  const float* x       = (const float*)d_in[0];
  const float* protos  = (const float*)d_in[1];
  const float* cls_tok = (const float*)d_in[2];
  const float* fc1_w   = (const float*)d_in[3];
  const float* fc1_b   = (const float*)d_in[4];
  const float* a0_in_w = (const float*)d_in[5];
  const float* a0_in_b = (const float*)d_in[6];
  const float* a0_out_w= (const float*)d_in[7];
  const float* a0_out_b= (const float*)d_in[8];
  const float* n1g0    = (const float*)d_in[9];
  const float* n1b0    = (const float*)d_in[10];
  const float* n2g0    = (const float*)d_in[11];
  const float* n2b0    = (const float*)d_in[12];
  const float* a1_in_w = (const float*)d_in[13];
  const float* a1_in_b = (const float*)d_in[14];
  const float* a1_out_w= (const float*)d_in[15];
  const float* a1_out_b= (const float*)d_in[16];
  const float* n1g1    = (const float*)d_in[17];
  const float* n1b1    = (const float*)d_in[18];
  const float* n2g1    = (const float*)d_in[19];
  const float* n2b1    = (const float*)d_in[20];
  const float* cw1     = (const float*)d_in[21];
  const float* cb1     = (const float*)d_in[22];
  const float* clg     = (const float*)d_in[23];
  const float* clb     = (const float*)d_in[24];
  const float* cw2     = (const float*)d_in[25];
  const float* cb2     = (const float*)d_in[26];
  const float* gate_w  = (const float*)d_in[27];
  const float* ew1     = (const float*)d_in[28];
  const float* eb1     = (const float*)d_in[29];
  const float* ew2     = (const float*)d_in[30];
  const float* eb2     = (const float*)d_in[31];
  const float* fw1     = (const float*)d_in[32];
  const float* fb1     = (const float*)d_in[33];
  const float* flg     = (const float*)d_in[34];
  const float* flb     = (const float*)d_in[35];
  const float* fw2     = (const float*)d_in[36];
  const float* fb2     = (const float*)d_in[37];
  const float* ng      = (const float*)d_in[38];
  const float* nb      = (const float*)d_in[39];
  const float* fc2_w   = (const float*)d_in[40];
  const float* fc2_b   = (const float*)d_in[41];
  float* out = (float*)d_out;

  float* w = (float*)d_ws;
  size_t off = 0;
  float* BUF0 = w + off; off += (size_t)RR * Dd;
  float* BUF1 = w + off; off += (size_t)RR * Dd;
  float* BUF2 = w + off; off += (size_t)RR * Dd;
  float* BIG  = w + off; off += (size_t)RR * FF;   // qkv (RR*1536) / moe hid / ffn hid
  float* TOPP = w + off; off += NTOK;
  float* PART = w + off; off += 64;
  int* LBL  = (int*)(w + off); off += NTOK;
  int* IDX  = (int*)(w + off); off += NTOK;
  int* LIST = (int*)(w + off); off += Ee * MOE_ROWS;
  int* CNT  = (int*)(w + off); off += Ee * Bb;

  const int elem_grid = (RR * Dd + 255) / 256;

  // 1. labels
  labels_kernel<<<NTOK / 4, 256, 0, stream>>>(x, protos, LBL);
  // 2. fc1: (4096x1024)@(1024x512)+b -> BUF1
  mgemm_kernel<false, false><<<dim3(32, 4), 256, 0, stream>>>(
      x, DIN, fc1_w, Dd, fc1_b, nullptr, BUF1, Dd, NTOK, Dd, DIN);
  // 3. h = concat(cls, fc1out) -> BUF0
  assemble_kernel<<<elem_grid, 256, 0, stream>>>(BUF1, cls_tok, BUF0);

  // ---- layer 0 attention ----
  mgemm_kernel<true, false><<<dim3(33, 12), 256, 0, stream>>>(
      BUF0, Dd, a0_in_w, Dd, a0_in_b, nullptr, BIG, 3 * Dd, RR, 3 * Dd, Dd);
  attn_mfma_kernel<<<dim3(33, Hh, Bb), 256, 0, stream>>>(BIG, BUF1);
  mgemm_kernel<true, false><<<dim3(33, 4), 256, 0, stream>>>(
      BUF1, Dd, a0_out_w, Dd, a0_out_b, nullptr, BUF2, Dd, RR, Dd, Dd);
  // h = LN(h,n1) + attn -> BUF1 ; h = LN(BUF1,n2) -> BUF0
  ln_kernel<2><<<RR, 256, 0, stream>>>(BUF0, BUF2, n1g0, n1b0, BUF1);
  ln_kernel<2><<<RR, 256, 0, stream>>>(BUF1, nullptr, n2g0, n2b0, BUF0);

  // ---- h_res copy, cls ffn, moe ----
  copy_kernel<<<elem_grid, 256, 0, stream>>>(BUF0, BUF2);
  cls_ffn_kernel<<<Bb, 256, 0, stream>>>(BUF0, cw1, cb1, clg, clb, cw2, cb2, BUF2);
  gate_kernel<<<NTOK / 4, 256, 0, stream>>>(BUF0, gate_w, out, TOPP, IDX);
  route_kernel<<<dim3(Ee, Bb), 256, 0, stream>>>(IDX, LIST, CNT);
  moe_mgemm1_kernel<<<dim3(6, 16, Ee), 256, 0, stream>>>(BUF0, ew1, eb1, LIST, CNT, BIG);
  moe_mgemm2_kernel<<<dim3(6, 4, Ee), 256, 0, stream>>>(BIG, ew2, eb2, LIST, CNT, TOPP, BUF2);
  loss_part_kernel<<<16, 256, 0, stream>>>(out, LBL, PART);
  loss_final_kernel<<<1, 64, 0, stream>>>(PART, out);

  // ---- layer 1 attention ----
  mgemm_kernel<true, false><<<dim3(33, 12), 256, 0, stream>>>(
      BUF2, Dd, a1_in_w, Dd, a1_in_b, nullptr, BIG, 3 * Dd, RR, 3 * Dd, Dd);
  attn_mfma_kernel<<<dim3(33, Hh, Bb), 256, 0, stream>>>(BIG, BUF1);
  mgemm_kernel<true, false><<<dim3(33, 4), 256, 0, stream>>>(
      BUF1, Dd, a1_out_w, Dd, a1_out_b, nullptr, BUF0, Dd, RR, Dd, Dd);
  ln_kernel<2><<<RR, 256, 0, stream>>>(BUF2, BUF0, n1g1, n1b1, BUF1);
  ln_kernel<2><<<RR, 256, 0, stream>>>(BUF1, nullptr, n2g1, n2b1, BUF2);

  // ---- layer 1 FFN (sub-LN) with residual ----
  mgemm_kernel<false, true><<<dim3(33, 16), 256, 0, stream>>>(
      BUF2, Dd, fw1, FF, fb1, nullptr, BIG, FF, RR, FF, Dd);
  ln_kernel<8><<<RR, 256, 0, stream>>>(BIG, nullptr, flg, flb, BIG);
  mgemm_kernel<false, false><<<dim3(33, 4), 256, 0, stream>>>(
      BIG, FF, fw2, Dd, fb2, BUF2, BUF0, Dd, RR, Dd, FF);

  // ---- head ----
  final_head_kernel<<<Bb, 256, 0, stream>>>(BUF0, ng, nb, fc2_w, fc2_b, out);
}

// Round 4
// 944.379 us; speedup vs baseline: 4.9770x; 1.1708x over previous
//
#include <hip/hip_runtime.h>
#include <cmath>

#define DEVINL __device__ __forceinline__

constexpr int Bb   = 2;
constexpr int Ss   = 2048;
constexpr int S1   = 2049;
constexpr int DIN  = 1024;
constexpr int Dd   = 512;
constexpr int Hh   = 8;
constexpr int FF   = 2048;
constexpr int Ee   = 6;
constexpr int NCc  = 2;
constexpr int CAP  = 341;
constexpr int NTOK = Bb * Ss;     // 4096
constexpr int RR   = Bb * S1;     // 4098
constexpr int MOE_ROWS = Bb * CAP; // 682

typedef __attribute__((ext_vector_type(4))) float f32x4;
typedef __attribute__((ext_vector_type(8))) short bf16x8;

DEVINL float geluf(float x) { return 0.5f * x * (1.0f + erff(x * 0.7071067811865476f)); }

DEVINL unsigned short f2bf(float f) {
  unsigned int u = __float_as_uint(f);
  u += 0x7FFFu + ((u >> 16) & 1u);
  return (unsigned short)(u >> 16);
}

DEVINL float wsum(float v) {
#pragma unroll
  for (int off = 32; off; off >>= 1) v += __shfl_xor(v, off);
  return v;
}
// block=256 reduction, broadcast result to all threads
DEVINL float bsum(float v, float* red) {
  v = wsum(v);
  int w = threadIdx.x >> 6;
  if ((threadIdx.x & 63) == 0) red[w] = v;
  __syncthreads();
  float r = red[0] + red[1] + red[2] + red[3];
  __syncthreads();
  return r;
}

// ---------------- labels: cosine-sim argmax over 4 protos -------------------
__global__ __launch_bounds__(256) void labels_kernel(const float* __restrict__ x,
                                                     const float* __restrict__ protos,
                                                     int* __restrict__ lbl) {
  int t = blockIdx.x * 4 + (threadIdx.x >> 6);
  int lane = threadIdx.x & 63;
  if (t >= NTOK) return;
  const float* xr = x + (size_t)t * DIN;
  float xv[16];
  float ss = 0.f;
#pragma unroll
  for (int i = 0; i < 16; ++i) { xv[i] = xr[lane + 64 * i]; ss += xv[i] * xv[i]; }
  ss = wsum(ss);
  float nx = sqrtf(ss) + 1e-8f;
  float best = -2e30f; int bi = 0;
  for (int p = 0; p < 4; ++p) {
    const float* pr = protos + (size_t)p * DIN;
    float dp = 0.f, pp = 0.f;
#pragma unroll
    for (int i = 0; i < 16; ++i) { float v = pr[lane + 64 * i]; dp += v * xv[i]; pp += v * v; }
    dp = wsum(dp); pp = wsum(pp);
    float sim = dp / (nx * (sqrtf(pp) + 1e-8f));
    if (sim > best) { best = sim; bi = p; }
  }
  if (lane == 0) lbl[t] = bi;
}

// ================= bf16 MFMA GEMM =========================================
// C(MxN) = act(A@op(B) + bias) [+ res].  A fp32 MxK row-major (bf16-converted
// on stage).  BT=0: B is KxN row-major; BT=1: B is NxK row-major.
// Tile 128x128x64, 4 waves (2x2), each wave 64x64 via 4x4 frags of 16x16x32.
// LDS: As[m][k], Bs[n][k], 128B rows, XOR swizzle byte^=(row&7)<<4 (G4).
template <bool BT, bool ACT>
__global__ __launch_bounds__(256) void mgemm_kernel(const float* __restrict__ A, int lda,
                                                    const float* __restrict__ Bw, int ldb,
                                                    const float* __restrict__ bias,
                                                    const float* __restrict__ res,
                                                    float* __restrict__ C, int ldc,
                                                    int M, int N, int K) {
  __shared__ unsigned short As[128 * 64];
  __shared__ unsigned short Bs[128 * 64];
  const int tid = threadIdx.x;
  const int l = tid & 63, l15 = l & 15, lg = l >> 4;
  const int wm = (tid >> 7), wn = (tid >> 6) & 1;
  const int bm = blockIdx.x * 128, bn = blockIdx.y * 128;

  f32x4 acc[4][4];
#pragma unroll
  for (int i = 0; i < 4; ++i)
#pragma unroll
    for (int j = 0; j < 4; ++j) acc[i][j] = (f32x4){0.f, 0.f, 0.f, 0.f};

  const int ar = tid >> 1, ac = (tid & 1) * 32;       // A/B(T) staging: row, col-chunk
  const int bkp = (tid & 31) * 2, bnc = (tid >> 5) * 16; // B(KxN) staging

  for (int k0 = 0; k0 < K; k0 += 64) {
    // ---- stage A (fp32 -> bf16) ----
    {
      float f[32];
      if (bm + ar < M) {
        const float* ap = A + (size_t)(bm + ar) * lda + k0 + ac;
#pragma unroll
        for (int i = 0; i < 8; ++i) *(float4*)&f[i * 4] = *(const float4*)(ap + i * 4);
      } else {
#pragma unroll
        for (int i = 0; i < 32; ++i) f[i] = 0.f;
      }
      const int rswz = (ar & 7) << 4;
#pragma unroll
      for (int i = 0; i < 4; ++i) {
        bf16x8 v;
#pragma unroll
        for (int j = 0; j < 8; ++j) v[j] = (short)f2bf(f[i * 8 + j]);
        *(bf16x8*)((char*)As + ((ar * 128 + (ac + i * 8) * 2) ^ rswz)) = v;
      }
    }
    // ---- stage B ----
    if (BT) {
      float f[32];
      const float* bp = Bw + (size_t)(bn + ar) * ldb + k0 + ac;
#pragma unroll
      for (int i = 0; i < 8; ++i) *(float4*)&f[i * 4] = *(const float4*)(bp + i * 4);
      const int rswz = (ar & 7) << 4;
#pragma unroll
      for (int i = 0; i < 4; ++i) {
        bf16x8 v;
#pragma unroll
        for (int j = 0; j < 8; ++j) v[j] = (short)f2bf(f[i * 8 + j]);
        *(bf16x8*)((char*)Bs + ((ar * 128 + (ac + i * 8) * 2) ^ rswz)) = v;
      }
    } else {
      const float* bp = Bw + (size_t)(k0 + bkp) * ldb + bn + bnc;
      float fa[16], fb[16];
#pragma unroll
      for (int i = 0; i < 4; ++i) {
        *(float4*)&fa[i * 4] = *(const float4*)(bp + i * 4);
        *(float4*)&fb[i * 4] = *(const float4*)(bp + ldb + i * 4);
      }
#pragma unroll
      for (int i = 0; i < 16; ++i) {
        unsigned int pk = (unsigned int)f2bf(fa[i]) | ((unsigned int)f2bf(fb[i]) << 16);
        int n = bnc + i;
        *(unsigned int*)((char*)Bs + ((n * 128 + bkp * 2) ^ ((n & 7) << 4))) = pk;
      }
    }
    __syncthreads();

#pragma unroll
    for (int kc = 0; kc < 2; ++kc) {
      bf16x8 af[4], bfr[4];
#pragma unroll
      for (int mi = 0; mi < 4; ++mi) {
        int row = wm * 64 + mi * 16 + l15;
        af[mi] = *(const bf16x8*)((const char*)As +
                   ((row * 128 + (kc * 32 + lg * 8) * 2) ^ ((row & 7) << 4)));
      }
#pragma unroll
      for (int ni = 0; ni < 4; ++ni) {
        int row = wn * 64 + ni * 16 + l15;
        bfr[ni] = *(const bf16x8*)((const char*)Bs +
                   ((row * 128 + (kc * 32 + lg * 8) * 2) ^ ((row & 7) << 4)));
      }
#pragma unroll
      for (int mi = 0; mi < 4; ++mi)
#pragma unroll
        for (int ni = 0; ni < 4; ++ni)
          acc[mi][ni] = __builtin_amdgcn_mfma_f32_16x16x32_bf16(af[mi], bfr[ni], acc[mi][ni], 0, 0, 0);
    }
    __syncthreads();
  }

  // ---- epilogue ----
#pragma unroll
  for (int mi = 0; mi < 4; ++mi)
#pragma unroll
    for (int r = 0; r < 4; ++r) {
      int row = bm + wm * 64 + mi * 16 + lg * 4 + r;
      if (row < M) {
#pragma unroll
        for (int ni = 0; ni < 4; ++ni) {
          int col = bn + wn * 64 + ni * 16 + l15;
          float t = acc[mi][ni][r];
          if (bias) t += bias[col];
          if (ACT) t = geluf(t);
          if (res) t += res[(size_t)row * ldc + col];
          C[(size_t)row * ldc + col] = t;
        }
      }
    }
}

// ---- MoE variant 1: gathered-A GEMM, hid = gelu(h2[tok] @ w1[e] + b1[e]) ----
__global__ __launch_bounds__(256) void moe_mgemm1_kernel(const float* __restrict__ h2,
                                                         const float* __restrict__ w1all,
                                                         const float* __restrict__ b1all,
                                                         const int* __restrict__ list,
                                                         const int* __restrict__ cnt,
                                                         float* __restrict__ hid) {
  __shared__ unsigned short As[128 * 64];
  __shared__ unsigned short Bs[128 * 64];
  const int e = blockIdx.z;
  const int c0 = cnt[e * 2 + 0], c1 = cnt[e * 2 + 1];
  const float* Bw = w1all + (size_t)e * Dd * FF;
  const int tid = threadIdx.x;
  const int l = tid & 63, l15 = l & 15, lg = l >> 4;
  const int wm = (tid >> 7), wn = (tid >> 6) & 1;
  const int bm = blockIdx.x * 128, bn = blockIdx.y * 128;

  f32x4 acc[4][4];
#pragma unroll
  for (int i = 0; i < 4; ++i)
#pragma unroll
    for (int j = 0; j < 4; ++j) acc[i][j] = (f32x4){0.f, 0.f, 0.f, 0.f};

  const int ar = tid >> 1, ac = (tid & 1) * 32;
  const int bkp = (tid & 31) * 2, bnc = (tid >> 5) * 16;

  int r = bm + ar;
  bool aval = (r < MOE_ROWS) && ((r < CAP) ? (r < c0) : ((r - CAP) < c1));
  size_t abase = 0;
  if (aval) {
    int tok = list[e * MOE_ROWS + r];
    int b = tok >> 11, s = tok & (Ss - 1);
    abase = (size_t)(b * S1 + s + 1) * Dd;
  }

  for (int k0 = 0; k0 < Dd; k0 += 64) {
    {
      float f[32];
      if (aval) {
        const float* ap = h2 + abase + k0 + ac;
#pragma unroll
        for (int i = 0; i < 8; ++i) *(float4*)&f[i * 4] = *(const float4*)(ap + i * 4);
      } else {
#pragma unroll
        for (int i = 0; i < 32; ++i) f[i] = 0.f;
      }
      const int rswz = (ar & 7) << 4;
#pragma unroll
      for (int i = 0; i < 4; ++i) {
        bf16x8 v;
#pragma unroll
        for (int j = 0; j < 8; ++j) v[j] = (short)f2bf(f[i * 8 + j]);
        *(bf16x8*)((char*)As + ((ar * 128 + (ac + i * 8) * 2) ^ rswz)) = v;
      }
    }
    {
      const float* bp = Bw + (size_t)(k0 + bkp) * FF + bn + bnc;
      float fa[16], fb[16];
#pragma unroll
      for (int i = 0; i < 4; ++i) {
        *(float4*)&fa[i * 4] = *(const float4*)(bp + i * 4);
        *(float4*)&fb[i * 4] = *(const float4*)(bp + FF + i * 4);
      }
#pragma unroll
      for (int i = 0; i < 16; ++i) {
        unsigned int pk = (unsigned int)f2bf(fa[i]) | ((unsigned int)f2bf(fb[i]) << 16);
        int n = bnc + i;
        *(unsigned int*)((char*)Bs + ((n * 128 + bkp * 2) ^ ((n & 7) << 4))) = pk;
      }
    }
    __syncthreads();
#pragma unroll
    for (int kc = 0; kc < 2; ++kc) {
      bf16x8 af[4], bfr[4];
#pragma unroll
      for (int mi = 0; mi < 4; ++mi) {
        int row = wm * 64 + mi * 16 + l15;
        af[mi] = *(const bf16x8*)((const char*)As +
                   ((row * 128 + (kc * 32 + lg * 8) * 2) ^ ((row & 7) << 4)));
      }
#pragma unroll
      for (int ni = 0; ni < 4; ++ni) {
        int row = wn * 64 + ni * 16 + l15;
        bfr[ni] = *(const bf16x8*)((const char*)Bs +
                   ((row * 128 + (kc * 32 + lg * 8) * 2) ^ ((row & 7) << 4)));
      }
#pragma unroll
      for (int mi = 0; mi < 4; ++mi)
#pragma unroll
        for (int ni = 0; ni < 4; ++ni)
          acc[mi][ni] = __builtin_amdgcn_mfma_f32_16x16x32_bf16(af[mi], bfr[ni], acc[mi][ni], 0, 0, 0);
    }
    __syncthreads();
  }

#pragma unroll
  for (int mi = 0; mi < 4; ++mi)
#pragma unroll
    for (int rr = 0; rr < 4; ++rr) {
      int row = bm + wm * 64 + mi * 16 + lg * 4 + rr;
      bool v2 = (row < MOE_ROWS) && ((row < CAP) ? (row < c0) : ((row - CAP) < c1));
      if (v2) {
#pragma unroll
        for (int ni = 0; ni < 4; ++ni) {
          int col = bn + wn * 64 + ni * 16 + l15;
          hid[((size_t)e * MOE_ROWS + row) * FF + col] =
              geluf(acc[mi][ni][rr] + b1all[e * FF + col]);
        }
      }
    }
}

// ---- MoE variant 2: out[tok] += topp * (hid @ w2[e] + b2[e]) ----------------
__global__ __launch_bounds__(256) void moe_mgemm2_kernel(const float* __restrict__ hid,
                                                         const float* __restrict__ w2all,
                                                         const float* __restrict__ b2all,
                                                         const int* __restrict__ list,
                                                         const int* __restrict__ cnt,
                                                         const float* __restrict__ topp,
                                                         float* __restrict__ out) {
  __shared__ unsigned short As[128 * 64];
  __shared__ unsigned short Bs[128 * 64];
  const int e = blockIdx.z;
  const int c0 = cnt[e * 2 + 0], c1 = cnt[e * 2 + 1];
  const float* Bw = w2all + (size_t)e * FF * Dd;
  const int tid = threadIdx.x;
  const int l = tid & 63, l15 = l & 15, lg = l >> 4;
  const int wm = (tid >> 7), wn = (tid >> 6) & 1;
  const int bm = blockIdx.x * 128, bn = blockIdx.y * 128;

  f32x4 acc[4][4];
#pragma unroll
  for (int i = 0; i < 4; ++i)
#pragma unroll
    for (int j = 0; j < 4; ++j) acc[i][j] = (f32x4){0.f, 0.f, 0.f, 0.f};

  const int ar = tid >> 1, ac = (tid & 1) * 32;
  const int bkp = (tid & 31) * 2, bnc = (tid >> 5) * 16;

  int r = bm + ar;
  bool aval = (r < MOE_ROWS) && ((r < CAP) ? (r < c0) : ((r - CAP) < c1));
  size_t abase = ((size_t)e * MOE_ROWS + r) * FF;

  for (int k0 = 0; k0 < FF; k0 += 64) {
    {
      float f[32];
      if (aval) {
        const float* ap = hid + abase + k0 + ac;
#pragma unroll
        for (int i = 0; i < 8; ++i) *(float4*)&f[i * 4] = *(const float4*)(ap + i * 4);
      } else {
#pragma unroll
        for (int i = 0; i < 32; ++i) f[i] = 0.f;
      }
      const int rswz = (ar & 7) << 4;
#pragma unroll
      for (int i = 0; i < 4; ++i) {
        bf16x8 v;
#pragma unroll
        for (int j = 0; j < 8; ++j) v[j] = (short)f2bf(f[i * 8 + j]);
        *(bf16x8*)((char*)As + ((ar * 128 + (ac + i * 8) * 2) ^ rswz)) = v;
      }
    }
    {
      const float* bp = Bw + (size_t)(k0 + bkp) * Dd + bn + bnc;
      float fa[16], fb[16];
#pragma unroll
      for (int i = 0; i < 4; ++i) {
        *(float4*)&fa[i * 4] = *(const float4*)(bp + i * 4);
        *(float4*)&fb[i * 4] = *(const float4*)(bp + Dd + i * 4);
      }
#pragma unroll
      for (int i = 0; i < 16; ++i) {
        unsigned int pk = (unsigned int)f2bf(fa[i]) | ((unsigned int)f2bf(fb[i]) << 16);
        int n = bnc + i;
        *(unsigned int*)((char*)Bs + ((n * 128 + bkp * 2) ^ ((n & 7) << 4))) = pk;
      }
    }
    __syncthreads();
#pragma unroll
    for (int kc = 0; kc < 2; ++kc) {
      bf16x8 af[4], bfr[4];
#pragma unroll
      for (int mi = 0; mi < 4; ++mi) {
        int row = wm * 64 + mi * 16 + l15;
        af[mi] = *(const bf16x8*)((const char*)As +
                   ((row * 128 + (kc * 32 + lg * 8) * 2) ^ ((row & 7) << 4)));
      }
#pragma unroll
      for (int ni = 0; ni < 4; ++ni) {
        int row = wn * 64 + ni * 16 + l15;
        bfr[ni] = *(const bf16x8*)((const char*)Bs +
                   ((row * 128 + (kc * 32 + lg * 8) * 2) ^ ((row & 7) << 4)));
      }
#pragma unroll
      for (int mi = 0; mi < 4; ++mi)
#pragma unroll
        for (int ni = 0; ni < 4; ++ni)
          acc[mi][ni] = __builtin_amdgcn_mfma_f32_16x16x32_bf16(af[mi], bfr[ni], acc[mi][ni], 0, 0, 0);
    }
    __syncthreads();
  }

#pragma unroll
  for (int mi = 0; mi < 4; ++mi)
#pragma unroll
    for (int rr = 0; rr < 4; ++rr) {
      int row = bm + wm * 64 + mi * 16 + lg * 4 + rr;
      bool v2 = (row < MOE_ROWS) && ((row < CAP) ? (row < c0) : ((row - CAP) < c1));
      if (v2) {
        int tok = list[e * MOE_ROWS + row];
        int b = tok >> 11, s = tok & (Ss - 1);
        float tp = topp[tok];
#pragma unroll
        for (int ni = 0; ni < 4; ++ni) {
          int col = bn + wn * 64 + ni * 16 + l15;
          size_t oidx = (size_t)(b * S1 + s + 1) * Dd + col;
          out[oidx] += tp * (acc[mi][ni][rr] + b2all[e * Dd + col]);
        }
      }
    }
}

// ---------------- assemble h = concat(cls, fc1_out) -------------------------
__global__ __launch_bounds__(256) void assemble_kernel(const float* __restrict__ fc1out,
                                                       const float* __restrict__ cls,
                                                       float* __restrict__ h) {
  size_t i = (size_t)blockIdx.x * 256 + threadIdx.x;
  if (i >= (size_t)RR * Dd) return;
  int r = (int)(i >> 9), d = (int)(i & 511);
  int b = r / S1, sl = r - b * S1;
  float v = (sl == 0) ? cls[d] : fc1out[((size_t)(b * Ss + sl - 1) << 9) + d];
  h[i] = v;
}

// ---------------- LayerNorm (optionally + add; optional dual write) ---------
template <int NPT>
__global__ __launch_bounds__(256) void ln_kernel(const float* __restrict__ in,
                                                 const float* __restrict__ addv,
                                                 const float* __restrict__ g,
                                                 const float* __restrict__ bvec,
                                                 float* __restrict__ out,
                                                 float* __restrict__ out2) {
  constexpr int N = NPT * 256;
  __shared__ float red[8];
  size_t base = (size_t)blockIdx.x * N;
  int tid = threadIdx.x;
  float x[NPT];
  float s1 = 0.f, s2 = 0.f;
#pragma unroll
  for (int j = 0; j < NPT; ++j) {
    x[j] = in[base + tid + j * 256];
    s1 += x[j]; s2 += x[j] * x[j];
  }
  s1 = bsum(s1, red);
  s2 = bsum(s2, red);
  float mean = s1 * (1.0f / N);
  float var = s2 * (1.0f / N) - mean * mean;
  float rstd = rsqrtf(var + 1e-5f);
#pragma unroll
  for (int j = 0; j < NPT; ++j) {
    int col = tid + j * 256;
    float v = (x[j] - mean) * rstd * g[col] + bvec[col];
    if (addv) v += addv[base + col];
    out[base + col] = v;
    if (out2) out2[base + col] = v;
  }
}

// ---------------- MFMA bf16 flash attention ---------------------------------
__global__ __launch_bounds__(256) void attn_mfma_kernel(const float* __restrict__ qkv,
                                                        float* __restrict__ o) {
  __shared__ unsigned short Ksh[64 * 64];   // [k][d], XOR-swizzled by (k&7)<<4
  __shared__ unsigned short Vt[64 * 64];    // [d][k], XOR-swizzled by (d&7)<<4
  __shared__ unsigned short Psh[4 * 16 * 64]; // per-wave [q][k], swizzled by (q&7)<<4
  const int tid = threadIdx.x;
  const int w = tid >> 6, l = tid & 63;
  const int l15 = l & 15, lg = l >> 4;
  const int hh = blockIdx.y, b = blockIdx.z;
  const int qblk = blockIdx.x * 64;
  const size_t rbase = (size_t)b * S1 * 1536;

  bf16x8 aq[2];
  {
    int qr = qblk + w * 16 + l15;
    bool qv = qr < S1;
    const float* qp = qkv + rbase + (size_t)qr * 1536 + hh * 64;
#pragma unroll
    for (int dc = 0; dc < 2; ++dc) {
      float f[8];
      if (qv) {
        *(float4*)&f[0] = *(const float4*)(qp + dc * 32 + lg * 8);
        *(float4*)&f[4] = *(const float4*)(qp + dc * 32 + lg * 8 + 4);
      } else {
#pragma unroll
        for (int j = 0; j < 8; ++j) f[j] = 0.f;
      }
#pragma unroll
      for (int j = 0; j < 8; ++j) aq[dc][j] = (short)f2bf(f[j] * 0.125f);
    }
  }

  f32x4 ovac[4];
#pragma unroll
  for (int dt = 0; dt < 4; ++dt) ovac[dt] = (f32x4){0.f, 0.f, 0.f, 0.f};
  float m_r[4], l_r[4];
#pragma unroll
  for (int r = 0; r < 4; ++r) { m_r[r] = -1e30f; l_r[r] = 0.f; }

  const int sk_k = tid >> 2, sk_d0 = (tid & 3) * 16;
  const int sv_k0 = (tid & 31) * 2, sv_d0 = (tid >> 5) * 8;

  for (int c = 0; c < 33; ++c) {
    {
      int key = c * 64 + sk_k;
      float f[16];
      if (key < S1) {
        const float* kp = qkv + rbase + (size_t)key * 1536 + 512 + hh * 64 + sk_d0;
        *(float4*)&f[0]  = *(const float4*)(kp + 0);
        *(float4*)&f[4]  = *(const float4*)(kp + 4);
        *(float4*)&f[8]  = *(const float4*)(kp + 8);
        *(float4*)&f[12] = *(const float4*)(kp + 12);
      } else {
#pragma unroll
        for (int j = 0; j < 16; ++j) f[j] = 0.f;
      }
      bf16x8 lo, hi;
#pragma unroll
      for (int j = 0; j < 8; ++j) { lo[j] = (short)f2bf(f[j]); hi[j] = (short)f2bf(f[8 + j]); }
      const int rswz = (sk_k & 7) << 4;
      *(bf16x8*)((char*)Ksh + (((sk_k * 64 + sk_d0) * 2) ^ rswz)) = lo;
      *(bf16x8*)((char*)Ksh + (((sk_k * 64 + sk_d0 + 8) * 2) ^ rswz)) = hi;
    }
    {
      int key0 = c * 64 + sv_k0;
      const float* vp = qkv + rbase + (size_t)key0 * 1536 + 1024 + hh * 64 + sv_d0;
      float fa[8], fb[8];
      if (key0 < S1) {
        *(float4*)&fa[0] = *(const float4*)(vp);
        *(float4*)&fa[4] = *(const float4*)(vp + 4);
      } else {
#pragma unroll
        for (int j = 0; j < 8; ++j) fa[j] = 0.f;
      }
      if (key0 + 1 < S1) {
        *(float4*)&fb[0] = *(const float4*)(vp + 1536);
        *(float4*)&fb[4] = *(const float4*)(vp + 1536 + 4);
      } else {
#pragma unroll
        for (int j = 0; j < 8; ++j) fb[j] = 0.f;
      }
#pragma unroll
      for (int i = 0; i < 8; ++i) {
        unsigned int pk = (unsigned int)f2bf(fa[i]) | ((unsigned int)f2bf(fb[i]) << 16);
        int d = sv_d0 + i;
        *(unsigned int*)((char*)Vt + (((d * 64 + sv_k0) * 2) ^ ((d & 7) << 4))) = pk;
      }
    }
    __syncthreads();

    f32x4 s[4];
#pragma unroll
    for (int kt = 0; kt < 4; ++kt) {
      f32x4 acc = (f32x4){0.f, 0.f, 0.f, 0.f};
      const int krow = kt * 16 + l15;
      const int rswz = (krow & 7) << 4;
#pragma unroll
      for (int dc = 0; dc < 2; ++dc) {
        bf16x8 kb = *(const bf16x8*)((const char*)Ksh + (((krow * 64 + dc * 32 + lg * 8) * 2) ^ rswz));
        acc = __builtin_amdgcn_mfma_f32_16x16x32_bf16(aq[dc], kb, acc, 0, 0, 0);
      }
      if (c * 64 + kt * 16 + l15 >= S1) acc = (f32x4){-1e30f, -1e30f, -1e30f, -1e30f};
      s[kt] = acc;
    }

    float mx[4];
#pragma unroll
    for (int r = 0; r < 4; ++r)
      mx[r] = fmaxf(fmaxf(s[0][r], s[1][r]), fmaxf(s[2][r], s[3][r]));
#pragma unroll
    for (int off = 1; off < 16; off <<= 1)
#pragma unroll
      for (int r = 0; r < 4; ++r) mx[r] = fmaxf(mx[r], __shfl_xor(mx[r], off));
    float fac[4], rs[4];
#pragma unroll
    for (int r = 0; r < 4; ++r) {
      float mn = fmaxf(m_r[r], mx[r]);
      fac[r] = __expf(m_r[r] - mn);
      m_r[r] = mn;
      rs[r] = 0.f;
    }
#pragma unroll
    for (int kt = 0; kt < 4; ++kt)
#pragma unroll
      for (int r = 0; r < 4; ++r) {
        float p = __expf(s[kt][r] - m_r[r]);
        s[kt][r] = p;
        rs[r] += p;
      }
#pragma unroll
    for (int off = 1; off < 16; off <<= 1)
#pragma unroll
      for (int r = 0; r < 4; ++r) rs[r] += __shfl_xor(rs[r], off);
#pragma unroll
    for (int r = 0; r < 4; ++r) l_r[r] = l_r[r] * fac[r] + rs[r];

    {
      char* pb = (char*)Psh + w * 2048;
#pragma unroll
      for (int kt = 0; kt < 4; ++kt)
#pragma unroll
        for (int r = 0; r < 4; ++r) {
          int q = lg * 4 + r;
          *(unsigned short*)(pb + (((q * 64 + kt * 16 + l15) * 2) ^ ((q & 7) << 4))) =
              f2bf(s[kt][r]);
        }
    }

#pragma unroll
    for (int dt = 0; dt < 4; ++dt)
#pragma unroll
      for (int r = 0; r < 4; ++r) ovac[dt][r] *= fac[r];

    {
      const char* pb = (const char*)Psh + w * 2048;
      const int pswz = (l15 & 7) << 4;
#pragma unroll
      for (int kh = 0; kh < 2; ++kh) {
        bf16x8 pa = *(const bf16x8*)(pb + (((l15 * 64 + kh * 32 + lg * 8) * 2) ^ pswz));
#pragma unroll
        for (int dt = 0; dt < 4; ++dt) {
          bf16x8 vb = *(const bf16x8*)((const char*)Vt +
                        ((((dt * 16 + l15) * 64 + kh * 32 + lg * 8) * 2) ^ pswz));
          ovac[dt] = __builtin_amdgcn_mfma_f32_16x16x32_bf16(pa, vb, ovac[dt], 0, 0, 0);
        }
      }
    }
    __syncthreads();
  }

  float inv[4];
#pragma unroll
  for (int r = 0; r < 4; ++r) inv[r] = 1.0f / l_r[r];
#pragma unroll
  for (int r = 0; r < 4; ++r) {
    int qq = qblk + w * 16 + lg * 4 + r;
    if (qq < S1) {
      float* orow = o + (size_t)(b * S1 + qq) * Dd + hh * 64;
#pragma unroll
      for (int dt = 0; dt < 4; ++dt) orow[dt * 16 + l15] = ovac[dt][r] * inv[r];
    }
  }
}

// ---------------- gate softmax + top1 routing info --------------------------
__global__ __launch_bounds__(256) void gate_kernel(const float* __restrict__ h2,
                                                   const float* __restrict__ gw,
                                                   float* __restrict__ gate_out,
                                                   float* __restrict__ topp,
                                                   int* __restrict__ idx) {
  int t = blockIdx.x * 4 + (threadIdx.x >> 6);
  int lane = threadIdx.x & 63;
  if (t >= NTOK) return;
  int b = t >> 11, s = t & (Ss - 1);
  const float* hr = h2 + (size_t)(b * S1 + s + 1) * Dd;
  float acc[6] = {};
#pragma unroll
  for (int i = 0; i < 8; ++i) {
    int d = lane + i * 64;
    float xv = hr[d];
    const float* g = gw + (size_t)d * Ee;
#pragma unroll
    for (int e = 0; e < 6; ++e) acc[e] += xv * g[e];
  }
#pragma unroll
  for (int e = 0; e < 6; ++e) acc[e] = wsum(acc[e]);
  if (lane == 0) {
    float mx = acc[0];
#pragma unroll
    for (int e = 1; e < 6; ++e) mx = fmaxf(mx, acc[e]);
    float ex[6], sum = 0.f;
#pragma unroll
    for (int e = 0; e < 6; ++e) { ex[e] = __expf(acc[e] - mx); sum += ex[e]; }
    float invs = 1.0f / sum;
    int best = 0; float bp = ex[0];
#pragma unroll
    for (int e = 1; e < 6; ++e) { if (ex[e] > bp) { bp = ex[e]; best = e; } }
#pragma unroll
    for (int e = 0; e < 6; ++e) gate_out[(size_t)t * Ee + e] = ex[e] * invs;
    topp[t] = bp * invs;
    idx[t] = best;
  }
}

// ---------------- capacity-limited top-1 router (parallel scan) -------------
__global__ __launch_bounds__(256) void route_kernel(const int* __restrict__ idx,
                                                    int* __restrict__ list,
                                                    int* __restrict__ cnt) {
  __shared__ int cnts[256];
  __shared__ int tot;
  const int e = blockIdx.x, b = blockIdx.y;
  const int tid = threadIdx.x;
  const int s0 = tid * 8;
  int loc[8];
  int c = 0;
#pragma unroll
  for (int j = 0; j < 8; ++j) {
    int t = b * Ss + s0 + j;
    if (idx[t] == e) loc[c++] = t;
  }
  cnts[tid] = c;
  __syncthreads();
  if (tid == 0) {
    int run = 0;
    for (int i = 0; i < 256; ++i) { int v = cnts[i]; cnts[i] = run; run += v; }
    tot = run;
  }
  __syncthreads();
  int base = cnts[tid];
  for (int j = 0; j < c; ++j) {
    int pos = base + j;
    if (pos < CAP) list[e * MOE_ROWS + b * CAP + pos] = loc[j];
  }
  if (tid == 0) cnt[e * Bb + b] = (tot < CAP) ? tot : CAP;
}

// ---------------- cls-token sub-LN FFN, parallelized over columns -----------
// Phase 1: chid[b][col] = gelu(h_cls[b] @ w1[:,col] + b1[col]); grid (FF/256, Bb)
__global__ __launch_bounds__(256) void cls_ffn1_kernel(const float* __restrict__ h2,
                                                       const float* __restrict__ w1,
                                                       const float* __restrict__ b1,
                                                       float* __restrict__ chid) {
  __shared__ float hrow[Dd];
  const int b = blockIdx.y, tid = threadIdx.x;
  const int col = blockIdx.x * 256 + tid;
  const float* hr = h2 + (size_t)(b * S1) * Dd;
  hrow[tid] = hr[tid];
  hrow[tid + 256] = hr[tid + 256];
  __syncthreads();
  float acc = b1[col];
  for (int d = 0; d < Dd; ++d) acc += hrow[d] * w1[(size_t)d * FF + col];
  chid[b * FF + col] = geluf(acc);
}

// Phase 2: LN(chid[b]) then out[b*S1][col] += LN @ w2[:,col] + b2[col]; grid (Dd/256, Bb)
__global__ __launch_bounds__(256) void cls_ffn2_kernel(const float* __restrict__ chid,
                                                       const float* __restrict__ lg,
                                                       const float* __restrict__ lb,
                                                       const float* __restrict__ w2,
                                                       const float* __restrict__ b2,
                                                       float* __restrict__ outbuf) {
  __shared__ float hln[FF];
  __shared__ float red[8];
  const int b = blockIdx.y, tid = threadIdx.x;
  const int col = blockIdx.x * 256 + tid;
  const float* hr = chid + b * FF;
  float hv[8];
  float s1 = 0.f, s2 = 0.f;
#pragma unroll
  for (int j = 0; j < 8; ++j) {
    hv[j] = hr[tid + j * 256];
    s1 += hv[j]; s2 += hv[j] * hv[j];
  }
  s1 = bsum(s1, red);
  s2 = bsum(s2, red);
  float mean = s1 * (1.0f / FF);
  float var = s2 * (1.0f / FF) - mean * mean;
  float rstd = rsqrtf(var + 1e-5f);
#pragma unroll
  for (int j = 0; j < 8; ++j) {
    int k = tid + j * 256;
    hln[k] = (hv[j] - mean) * rstd * lg[k] + lb[k];
  }
  __syncthreads();
  float acc = b2[col];
  for (int k = 0; k < FF; ++k) acc += hln[k] * w2[(size_t)k * Dd + col];
  outbuf[(size_t)(b * S1) * Dd + col] += acc;
}

// ---------------- loss ------------------------------------------------------
__global__ __launch_bounds__(256) void loss_part_kernel(const float* __restrict__ gate,
                                                        const int* __restrict__ lbl,
                                                        float* __restrict__ part) {
  __shared__ float red[8];
  int t = blockIdx.x * 256 + threadIdx.x;
  float v = 0.f;
  if (t < NTOK) {
    const float* p = gate + (size_t)t * Ee;
    float sum = p[0] + p[1] + p[2] + p[3];
    float pl = p[lbl[t]];
    v = -logf(pl / sum + 1e-9f);
  }
  v = bsum(v, red);
  if (threadIdx.x == 0) part[blockIdx.x] = v;
}

__global__ void loss_final_kernel(const float* __restrict__ part, float* __restrict__ out) {
  if (threadIdx.x == 0) {
    float s = 0.f;
    for (int i = 0; i < 16; ++i) s += part[i];
    out[NTOK * Ee + Bb * NCc] = s / (float)NTOK;
  }
}

// ---------------- final LN + logits ----------------------------------------
__global__ __launch_bounds__(256) void final_head_kernel(const float* __restrict__ h,
                                                         const float* __restrict__ g,
                                                         const float* __restrict__ bvec,
                                                         const float* __restrict__ w,
                                                         const float* __restrict__ fb,
                                                         float* __restrict__ out) {
  __shared__ float red[8];
  int b = blockIdx.x, tid = threadIdx.x;
  const float* hr = h + (size_t)(b * S1) * Dd;
  float x0 = hr[tid], x1 = hr[tid + 256];
  float s1 = bsum(x0 + x1, red);
  float s2 = bsum(x0 * x0 + x1 * x1, red);
  float mean = s1 * (1.0f / Dd);
  float var = s2 * (1.0f / Dd) - mean * mean;
  float rstd = rsqrtf(var + 1e-5f);
  float p0 = (x0 - mean) * rstd * g[tid] + bvec[tid];
  float p1 = (x1 - mean) * rstd * g[tid + 256] + bvec[tid + 256];
  float l0 = p0 * w[tid * 2 + 0] + p1 * w[(tid + 256) * 2 + 0];
  float l1 = p0 * w[tid * 2 + 1] + p1 * w[(tid + 256) * 2 + 1];
  l0 = bsum(l0, red);
  l1 = bsum(l1, red);
  if (tid == 0) {
    out[NTOK * Ee + b * NCc + 0] = l0 + fb[0];
    out[NTOK * Ee + b * NCc + 1] = l1 + fb[1];
  }
}

// ============================================================================
extern "C" void kernel_launch(void* const* d_in, const int* in_sizes, int n_in,
                              void* d_out, int out_size, void* d_ws, size_t ws_size,
                              hipStream_t stream) {
  (void)in_sizes; (void)n_in; (void)out_size; (void)ws_size;
  const float* x       = (const float*)d_in[0];
  const float* protos  = (const float*)d_in[1];
  const float* cls_tok = (const float*)d_in[2];
  const float* fc1_w   = (const float*)d_in[3];
  const float* fc1_b   = (const float*)d_in[4];
  const float* a0_in_w = (const float*)d_in[5];
  const float* a0_in_b = (const float*)d_in[6];
  const float* a0_out_w= (const float*)d_in[7];
  const float* a0_out_b= (const float*)d_in[8];
  const float* n1g0    = (const float*)d_in[9];
  const float* n1b0    = (const float*)d_in[10];
  const float* n2g0    = (const float*)d_in[11];
  const float* n2b0    = (const float*)d_in[12];
  const float* a1_in_w = (const float*)d_in[13];
  const float* a1_in_b = (const float*)d_in[14];
  const float* a1_out_w= (const float*)d_in[15];
  const float* a1_out_b= (const float*)d_in[16];
  const float* n1g1    = (const float*)d_in[17];
  const float* n1b1    = (const float*)d_in[18];
  const float* n2g1    = (const float*)d_in[19];
  const float* n2b1    = (const float*)d_in[20];
  const float* cw1     = (const float*)d_in[21];
  const float* cb1     = (const float*)d_in[22];
  const float* clg     = (const float*)d_in[23];
  const float* clb     = (const float*)d_in[24];
  const float* cw2     = (const float*)d_in[25];
  const float* cb2     = (const float*)d_in[26];
  const float* gate_w  = (const float*)d_in[27];
  const float* ew1     = (const float*)d_in[28];
  const float* eb1     = (const float*)d_in[29];
  const float* ew2     = (const float*)d_in[30];
  const float* eb2     = (const float*)d_in[31];
  const float* fw1     = (const float*)d_in[32];
  const float* fb1     = (const float*)d_in[33];
  const float* flg     = (const float*)d_in[34];
  const float* flb     = (const float*)d_in[35];
  const float* fw2     = (const float*)d_in[36];
  const float* fb2     = (const float*)d_in[37];
  const float* ng      = (const float*)d_in[38];
  const float* nb      = (const float*)d_in[39];
  const float* fc2_w   = (const float*)d_in[40];
  const float* fc2_b   = (const float*)d_in[41];
  float* out = (float*)d_out;

  float* w = (float*)d_ws;
  size_t off = 0;
  float* BUF0 = w + off; off += (size_t)RR * Dd;
  float* BUF1 = w + off; off += (size_t)RR * Dd;
  float* BUF2 = w + off; off += (size_t)RR * Dd;
  float* BIG  = w + off; off += (size_t)RR * FF;   // qkv (RR*1536) / moe hid / ffn hid
  float* TOPP = w + off; off += NTOK;
  float* PART = w + off; off += 64;
  float* CHID = w + off; off += Bb * FF;
  int* LBL  = (int*)(w + off); off += NTOK;
  int* IDX  = (int*)(w + off); off += NTOK;
  int* LIST = (int*)(w + off); off += Ee * MOE_ROWS;
  int* CNT  = (int*)(w + off); off += Ee * Bb;

  const int elem_grid = (RR * Dd + 255) / 256;

  // 1. labels
  labels_kernel<<<NTOK / 4, 256, 0, stream>>>(x, protos, LBL);
  // 2. fc1: (4096x1024)@(1024x512)+b -> BUF1
  mgemm_kernel<false, false><<<dim3(32, 4), 256, 0, stream>>>(
      x, DIN, fc1_w, Dd, fc1_b, nullptr, BUF1, Dd, NTOK, Dd, DIN);
  // 3. h = concat(cls, fc1out) -> BUF0
  assemble_kernel<<<elem_grid, 256, 0, stream>>>(BUF1, cls_tok, BUF0);

  // ---- layer 0 attention ----
  mgemm_kernel<true, false><<<dim3(33, 12), 256, 0, stream>>>(
      BUF0, Dd, a0_in_w, Dd, a0_in_b, nullptr, BIG, 3 * Dd, RR, 3 * Dd, Dd);
  attn_mfma_kernel<<<dim3(33, Hh, Bb), 256, 0, stream>>>(BIG, BUF1);
  mgemm_kernel<true, false><<<dim3(33, 4), 256, 0, stream>>>(
      BUF1, Dd, a0_out_w, Dd, a0_out_b, nullptr, BUF2, Dd, RR, Dd, Dd);
  // h = LN(h,n1) + attn -> BUF1 ; h = LN(BUF1,n2) -> BUF0 (+BUF2 as h_res)
  ln_kernel<2><<<RR, 256, 0, stream>>>(BUF0, BUF2, n1g0, n1b0, BUF1, nullptr);
  ln_kernel<2><<<RR, 256, 0, stream>>>(BUF1, nullptr, n2g0, n2b0, BUF0, BUF2);

  // ---- cls ffn (parallel), gate, route, moe ----
  cls_ffn1_kernel<<<dim3(FF / 256, Bb), 256, 0, stream>>>(BUF0, cw1, cb1, CHID);
  cls_ffn2_kernel<<<dim3(Dd / 256, Bb), 256, 0, stream>>>(CHID, clg, clb, cw2, cb2, BUF2);
  gate_kernel<<<NTOK / 4, 256, 0, stream>>>(BUF0, gate_w, out, TOPP, IDX);
  route_kernel<<<dim3(Ee, Bb), 256, 0, stream>>>(IDX, LIST, CNT);
  moe_mgemm1_kernel<<<dim3(6, 16, Ee), 256, 0, stream>>>(BUF0, ew1, eb1, LIST, CNT, BIG);
  moe_mgemm2_kernel<<<dim3(6, 4, Ee), 256, 0, stream>>>(BIG, ew2, eb2, LIST, CNT, TOPP, BUF2);
  loss_part_kernel<<<16, 256, 0, stream>>>(out, LBL, PART);
  loss_final_kernel<<<1, 64, 0, stream>>>(PART, out);

  // ---- layer 1 attention ----
  mgemm_kernel<true, false><<<dim3(33, 12), 256, 0, stream>>>(
      BUF2, Dd, a1_in_w, Dd, a1_in_b, nullptr, BIG, 3 * Dd, RR, 3 * Dd, Dd);
  attn_mfma_kernel<<<dim3(33, Hh, Bb), 256, 0, stream>>>(BIG, BUF1);
  mgemm_kernel<true, false><<<dim3(33, 4), 256, 0, stream>>>(
      BUF1, Dd, a1_out_w, Dd, a1_out_b, nullptr, BUF0, Dd, RR, Dd, Dd);
  ln_kernel<2><<<RR, 256, 0, stream>>>(BUF2, BUF0, n1g1, n1b1, BUF1, nullptr);
  ln_kernel<2><<<RR, 256, 0, stream>>>(BUF1, nullptr, n2g1, n2b1, BUF2, nullptr);

  // ---- layer 1 FFN (sub-LN) with residual ----
  mgemm_kernel<false, true><<<dim3(33, 16), 256, 0, stream>>>(
      BUF2, Dd, fw1, FF, fb1, nullptr, BIG, FF, RR, FF, Dd);
  ln_kernel<8><<<RR, 256, 0, stream>>>(BIG, nullptr, flg, flb, BIG, nullptr);
  mgemm_kernel<false, false><<<dim3(33, 4), 256, 0, stream>>>(
      BIG, FF, fw2, Dd, fb2, BUF2, BUF0, Dd, RR, Dd, FF);

  // ---- head ----
  final_head_kernel<<<Bb, 256, 0, stream>>>(BUF0, ng, nb, fc2_w, fc2_b, out);
}

// Round 5
// 772.961 us; speedup vs baseline: 6.0807x; 1.2218x over previous
//
#include <hip/hip_runtime.h>
#include <cmath>

#define DEVINL __device__ __forceinline__

typedef unsigned short ushort_t;
typedef unsigned int uint_t;

constexpr int Bb   = 2;
constexpr int Ss   = 2048;
constexpr int S1   = 2049;
constexpr int DIN  = 1024;
constexpr int Dd   = 512;
constexpr int Hh   = 8;
constexpr int FF   = 2048;
constexpr int Ee   = 6;
constexpr int NCc  = 2;
constexpr int CAP  = 341;
constexpr int NTOK = Bb * Ss;     // 4096
constexpr int RR   = Bb * S1;     // 4098
constexpr int MOE_ROWS = Bb * CAP; // 682

typedef __attribute__((ext_vector_type(4))) float f32x4;
typedef __attribute__((ext_vector_type(8))) short bf16x8;

DEVINL float geluf(float x) { return 0.5f * x * (1.0f + erff(x * 0.7071067811865476f)); }

DEVINL ushort_t f2bf(float f) {
  uint_t u = __float_as_uint(f);
  u += 0x7FFFu + ((u >> 16) & 1u);
  return (ushort_t)(u >> 16);
}
DEVINL float bf2f(ushort_t u) { return __uint_as_float((uint_t)u << 16); }

DEVINL float wsum(float v) {
#pragma unroll
  for (int off = 32; off; off >>= 1) v += __shfl_xor(v, off);
  return v;
}
DEVINL float bsum(float v, float* red) {
  v = wsum(v);
  int w = threadIdx.x >> 6;
  if ((threadIdx.x & 63) == 0) red[w] = v;
  __syncthreads();
  float r = red[0] + red[1] + red[2] + red[3];
  __syncthreads();
  return r;
}

// ---------------- labels: cosine-sim argmax over 4 protos -------------------
__global__ __launch_bounds__(256) void labels_kernel(const float* __restrict__ x,
                                                     const float* __restrict__ protos,
                                                     int* __restrict__ lbl) {
  int t = blockIdx.x * 4 + (threadIdx.x >> 6);
  int lane = threadIdx.x & 63;
  if (t >= NTOK) return;
  const float* xr = x + (size_t)t * DIN;
  float xv[16];
  float ss = 0.f;
#pragma unroll
  for (int i = 0; i < 16; ++i) { xv[i] = xr[lane + 64 * i]; ss += xv[i] * xv[i]; }
  ss = wsum(ss);
  float nx = sqrtf(ss) + 1e-8f;
  float best = -2e30f; int bi = 0;
  for (int p = 0; p < 4; ++p) {
    const float* pr = protos + (size_t)p * DIN;
    float dp = 0.f, pp = 0.f;
#pragma unroll
    for (int i = 0; i < 16; ++i) { float v = pr[lane + 64 * i]; dp += v * xv[i]; pp += v * v; }
    dp = wsum(dp); pp = wsum(pp);
    float sim = dp / (nx * (sqrtf(pp) + 1e-8f));
    if (sim > best) { best = sim; bi = p; }
  }
  if (lane == 0) lbl[t] = bi;
}

// ================= bf16 MFMA GEMM =========================================
// C(MxN) bf16 = act(A@op(B) + bias) [+ res(bf16)].
// ABF: A is bf16 row-major (else fp32, converted at stage).
// BT=0: B fp32 KxN; BT=1: B fp32 NxK. Tile 128x128x64, 4 waves (2x2).
template <bool ABF, bool BT, bool ACT>
__global__ __launch_bounds__(256) void mgemm_kernel(const void* __restrict__ Av, int lda,
                                                    const float* __restrict__ Bw, int ldb,
                                                    const float* __restrict__ bias,
                                                    const ushort_t* __restrict__ res,
                                                    ushort_t* __restrict__ C, int ldc,
                                                    int M, int N, int K) {
  __shared__ ushort_t As[128 * 64];
  __shared__ ushort_t Bs[128 * 64];
  const int tid = threadIdx.x;
  const int l = tid & 63, l15 = l & 15, lg = l >> 4;
  const int wm = (tid >> 7), wn = (tid >> 6) & 1;
  const int bm = blockIdx.x * 128, bn = blockIdx.y * 128;

  f32x4 acc[4][4];
#pragma unroll
  for (int i = 0; i < 4; ++i)
#pragma unroll
    for (int j = 0; j < 4; ++j) acc[i][j] = (f32x4){0.f, 0.f, 0.f, 0.f};

  const int ar = tid >> 1, ac = (tid & 1) * 32;
  const int bkp = (tid & 31) * 2, bnc = (tid >> 5) * 16;

  for (int k0 = 0; k0 < K; k0 += 64) {
    // ---- stage A ----
    {
      const int rswz = (ar & 7) << 4;
      if (ABF) {
        const ushort_t* ap = (const ushort_t*)Av + (size_t)(bm + ar) * lda + k0 + ac;
        bf16x8 v[4];
        if (bm + ar < M) {
#pragma unroll
          for (int i = 0; i < 4; ++i) v[i] = *(const bf16x8*)(ap + i * 8);
        } else {
#pragma unroll
          for (int i = 0; i < 4; ++i) v[i] = (bf16x8){0, 0, 0, 0, 0, 0, 0, 0};
        }
#pragma unroll
        for (int i = 0; i < 4; ++i)
          *(bf16x8*)((char*)As + ((ar * 128 + (ac + i * 8) * 2) ^ rswz)) = v[i];
      } else {
        float f[32];
        if (bm + ar < M) {
          const float* ap = (const float*)Av + (size_t)(bm + ar) * lda + k0 + ac;
#pragma unroll
          for (int i = 0; i < 8; ++i) *(float4*)&f[i * 4] = *(const float4*)(ap + i * 4);
        } else {
#pragma unroll
          for (int i = 0; i < 32; ++i) f[i] = 0.f;
        }
#pragma unroll
        for (int i = 0; i < 4; ++i) {
          bf16x8 v;
#pragma unroll
          for (int j = 0; j < 8; ++j) v[j] = (short)f2bf(f[i * 8 + j]);
          *(bf16x8*)((char*)As + ((ar * 128 + (ac + i * 8) * 2) ^ rswz)) = v;
        }
      }
    }
    // ---- stage B (fp32 weights) ----
    if (BT) {
      float f[32];
      const float* bp = Bw + (size_t)(bn + ar) * ldb + k0 + ac;
#pragma unroll
      for (int i = 0; i < 8; ++i) *(float4*)&f[i * 4] = *(const float4*)(bp + i * 4);
      const int rswz = (ar & 7) << 4;
#pragma unroll
      for (int i = 0; i < 4; ++i) {
        bf16x8 v;
#pragma unroll
        for (int j = 0; j < 8; ++j) v[j] = (short)f2bf(f[i * 8 + j]);
        *(bf16x8*)((char*)Bs + ((ar * 128 + (ac + i * 8) * 2) ^ rswz)) = v;
      }
    } else {
      const float* bp = Bw + (size_t)(k0 + bkp) * ldb + bn + bnc;
      float fa[16], fb[16];
#pragma unroll
      for (int i = 0; i < 4; ++i) {
        *(float4*)&fa[i * 4] = *(const float4*)(bp + i * 4);
        *(float4*)&fb[i * 4] = *(const float4*)(bp + ldb + i * 4);
      }
#pragma unroll
      for (int i = 0; i < 16; ++i) {
        uint_t pk = (uint_t)f2bf(fa[i]) | ((uint_t)f2bf(fb[i]) << 16);
        int n = bnc + i;
        *(uint_t*)((char*)Bs + ((n * 128 + bkp * 2) ^ ((n & 7) << 4))) = pk;
      }
    }
    __syncthreads();

#pragma unroll
    for (int kc = 0; kc < 2; ++kc) {
      bf16x8 af[4], bfr[4];
#pragma unroll
      for (int mi = 0; mi < 4; ++mi) {
        int row = wm * 64 + mi * 16 + l15;
        af[mi] = *(const bf16x8*)((const char*)As +
                   ((row * 128 + (kc * 32 + lg * 8) * 2) ^ ((row & 7) << 4)));
      }
#pragma unroll
      for (int ni = 0; ni < 4; ++ni) {
        int row = wn * 64 + ni * 16 + l15;
        bfr[ni] = *(const bf16x8*)((const char*)Bs +
                   ((row * 128 + (kc * 32 + lg * 8) * 2) ^ ((row & 7) << 4)));
      }
#pragma unroll
      for (int mi = 0; mi < 4; ++mi)
#pragma unroll
        for (int ni = 0; ni < 4; ++ni)
          acc[mi][ni] = __builtin_amdgcn_mfma_f32_16x16x32_bf16(af[mi], bfr[ni], acc[mi][ni], 0, 0, 0);
    }
    __syncthreads();
  }

  // ---- epilogue ----
#pragma unroll
  for (int mi = 0; mi < 4; ++mi)
#pragma unroll
    for (int r = 0; r < 4; ++r) {
      int row = bm + wm * 64 + mi * 16 + lg * 4 + r;
      if (row < M) {
#pragma unroll
        for (int ni = 0; ni < 4; ++ni) {
          int col = bn + wn * 64 + ni * 16 + l15;
          float t = acc[mi][ni][r];
          if (bias) t += bias[col];
          if (ACT) t = geluf(t);
          if (res) t += bf2f(res[(size_t)row * ldc + col]);
          C[(size_t)row * ldc + col] = f2bf(t);
        }
      }
    }
}

// ---- MoE variant 1: hid = gelu(h2[tok] @ w1[e] + b1[e]), all act bf16 ------
__global__ __launch_bounds__(256) void moe_mgemm1_kernel(const ushort_t* __restrict__ h2,
                                                         const float* __restrict__ w1all,
                                                         const float* __restrict__ b1all,
                                                         const int* __restrict__ list,
                                                         const int* __restrict__ cnt,
                                                         ushort_t* __restrict__ hid) {
  __shared__ ushort_t As[128 * 64];
  __shared__ ushort_t Bs[128 * 64];
  const int e = blockIdx.z;
  const int c0 = cnt[e * 2 + 0], c1 = cnt[e * 2 + 1];
  const float* Bw = w1all + (size_t)e * Dd * FF;
  const int tid = threadIdx.x;
  const int l = tid & 63, l15 = l & 15, lg = l >> 4;
  const int wm = (tid >> 7), wn = (tid >> 6) & 1;
  const int bm = blockIdx.x * 128, bn = blockIdx.y * 128;

  f32x4 acc[4][4];
#pragma unroll
  for (int i = 0; i < 4; ++i)
#pragma unroll
    for (int j = 0; j < 4; ++j) acc[i][j] = (f32x4){0.f, 0.f, 0.f, 0.f};

  const int ar = tid >> 1, ac = (tid & 1) * 32;
  const int bkp = (tid & 31) * 2, bnc = (tid >> 5) * 16;

  int r = bm + ar;
  bool aval = (r < MOE_ROWS) && ((r < CAP) ? (r < c0) : ((r - CAP) < c1));
  size_t abase = 0;
  if (aval) {
    int tok = list[e * MOE_ROWS + r];
    int b = tok >> 11, s = tok & (Ss - 1);
    abase = (size_t)(b * S1 + s + 1) * Dd;
  }

  for (int k0 = 0; k0 < Dd; k0 += 64) {
    {
      const int rswz = (ar & 7) << 4;
      bf16x8 v[4];
      if (aval) {
        const ushort_t* ap = h2 + abase + k0 + ac;
#pragma unroll
        for (int i = 0; i < 4; ++i) v[i] = *(const bf16x8*)(ap + i * 8);
      } else {
#pragma unroll
        for (int i = 0; i < 4; ++i) v[i] = (bf16x8){0, 0, 0, 0, 0, 0, 0, 0};
      }
#pragma unroll
      for (int i = 0; i < 4; ++i)
        *(bf16x8*)((char*)As + ((ar * 128 + (ac + i * 8) * 2) ^ rswz)) = v[i];
    }
    {
      const float* bp = Bw + (size_t)(k0 + bkp) * FF + bn + bnc;
      float fa[16], fb[16];
#pragma unroll
      for (int i = 0; i < 4; ++i) {
        *(float4*)&fa[i * 4] = *(const float4*)(bp + i * 4);
        *(float4*)&fb[i * 4] = *(const float4*)(bp + FF + i * 4);
      }
#pragma unroll
      for (int i = 0; i < 16; ++i) {
        uint_t pk = (uint_t)f2bf(fa[i]) | ((uint_t)f2bf(fb[i]) << 16);
        int n = bnc + i;
        *(uint_t*)((char*)Bs + ((n * 128 + bkp * 2) ^ ((n & 7) << 4))) = pk;
      }
    }
    __syncthreads();
#pragma unroll
    for (int kc = 0; kc < 2; ++kc) {
      bf16x8 af[4], bfr[4];
#pragma unroll
      for (int mi = 0; mi < 4; ++mi) {
        int row = wm * 64 + mi * 16 + l15;
        af[mi] = *(const bf16x8*)((const char*)As +
                   ((row * 128 + (kc * 32 + lg * 8) * 2) ^ ((row & 7) << 4)));
      }
#pragma unroll
      for (int ni = 0; ni < 4; ++ni) {
        int row = wn * 64 + ni * 16 + l15;
        bfr[ni] = *(const bf16x8*)((const char*)Bs +
                   ((row * 128 + (kc * 32 + lg * 8) * 2) ^ ((row & 7) << 4)));
      }
#pragma unroll
      for (int mi = 0; mi < 4; ++mi)
#pragma unroll
        for (int ni = 0; ni < 4; ++ni)
          acc[mi][ni] = __builtin_amdgcn_mfma_f32_16x16x32_bf16(af[mi], bfr[ni], acc[mi][ni], 0, 0, 0);
    }
    __syncthreads();
  }

#pragma unroll
  for (int mi = 0; mi < 4; ++mi)
#pragma unroll
    for (int rr = 0; rr < 4; ++rr) {
      int row = bm + wm * 64 + mi * 16 + lg * 4 + rr;
      bool v2 = (row < MOE_ROWS) && ((row < CAP) ? (row < c0) : ((row - CAP) < c1));
      if (v2) {
#pragma unroll
        for (int ni = 0; ni < 4; ++ni) {
          int col = bn + wn * 64 + ni * 16 + l15;
          hid[((size_t)e * MOE_ROWS + row) * FF + col] =
              f2bf(geluf(acc[mi][ni][rr] + b1all[e * FF + col]));
        }
      }
    }
}

// ---- MoE variant 2: out[tok] += topp * (hid @ w2[e] + b2[e]) (bf16 RMW) ----
__global__ __launch_bounds__(256) void moe_mgemm2_kernel(const ushort_t* __restrict__ hid,
                                                         const float* __restrict__ w2all,
                                                         const float* __restrict__ b2all,
                                                         const int* __restrict__ list,
                                                         const int* __restrict__ cnt,
                                                         const float* __restrict__ topp,
                                                         ushort_t* __restrict__ out) {
  __shared__ ushort_t As[128 * 64];
  __shared__ ushort_t Bs[128 * 64];
  const int e = blockIdx.z;
  const int c0 = cnt[e * 2 + 0], c1 = cnt[e * 2 + 1];
  const float* Bw = w2all + (size_t)e * FF * Dd;
  const int tid = threadIdx.x;
  const int l = tid & 63, l15 = l & 15, lg = l >> 4;
  const int wm = (tid >> 7), wn = (tid >> 6) & 1;
  const int bm = blockIdx.x * 128, bn = blockIdx.y * 128;

  f32x4 acc[4][4];
#pragma unroll
  for (int i = 0; i < 4; ++i)
#pragma unroll
    for (int j = 0; j < 4; ++j) acc[i][j] = (f32x4){0.f, 0.f, 0.f, 0.f};

  const int ar = tid >> 1, ac = (tid & 1) * 32;
  const int bkp = (tid & 31) * 2, bnc = (tid >> 5) * 16;

  int r = bm + ar;
  bool aval = (r < MOE_ROWS) && ((r < CAP) ? (r < c0) : ((r - CAP) < c1));
  size_t abase = ((size_t)e * MOE_ROWS + r) * FF;

  for (int k0 = 0; k0 < FF; k0 += 64) {
    {
      const int rswz = (ar & 7) << 4;
      bf16x8 v[4];
      if (aval) {
        const ushort_t* ap = hid + abase + k0 + ac;
#pragma unroll
        for (int i = 0; i < 4; ++i) v[i] = *(const bf16x8*)(ap + i * 8);
      } else {
#pragma unroll
        for (int i = 0; i < 4; ++i) v[i] = (bf16x8){0, 0, 0, 0, 0, 0, 0, 0};
      }
#pragma unroll
      for (int i = 0; i < 4; ++i)
        *(bf16x8*)((char*)As + ((ar * 128 + (ac + i * 8) * 2) ^ rswz)) = v[i];
    }
    {
      const float* bp = Bw + (size_t)(k0 + bkp) * Dd + bn + bnc;
      float fa[16], fb[16];
#pragma unroll
      for (int i = 0; i < 4; ++i) {
        *(float4*)&fa[i * 4] = *(const float4*)(bp + i * 4);
        *(float4*)&fb[i * 4] = *(const float4*)(bp + Dd + i * 4);
      }
#pragma unroll
      for (int i = 0; i < 16; ++i) {
        uint_t pk = (uint_t)f2bf(fa[i]) | ((uint_t)f2bf(fb[i]) << 16);
        int n = bnc + i;
        *(uint_t*)((char*)Bs + ((n * 128 + bkp * 2) ^ ((n & 7) << 4))) = pk;
      }
    }
    __syncthreads();
#pragma unroll
    for (int kc = 0; kc < 2; ++kc) {
      bf16x8 af[4], bfr[4];
#pragma unroll
      for (int mi = 0; mi < 4; ++mi) {
        int row = wm * 64 + mi * 16 + l15;
        af[mi] = *(const bf16x8*)((const char*)As +
                   ((row * 128 + (kc * 32 + lg * 8) * 2) ^ ((row & 7) << 4)));
      }
#pragma unroll
      for (int ni = 0; ni < 4; ++ni) {
        int row = wn * 64 + ni * 16 + l15;
        bfr[ni] = *(const bf16x8*)((const char*)Bs +
                   ((row * 128 + (kc * 32 + lg * 8) * 2) ^ ((row & 7) << 4)));
      }
#pragma unroll
      for (int mi = 0; mi < 4; ++mi)
#pragma unroll
        for (int ni = 0; ni < 4; ++ni)
          acc[mi][ni] = __builtin_amdgcn_mfma_f32_16x16x32_bf16(af[mi], bfr[ni], acc[mi][ni], 0, 0, 0);
    }
    __syncthreads();
  }

#pragma unroll
  for (int mi = 0; mi < 4; ++mi)
#pragma unroll
    for (int rr = 0; rr < 4; ++rr) {
      int row = bm + wm * 64 + mi * 16 + lg * 4 + rr;
      bool v2 = (row < MOE_ROWS) && ((row < CAP) ? (row < c0) : ((row - CAP) < c1));
      if (v2) {
        int tok = list[e * MOE_ROWS + row];
        int b = tok >> 11, s = tok & (Ss - 1);
        float tp = topp[tok];
#pragma unroll
        for (int ni = 0; ni < 4; ++ni) {
          int col = bn + wn * 64 + ni * 16 + l15;
          size_t oidx = (size_t)(b * S1 + s + 1) * Dd + col;
          out[oidx] = f2bf(bf2f(out[oidx]) + tp * (acc[mi][ni][rr] + b2all[e * Dd + col]));
        }
      }
    }
}

// ---------------- assemble h = concat(cls, fc1_out), 8-elem vector ----------
__global__ __launch_bounds__(256) void assemble_kernel(const ushort_t* __restrict__ fc1out,
                                                       const float* __restrict__ cls,
                                                       ushort_t* __restrict__ h) {
  int i = blockIdx.x * 256 + threadIdx.x;       // index of 8-elem chunk
  if (i >= RR * Dd / 8) return;
  int r = i >> 6, d8 = (i & 63) * 8;
  int b = r / S1, sl = r - b * S1;
  bf16x8 v;
  if (sl == 0) {
#pragma unroll
    for (int j = 0; j < 8; ++j) v[j] = (short)f2bf(cls[d8 + j]);
  } else {
    v = *(const bf16x8*)(fc1out + ((size_t)(b * Ss + sl - 1) << 9) + d8);
  }
  *(bf16x8*)(h + ((size_t)r << 9) + d8) = v;
}

// ---------------- wave-per-row LayerNorm (bf16 in/out, fp32 stats) ----------
template <int EPL>  // elems per lane; row length N = 64*EPL
__global__ __launch_bounds__(256) void ln_wave_kernel(const ushort_t* __restrict__ in,
                                                      const ushort_t* __restrict__ addv,
                                                      const float* __restrict__ g,
                                                      const float* __restrict__ bvec,
                                                      ushort_t* __restrict__ out,
                                                      ushort_t* __restrict__ out2,
                                                      int nrows) {
  constexpr int N = 64 * EPL;
  const int row = blockIdx.x * 4 + (threadIdx.x >> 6);
  const int lane = threadIdx.x & 63;
  if (row >= nrows) return;
  const size_t base = (size_t)row * N + lane * EPL;
  float xf[EPL];
  float s1 = 0.f, s2 = 0.f;
#pragma unroll
  for (int c = 0; c < EPL / 8; ++c) {
    bf16x8 x8 = *(const bf16x8*)(in + base + c * 8);
#pragma unroll
    for (int j = 0; j < 8; ++j) {
      float v = bf2f((ushort_t)x8[j]);
      xf[c * 8 + j] = v;
      s1 += v; s2 += v * v;
    }
  }
  s1 = wsum(s1); s2 = wsum(s2);
  float mean = s1 * (1.0f / N);
  float var = s2 * (1.0f / N) - mean * mean;
  float rstd = rsqrtf(var + 1e-5f);
#pragma unroll
  for (int c = 0; c < EPL / 8; ++c) {
    bf16x8 a8;
    if (addv) a8 = *(const bf16x8*)(addv + base + c * 8);
    bf16x8 o8;
#pragma unroll
    for (int j = 0; j < 8; ++j) {
      int col = lane * EPL + c * 8 + j;
      float v = (xf[c * 8 + j] - mean) * rstd * g[col] + bvec[col];
      if (addv) v += bf2f((ushort_t)a8[j]);
      o8[j] = (short)f2bf(v);
    }
    *(bf16x8*)(out + base + c * 8) = o8;
    if (out2) *(bf16x8*)(out2 + base + c * 8) = o8;
  }
}

// ---------------- MFMA bf16 flash attention (bf16 qkv) ----------------------
__global__ __launch_bounds__(256) void attn_mfma_kernel(const ushort_t* __restrict__ qkv,
                                                        ushort_t* __restrict__ o) {
  __shared__ ushort_t Ksh[64 * 64];   // [k][d], XOR-swizzled by (k&7)<<4
  __shared__ ushort_t Vt[64 * 64];    // [d][k], XOR-swizzled by (d&7)<<4
  __shared__ ushort_t Psh[4 * 16 * 64];
  const int tid = threadIdx.x;
  const int w = tid >> 6, l = tid & 63;
  const int l15 = l & 15, lg = l >> 4;
  const int hh = blockIdx.y, b = blockIdx.z;
  const int qblk = blockIdx.x * 64;
  const size_t rbase = (size_t)b * S1 * 1536;

  bf16x8 aq[2];
  {
    int qr = qblk + w * 16 + l15;
    const ushort_t* qp = qkv + rbase + (size_t)qr * 1536 + hh * 64;
#pragma unroll
    for (int dc = 0; dc < 2; ++dc) {
      if (qr < S1) aq[dc] = *(const bf16x8*)(qp + dc * 32 + lg * 8);
      else aq[dc] = (bf16x8){0, 0, 0, 0, 0, 0, 0, 0};
    }
  }

  f32x4 ovac[4];
#pragma unroll
  for (int dt = 0; dt < 4; ++dt) ovac[dt] = (f32x4){0.f, 0.f, 0.f, 0.f};
  float m_r[4], l_r[4];
#pragma unroll
  for (int r = 0; r < 4; ++r) { m_r[r] = -1e30f; l_r[r] = 0.f; }

  const int sk_r = tid >> 3, sk_c = tid & 7;              // K: 32 rows/pass x 8 chunks
  const int sv_k0 = (tid & 31) * 2, sv_d0 = (tid >> 5) * 8; // V: key pair x 8 d

  for (int c = 0; c < 33; ++c) {
    // ---- stage K ----
#pragma unroll
    for (int pass = 0; pass < 2; ++pass) {
      int r = sk_r + pass * 32;
      int key = c * 64 + r;
      bf16x8 v;
      if (key < S1)
        v = *(const bf16x8*)(qkv + rbase + (size_t)key * 1536 + 512 + hh * 64 + sk_c * 8);
      else
        v = (bf16x8){0, 0, 0, 0, 0, 0, 0, 0};
      *(bf16x8*)((char*)Ksh + (((r * 64 + sk_c * 8) * 2) ^ ((r & 7) << 4))) = v;
    }
    // ---- stage V transposed (pack key pairs) ----
    {
      int key0 = c * 64 + sv_k0;
      const ushort_t* vp = qkv + rbase + (size_t)key0 * 1536 + 1024 + hh * 64 + sv_d0;
      bf16x8 va, vb;
      if (key0 < S1) va = *(const bf16x8*)(vp);
      else va = (bf16x8){0, 0, 0, 0, 0, 0, 0, 0};
      if (key0 + 1 < S1) vb = *(const bf16x8*)(vp + 1536);
      else vb = (bf16x8){0, 0, 0, 0, 0, 0, 0, 0};
#pragma unroll
      for (int i = 0; i < 8; ++i) {
        uint_t pk = (uint_t)(ushort_t)va[i] | ((uint_t)(ushort_t)vb[i] << 16);
        int d = sv_d0 + i;
        *(uint_t*)((char*)Vt + (((d * 64 + sv_k0) * 2) ^ ((d & 7) << 4))) = pk;
      }
    }
    __syncthreads();

    f32x4 s[4];
#pragma unroll
    for (int kt = 0; kt < 4; ++kt) {
      f32x4 acc = (f32x4){0.f, 0.f, 0.f, 0.f};
      const int krow = kt * 16 + l15;
      const int rswz = (krow & 7) << 4;
#pragma unroll
      for (int dc = 0; dc < 2; ++dc) {
        bf16x8 kb = *(const bf16x8*)((const char*)Ksh + (((krow * 64 + dc * 32 + lg * 8) * 2) ^ rswz));
        acc = __builtin_amdgcn_mfma_f32_16x16x32_bf16(aq[dc], kb, acc, 0, 0, 0);
      }
#pragma unroll
      for (int r = 0; r < 4; ++r) acc[r] *= 0.125f;     // 1/sqrt(dh)
      if (c * 64 + kt * 16 + l15 >= S1) acc = (f32x4){-1e30f, -1e30f, -1e30f, -1e30f};
      s[kt] = acc;
    }

    float mx[4];
#pragma unroll
    for (int r = 0; r < 4; ++r)
      mx[r] = fmaxf(fmaxf(s[0][r], s[1][r]), fmaxf(s[2][r], s[3][r]));
#pragma unroll
    for (int off = 1; off < 16; off <<= 1)
#pragma unroll
      for (int r = 0; r < 4; ++r) mx[r] = fmaxf(mx[r], __shfl_xor(mx[r], off));
    float fac[4], rs[4];
#pragma unroll
    for (int r = 0; r < 4; ++r) {
      float mn = fmaxf(m_r[r], mx[r]);
      fac[r] = __expf(m_r[r] - mn);
      m_r[r] = mn;
      rs[r] = 0.f;
    }
#pragma unroll
    for (int kt = 0; kt < 4; ++kt)
#pragma unroll
      for (int r = 0; r < 4; ++r) {
        float p = __expf(s[kt][r] - m_r[r]);
        s[kt][r] = p;
        rs[r] += p;
      }
#pragma unroll
    for (int off = 1; off < 16; off <<= 1)
#pragma unroll
      for (int r = 0; r < 4; ++r) rs[r] += __shfl_xor(rs[r], off);
#pragma unroll
    for (int r = 0; r < 4; ++r) l_r[r] = l_r[r] * fac[r] + rs[r];

    {
      char* pb = (char*)Psh + w * 2048;
#pragma unroll
      for (int kt = 0; kt < 4; ++kt)
#pragma unroll
        for (int r = 0; r < 4; ++r) {
          int q = lg * 4 + r;
          *(ushort_t*)(pb + (((q * 64 + kt * 16 + l15) * 2) ^ ((q & 7) << 4))) =
              f2bf(s[kt][r]);
        }
    }

#pragma unroll
    for (int dt = 0; dt < 4; ++dt)
#pragma unroll
      for (int r = 0; r < 4; ++r) ovac[dt][r] *= fac[r];

    {
      const char* pb = (const char*)Psh + w * 2048;
      const int pswz = (l15 & 7) << 4;
#pragma unroll
      for (int kh = 0; kh < 2; ++kh) {
        bf16x8 pa = *(const bf16x8*)(pb + (((l15 * 64 + kh * 32 + lg * 8) * 2) ^ pswz));
#pragma unroll
        for (int dt = 0; dt < 4; ++dt) {
          bf16x8 vb = *(const bf16x8*)((const char*)Vt +
                        ((((dt * 16 + l15) * 64 + kh * 32 + lg * 8) * 2) ^ pswz));
          ovac[dt] = __builtin_amdgcn_mfma_f32_16x16x32_bf16(pa, vb, ovac[dt], 0, 0, 0);
        }
      }
    }
    __syncthreads();
  }

  float inv[4];
#pragma unroll
  for (int r = 0; r < 4; ++r) inv[r] = 1.0f / l_r[r];
#pragma unroll
  for (int r = 0; r < 4; ++r) {
    int qq = qblk + w * 16 + lg * 4 + r;
    if (qq < S1) {
      ushort_t* orow = o + (size_t)(b * S1 + qq) * Dd + hh * 64;
#pragma unroll
      for (int dt = 0; dt < 4; ++dt) orow[dt * 16 + l15] = f2bf(ovac[dt][r] * inv[r]);
    }
  }
}

// ---------------- gate softmax + top1 routing info (bf16 h) -----------------
__global__ __launch_bounds__(256) void gate_kernel(const ushort_t* __restrict__ h2,
                                                   const float* __restrict__ gw,
                                                   float* __restrict__ gate_out,
                                                   float* __restrict__ topp,
                                                   int* __restrict__ idx) {
  int t = blockIdx.x * 4 + (threadIdx.x >> 6);
  int lane = threadIdx.x & 63;
  if (t >= NTOK) return;
  int b = t >> 11, s = t & (Ss - 1);
  const ushort_t* hr = h2 + (size_t)(b * S1 + s + 1) * Dd;
  bf16x8 h8 = *(const bf16x8*)(hr + lane * 8);
  float acc[6] = {};
#pragma unroll
  for (int j = 0; j < 8; ++j) {
    int d = lane * 8 + j;
    float xv = bf2f((ushort_t)h8[j]);
    const float* g = gw + (size_t)d * Ee;
#pragma unroll
    for (int e = 0; e < 6; ++e) acc[e] += xv * g[e];
  }
#pragma unroll
  for (int e = 0; e < 6; ++e) acc[e] = wsum(acc[e]);
  if (lane == 0) {
    float mx = acc[0];
#pragma unroll
    for (int e = 1; e < 6; ++e) mx = fmaxf(mx, acc[e]);
    float ex[6], sum = 0.f;
#pragma unroll
    for (int e = 0; e < 6; ++e) { ex[e] = __expf(acc[e] - mx); sum += ex[e]; }
    float invs = 1.0f / sum;
    int best = 0; float bp = ex[0];
#pragma unroll
    for (int e = 1; e < 6; ++e) { if (ex[e] > bp) { bp = ex[e]; best = e; } }
#pragma unroll
    for (int e = 0; e < 6; ++e) gate_out[(size_t)t * Ee + e] = ex[e] * invs;
    topp[t] = bp * invs;
    idx[t] = best;
  }
}

// ---------------- capacity-limited top-1 router (parallel scan) -------------
__global__ __launch_bounds__(256) void route_kernel(const int* __restrict__ idx,
                                                    int* __restrict__ list,
                                                    int* __restrict__ cnt) {
  __shared__ int cnts[256];
  __shared__ int tot;
  const int e = blockIdx.x, b = blockIdx.y;
  const int tid = threadIdx.x;
  const int s0 = tid * 8;
  int loc[8];
  int c = 0;
#pragma unroll
  for (int j = 0; j < 8; ++j) {
    int t = b * Ss + s0 + j;
    if (idx[t] == e) loc[c++] = t;
  }
  cnts[tid] = c;
  __syncthreads();
  if (tid == 0) {
    int run = 0;
    for (int i = 0; i < 256; ++i) { int v = cnts[i]; cnts[i] = run; run += v; }
    tot = run;
  }
  __syncthreads();
  int base = cnts[tid];
  for (int j = 0; j < c; ++j) {
    int pos = base + j;
    if (pos < CAP) list[e * MOE_ROWS + b * CAP + pos] = loc[j];
  }
  if (tid == 0) cnt[e * Bb + b] = (tot < CAP) ? tot : CAP;
}

// ---------------- cls-token sub-LN FFN, parallelized over columns -----------
__global__ __launch_bounds__(256) void cls_ffn1_kernel(const ushort_t* __restrict__ h2,
                                                       const float* __restrict__ w1,
                                                       const float* __restrict__ b1,
                                                       float* __restrict__ chid) {
  __shared__ float hrow[Dd];
  const int b = blockIdx.y, tid = threadIdx.x;
  const int col = blockIdx.x * 256 + tid;
  const ushort_t* hr = h2 + (size_t)(b * S1) * Dd;
  hrow[tid] = bf2f(hr[tid]);
  hrow[tid + 256] = bf2f(hr[tid + 256]);
  __syncthreads();
  float acc = b1[col];
  for (int d = 0; d < Dd; ++d) acc += hrow[d] * w1[(size_t)d * FF + col];
  chid[b * FF + col] = geluf(acc);
}

__global__ __launch_bounds__(256) void cls_ffn2_kernel(const float* __restrict__ chid,
                                                       const float* __restrict__ lg,
                                                       const float* __restrict__ lb,
                                                       const float* __restrict__ w2,
                                                       const float* __restrict__ b2,
                                                       ushort_t* __restrict__ outbuf) {
  __shared__ float hln[FF];
  __shared__ float red[8];
  const int b = blockIdx.y, tid = threadIdx.x;
  const int col = blockIdx.x * 256 + tid;
  const float* hr = chid + b * FF;
  float hv[8];
  float s1 = 0.f, s2 = 0.f;
#pragma unroll
  for (int j = 0; j < 8; ++j) {
    hv[j] = hr[tid + j * 256];
    s1 += hv[j]; s2 += hv[j] * hv[j];
  }
  s1 = bsum(s1, red);
  s2 = bsum(s2, red);
  float mean = s1 * (1.0f / FF);
  float var = s2 * (1.0f / FF) - mean * mean;
  float rstd = rsqrtf(var + 1e-5f);
#pragma unroll
  for (int j = 0; j < 8; ++j) {
    int k = tid + j * 256;
    hln[k] = (hv[j] - mean) * rstd * lg[k] + lb[k];
  }
  __syncthreads();
  float acc = b2[col];
  for (int k = 0; k < FF; ++k) acc += hln[k] * w2[(size_t)k * Dd + col];
  size_t oidx = (size_t)(b * S1) * Dd + col;
  outbuf[oidx] = f2bf(bf2f(outbuf[oidx]) + acc);
}

// ---------------- loss ------------------------------------------------------
__global__ __launch_bounds__(256) void loss_part_kernel(const float* __restrict__ gate,
                                                        const int* __restrict__ lbl,
                                                        float* __restrict__ part) {
  __shared__ float red[8];
  int t = blockIdx.x * 256 + threadIdx.x;
  float v = 0.f;
  if (t < NTOK) {
    const float* p = gate + (size_t)t * Ee;
    float sum = p[0] + p[1] + p[2] + p[3];
    float pl = p[lbl[t]];
    v = -logf(pl / sum + 1e-9f);
  }
  v = bsum(v, red);
  if (threadIdx.x == 0) part[blockIdx.x] = v;
}

__global__ void loss_final_kernel(const float* __restrict__ part, float* __restrict__ out) {
  if (threadIdx.x == 0) {
    float s = 0.f;
    for (int i = 0; i < 16; ++i) s += part[i];
    out[NTOK * Ee + Bb * NCc] = s / (float)NTOK;
  }
}

// ---------------- final LN + logits ----------------------------------------
__global__ __launch_bounds__(256) void final_head_kernel(const ushort_t* __restrict__ h,
                                                         const float* __restrict__ g,
                                                         const float* __restrict__ bvec,
                                                         const float* __restrict__ w,
                                                         const float* __restrict__ fb,
                                                         float* __restrict__ out) {
  __shared__ float red[8];
  int b = blockIdx.x, tid = threadIdx.x;
  const ushort_t* hr = h + (size_t)(b * S1) * Dd;
  float x0 = bf2f(hr[tid]), x1 = bf2f(hr[tid + 256]);
  float s1 = bsum(x0 + x1, red);
  float s2 = bsum(x0 * x0 + x1 * x1, red);
  float mean = s1 * (1.0f / Dd);
  float var = s2 * (1.0f / Dd) - mean * mean;
  float rstd = rsqrtf(var + 1e-5f);
  float p0 = (x0 - mean) * rstd * g[tid] + bvec[tid];
  float p1 = (x1 - mean) * rstd * g[tid + 256] + bvec[tid + 256];
  float l0 = p0 * w[tid * 2 + 0] + p1 * w[(tid + 256) * 2 + 0];
  float l1 = p0 * w[tid * 2 + 1] + p1 * w[(tid + 256) * 2 + 1];
  l0 = bsum(l0, red);
  l1 = bsum(l1, red);
  if (tid == 0) {
    out[NTOK * Ee + b * NCc + 0] = l0 + fb[0];
    out[NTOK * Ee + b * NCc + 1] = l1 + fb[1];
  }
}

// ============================================================================
extern "C" void kernel_launch(void* const* d_in, const int* in_sizes, int n_in,
                              void* d_out, int out_size, void* d_ws, size_t ws_size,
                              hipStream_t stream) {
  (void)in_sizes; (void)n_in; (void)out_size; (void)ws_size;
  const float* x       = (const float*)d_in[0];
  const float* protos  = (const float*)d_in[1];
  const float* cls_tok = (const float*)d_in[2];
  const float* fc1_w   = (const float*)d_in[3];
  const float* fc1_b   = (const float*)d_in[4];
  const float* a0_in_w = (const float*)d_in[5];
  const float* a0_in_b = (const float*)d_in[6];
  const float* a0_out_w= (const float*)d_in[7];
  const float* a0_out_b= (const float*)d_in[8];
  const float* n1g0    = (const float*)d_in[9];
  const float* n1b0    = (const float*)d_in[10];
  const float* n2g0    = (const float*)d_in[11];
  const float* n2b0    = (const float*)d_in[12];
  const float* a1_in_w = (const float*)d_in[13];
  const float* a1_in_b = (const float*)d_in[14];
  const float* a1_out_w= (const float*)d_in[15];
  const float* a1_out_b= (const float*)d_in[16];
  const float* n1g1    = (const float*)d_in[17];
  const float* n1b1    = (const float*)d_in[18];
  const float* n2g1    = (const float*)d_in[19];
  const float* n2b1    = (const float*)d_in[20];
  const float* cw1     = (const float*)d_in[21];
  const float* cb1     = (const float*)d_in[22];
  const float* clg     = (const float*)d_in[23];
  const float* clb     = (const float*)d_in[24];
  const float* cw2     = (const float*)d_in[25];
  const float* cb2     = (const float*)d_in[26];
  const float* gate_w  = (const float*)d_in[27];
  const float* ew1     = (const float*)d_in[28];
  const float* eb1     = (const float*)d_in[29];
  const float* ew2     = (const float*)d_in[30];
  const float* eb2     = (const float*)d_in[31];
  const float* fw1     = (const float*)d_in[32];
  const float* fb1     = (const float*)d_in[33];
  const float* flg     = (const float*)d_in[34];
  const float* flb     = (const float*)d_in[35];
  const float* fw2     = (const float*)d_in[36];
  const float* fb2     = (const float*)d_in[37];
  const float* ng      = (const float*)d_in[38];
  const float* nb      = (const float*)d_in[39];
  const float* fc2_w   = (const float*)d_in[40];
  const float* fc2_b   = (const float*)d_in[41];
  float* out = (float*)d_out;

  float* w = (float*)d_ws;
  size_t off = 0;
  ushort_t* UB0 = (ushort_t*)(w + off); off += (size_t)RR * Dd;       // h-stream (bf16)
  ushort_t* UB1 = (ushort_t*)(w + off); off += (size_t)RR * Dd;
  ushort_t* UB2 = (ushort_t*)(w + off); off += (size_t)RR * Dd;
  ushort_t* BIGU = (ushort_t*)(w + off); off += (size_t)RR * FF;      // qkv / moe hid / ffn hid (bf16)
  float* TOPP = w + off; off += NTOK;
  float* PART = w + off; off += 64;
  float* CHID = w + off; off += Bb * FF;
  int* LBL  = (int*)(w + off); off += NTOK;
  int* IDX  = (int*)(w + off); off += NTOK;
  int* LIST = (int*)(w + off); off += Ee * MOE_ROWS;
  int* CNT  = (int*)(w + off); off += Ee * Bb;

  const int ln_grid = (RR + 3) / 4;

  // 1. labels
  labels_kernel<<<NTOK / 4, 256, 0, stream>>>(x, protos, LBL);
  // 2. fc1 (A fp32): (4096x1024)@(1024x512)+b -> UB1 (bf16)
  mgemm_kernel<false, false, false><<<dim3(32, 4), 256, 0, stream>>>(
      x, DIN, fc1_w, Dd, fc1_b, nullptr, UB1, Dd, NTOK, Dd, DIN);
  // 3. h = concat(cls, fc1out) -> UB0
  assemble_kernel<<<(RR * Dd / 8 + 255) / 256, 256, 0, stream>>>(UB1, cls_tok, UB0);

  // ---- layer 0 attention ----
  mgemm_kernel<true, true, false><<<dim3(33, 12), 256, 0, stream>>>(
      UB0, Dd, a0_in_w, Dd, a0_in_b, nullptr, BIGU, 3 * Dd, RR, 3 * Dd, Dd);
  attn_mfma_kernel<<<dim3(33, Hh, Bb), 256, 0, stream>>>(BIGU, UB1);
  mgemm_kernel<true, true, false><<<dim3(33, 4), 256, 0, stream>>>(
      UB1, Dd, a0_out_w, Dd, a0_out_b, nullptr, UB2, Dd, RR, Dd, Dd);
  // h = LN(h,n1) + attn -> UB1 ; h = LN(UB1,n2) -> UB0 (+UB2 as h_res)
  ln_wave_kernel<8><<<ln_grid, 256, 0, stream>>>(UB0, UB2, n1g0, n1b0, UB1, nullptr, RR);
  ln_wave_kernel<8><<<ln_grid, 256, 0, stream>>>(UB1, nullptr, n2g0, n2b0, UB0, UB2, RR);

  // ---- cls ffn (parallel), gate, route, moe ----
  cls_ffn1_kernel<<<dim3(FF / 256, Bb), 256, 0, stream>>>(UB0, cw1, cb1, CHID);
  cls_ffn2_kernel<<<dim3(Dd / 256, Bb), 256, 0, stream>>>(CHID, clg, clb, cw2, cb2, UB2);
  gate_kernel<<<NTOK / 4, 256, 0, stream>>>(UB0, gate_w, out, TOPP, IDX);
  route_kernel<<<dim3(Ee, Bb), 256, 0, stream>>>(IDX, LIST, CNT);
  moe_mgemm1_kernel<<<dim3(6, 16, Ee), 256, 0, stream>>>(UB0, ew1, eb1, LIST, CNT, BIGU);
  moe_mgemm2_kernel<<<dim3(6, 4, Ee), 256, 0, stream>>>(BIGU, ew2, eb2, LIST, CNT, TOPP, UB2);
  loss_part_kernel<<<16, 256, 0, stream>>>(out, LBL, PART);
  loss_final_kernel<<<1, 64, 0, stream>>>(PART, out);

  // ---- layer 1 attention ----
  mgemm_kernel<true, true, false><<<dim3(33, 12), 256, 0, stream>>>(
      UB2, Dd, a1_in_w, Dd, a1_in_b, nullptr, BIGU, 3 * Dd, RR, 3 * Dd, Dd);
  attn_mfma_kernel<<<dim3(33, Hh, Bb), 256, 0, stream>>>(BIGU, UB1);
  mgemm_kernel<true, true, false><<<dim3(33, 4), 256, 0, stream>>>(
      UB1, Dd, a1_out_w, Dd, a1_out_b, nullptr, UB0, Dd, RR, Dd, Dd);
  ln_wave_kernel<8><<<ln_grid, 256, 0, stream>>>(UB2, UB0, n1g1, n1b1, UB1, nullptr, RR);
  ln_wave_kernel<8><<<ln_grid, 256, 0, stream>>>(UB1, nullptr, n2g1, n2b1, UB2, nullptr, RR);

  // ---- layer 1 FFN (sub-LN) with residual ----
  mgemm_kernel<true, false, true><<<dim3(33, 16), 256, 0, stream>>>(
      UB2, Dd, fw1, FF, fb1, nullptr, BIGU, FF, RR, FF, Dd);
  ln_wave_kernel<32><<<ln_grid, 256, 0, stream>>>(BIGU, nullptr, flg, flb, BIGU, nullptr, RR);
  mgemm_kernel<true, false, false><<<dim3(33, 4), 256, 0, stream>>>(
      BIGU, FF, fw2, Dd, fb2, UB2, UB0, Dd, RR, Dd, FF);

  // ---- head ----
  final_head_kernel<<<Bb, 256, 0, stream>>>(UB0, ng, nb, fc2_w, fc2_b, out);
}

// Round 6
// 678.085 us; speedup vs baseline: 6.9315x; 1.1399x over previous
//
#include <hip/hip_runtime.h>
#include <cmath>

#define DEVINL __device__ __forceinline__

typedef unsigned short ushort_t;
typedef unsigned int uint_t;

constexpr int Bb   = 2;
constexpr int Ss   = 2048;
constexpr int S1   = 2049;
constexpr int DIN  = 1024;
constexpr int Dd   = 512;
constexpr int Hh   = 8;
constexpr int FF   = 2048;
constexpr int Ee   = 6;
constexpr int NCc  = 2;
constexpr int CAP  = 341;
constexpr int NTOK = Bb * Ss;     // 4096
constexpr int RR   = Bb * S1;     // 4098
constexpr int MOE_ROWS = Bb * CAP; // 682

typedef __attribute__((ext_vector_type(4))) float f32x4;
typedef __attribute__((ext_vector_type(8))) short bf16x8;

DEVINL float geluf(float x) { return 0.5f * x * (1.0f + erff(x * 0.7071067811865476f)); }

DEVINL ushort_t f2bf(float f) {
  uint_t u = __float_as_uint(f);
  u += 0x7FFFu + ((u >> 16) & 1u);
  return (ushort_t)(u >> 16);
}
DEVINL float bf2f(ushort_t u) { return __uint_as_float((uint_t)u << 16); }

// async global->LDS, 16B per lane; LDS dest = wave-uniform base + lane*16,
// global src per-lane (pre-swizzled).  [m97/m104/m173 pattern]
DEVINL void glds16(const ushort_t* g, void* lds) {
  __builtin_amdgcn_global_load_lds(
      (const __attribute__((address_space(1))) void*)g,
      (__attribute__((address_space(3))) void*)lds, 16, 0, 0);
}

DEVINL float wsum(float v) {
#pragma unroll
  for (int off = 32; off; off >>= 1) v += __shfl_xor(v, off);
  return v;
}
DEVINL float bsum(float v, float* red) {
  v = wsum(v);
  int w = threadIdx.x >> 6;
  if ((threadIdx.x & 63) == 0) red[w] = v;
  __syncthreads();
  float r = red[0] + red[1] + red[2] + red[3];
  __syncthreads();
  return r;
}

// ---------------- weight/input conversion ----------------------------------
// fp32 -> bf16 elementwise (n8 = count/8)
__global__ __launch_bounds__(256) void cast_kernel(const float* __restrict__ in,
                                                   ushort_t* __restrict__ out, int n8) {
  int i = blockIdx.x * 256 + threadIdx.x;
  if (i >= n8) return;
  float4 a = *(const float4*)(in + (size_t)i * 8);
  float4 b = *(const float4*)(in + (size_t)i * 8 + 4);
  bf16x8 v;
  v[0] = (short)f2bf(a.x); v[1] = (short)f2bf(a.y);
  v[2] = (short)f2bf(a.z); v[3] = (short)f2bf(a.w);
  v[4] = (short)f2bf(b.x); v[5] = (short)f2bf(b.y);
  v[6] = (short)f2bf(b.z); v[7] = (short)f2bf(b.w);
  *(bf16x8*)(out + (size_t)i * 8) = v;
}

// KxN fp32 -> NxK bf16 (batched over z)
__global__ __launch_bounds__(256) void tpose_cast_kernel(const float* __restrict__ in,
                                                         ushort_t* __restrict__ outp,
                                                         int K, int N) {
  __shared__ float t[64][65];
  const int z = blockIdx.z;
  const float* src = in + (size_t)z * K * N;
  ushort_t* dst = outp + (size_t)z * K * N;
  const int k0 = blockIdx.x * 64, n0 = blockIdx.y * 64;
  const int tx = threadIdx.x & 15, ty = threadIdx.x >> 4;
#pragma unroll
  for (int p = 0; p < 4; ++p) {
    int k = ty + p * 16;
    float4 v = *(const float4*)(src + (size_t)(k0 + k) * N + n0 + tx * 4);
    t[k][tx * 4 + 0] = v.x; t[k][tx * 4 + 1] = v.y;
    t[k][tx * 4 + 2] = v.z; t[k][tx * 4 + 3] = v.w;
  }
  __syncthreads();
#pragma unroll
  for (int p = 0; p < 4; ++p) {
    int n = ty + p * 16;
    uint_t lo = (uint_t)f2bf(t[tx * 4 + 0][n]) | ((uint_t)f2bf(t[tx * 4 + 1][n]) << 16);
    uint_t hi = (uint_t)f2bf(t[tx * 4 + 2][n]) | ((uint_t)f2bf(t[tx * 4 + 3][n]) << 16);
    *(uint2*)(dst + (size_t)(n0 + n) * K + k0 + tx * 4) = make_uint2(lo, hi);
  }
}

// ---------------- labels: cosine-sim argmax over 4 protos -------------------
__global__ __launch_bounds__(256) void labels_kernel(const float* __restrict__ x,
                                                     const float* __restrict__ protos,
                                                     int* __restrict__ lbl) {
  int t = blockIdx.x * 4 + (threadIdx.x >> 6);
  int lane = threadIdx.x & 63;
  if (t >= NTOK) return;
  const float* xr = x + (size_t)t * DIN;
  float xv[16];
  float ss = 0.f;
#pragma unroll
  for (int i = 0; i < 16; ++i) { xv[i] = xr[lane + 64 * i]; ss += xv[i] * xv[i]; }
  ss = wsum(ss);
  float nx = sqrtf(ss) + 1e-8f;
  float best = -2e30f; int bi = 0;
  for (int p = 0; p < 4; ++p) {
    const float* pr = protos + (size_t)p * DIN;
    float dp = 0.f, pp = 0.f;
#pragma unroll
    for (int i = 0; i < 16; ++i) { float v = pr[lane + 64 * i]; dp += v * xv[i]; pp += v * v; }
    dp = wsum(dp); pp = wsum(pp);
    float sim = dp / (nx * (sqrtf(pp) + 1e-8f));
    if (sim > best) { best = sim; bi = p; }
  }
  if (lane == 0) lbl[t] = bi;
}

// ================= bf16 MFMA GEMM, global_load_lds staging ==================
// C(MxN) bf16 = act(A @ B^T + bias) [+ res].  A bf16 MxK row-major,
// B bf16 NxK row-major.  Tile 128x128x64, 4 waves (2x2), 4x4 frags 16x16x32.
// Staging: linear LDS dest via glds16, source col-chunk pre-swizzled
// cc = (l&7)^(l>>3) so the read-side XOR ^((row&7)<<4) sees data[row][c].
template <bool ACT>
__global__ __launch_bounds__(256) void mgemm_kernel(const ushort_t* __restrict__ A, int lda,
                                                    const ushort_t* __restrict__ Bw, int ldb,
                                                    const float* __restrict__ bias,
                                                    const ushort_t* __restrict__ res,
                                                    ushort_t* __restrict__ C, int ldc,
                                                    int M, int N, int K) {
  __shared__ ushort_t As[128 * 64];
  __shared__ ushort_t Bs[128 * 64];
  const int tid = threadIdx.x;
  const int l = tid & 63, l15 = l & 15, lg = l >> 4;
  const int w = tid >> 6;
  const int wm = w >> 1, wn = w & 1;
  const int bm = blockIdx.x * 128, bn = blockIdx.y * 128;
  const int srow = w * 32 + (l >> 3);           // local row base per lane
  const int scc = ((l & 7) ^ (l >> 3)) * 8;     // pre-swizzled col chunk (elems)

  f32x4 acc[4][4];
#pragma unroll
  for (int i = 0; i < 4; ++i)
#pragma unroll
    for (int j = 0; j < 4; ++j) acc[i][j] = (f32x4){0.f, 0.f, 0.f, 0.f};

  const ushort_t* agp[4];
  const ushort_t* bgp[4];
#pragma unroll
  for (int j = 0; j < 4; ++j) {
    int ar = bm + srow + j * 8; if (ar > M - 1) ar = M - 1;   // clamp: invalid rows guarded at epilogue
    agp[j] = A + (size_t)ar * lda + scc;
    bgp[j] = Bw + (size_t)(bn + srow + j * 8) * ldb + scc;
  }

  for (int k0 = 0; k0 < K; k0 += 64) {
#pragma unroll
    for (int j = 0; j < 4; ++j) {
      glds16(agp[j] + k0, (char*)As + w * 4096 + j * 1024);
      glds16(bgp[j] + k0, (char*)Bs + w * 4096 + j * 1024);
    }
    __syncthreads();
#pragma unroll
    for (int kc = 0; kc < 2; ++kc) {
      bf16x8 af[4], bfr[4];
#pragma unroll
      for (int mi = 0; mi < 4; ++mi) {
        int row = wm * 64 + mi * 16 + l15;
        af[mi] = *(const bf16x8*)((const char*)As +
                   ((row * 128 + (kc * 32 + lg * 8) * 2) ^ ((row & 7) << 4)));
      }
#pragma unroll
      for (int ni = 0; ni < 4; ++ni) {
        int row = wn * 64 + ni * 16 + l15;
        bfr[ni] = *(const bf16x8*)((const char*)Bs +
                   ((row * 128 + (kc * 32 + lg * 8) * 2) ^ ((row & 7) << 4)));
      }
#pragma unroll
      for (int mi = 0; mi < 4; ++mi)
#pragma unroll
        for (int ni = 0; ni < 4; ++ni)
          acc[mi][ni] = __builtin_amdgcn_mfma_f32_16x16x32_bf16(af[mi], bfr[ni], acc[mi][ni], 0, 0, 0);
    }
    __syncthreads();
  }

#pragma unroll
  for (int mi = 0; mi < 4; ++mi)
#pragma unroll
    for (int r = 0; r < 4; ++r) {
      int row = bm + wm * 64 + mi * 16 + lg * 4 + r;
      if (row < M) {
#pragma unroll
        for (int ni = 0; ni < 4; ++ni) {
          int col = bn + wn * 64 + ni * 16 + l15;
          float t = acc[mi][ni][r];
          if (bias) t += bias[col];
          if (ACT) t = geluf(t);
          if (res) t += bf2f(res[(size_t)row * ldc + col]);
          C[(size_t)row * ldc + col] = f2bf(t);
        }
      }
    }
}

// ---- MoE variant 1: hid = gelu(h2[tok] @ w1T[e] + b1[e]) -------------------
__global__ __launch_bounds__(256) void moe_mgemm1_kernel(const ushort_t* __restrict__ h2,
                                                         const ushort_t* __restrict__ w1T,
                                                         const float* __restrict__ b1all,
                                                         const int* __restrict__ list,
                                                         const int* __restrict__ cnt,
                                                         ushort_t* __restrict__ hid) {
  __shared__ ushort_t As[128 * 64];
  __shared__ ushort_t Bs[128 * 64];
  const int e = blockIdx.z;
  const int c0 = cnt[e * 2 + 0], c1 = cnt[e * 2 + 1];
  const ushort_t* Bw = w1T + (size_t)e * Dd * FF;   // [FF][Dd]
  const int tid = threadIdx.x;
  const int l = tid & 63, l15 = l & 15, lg = l >> 4;
  const int w = tid >> 6;
  const int wm = w >> 1, wn = w & 1;
  const int bm = blockIdx.x * 128, bn = blockIdx.y * 128;
  const int srow = w * 32 + (l >> 3);
  const int scc = ((l & 7) ^ (l >> 3)) * 8;

  f32x4 acc[4][4];
#pragma unroll
  for (int i = 0; i < 4; ++i)
#pragma unroll
    for (int j = 0; j < 4; ++j) acc[i][j] = (f32x4){0.f, 0.f, 0.f, 0.f};

  const ushort_t* agp[4];
  const ushort_t* bgp[4];
#pragma unroll
  for (int j = 0; j < 4; ++j) {
    int r = bm + srow + j * 8; if (r > MOE_ROWS - 1) r = MOE_ROWS - 1;
    int tok = list[e * MOE_ROWS + r] & (NTOK - 1);  // clamp poison; invalid rows guarded at epilogue
    int b = tok >> 11, s = tok & (Ss - 1);
    agp[j] = h2 + (size_t)(b * S1 + s + 1) * Dd + scc;
    bgp[j] = Bw + (size_t)(bn + srow + j * 8) * Dd + scc;
  }

  for (int k0 = 0; k0 < Dd; k0 += 64) {
#pragma unroll
    for (int j = 0; j < 4; ++j) {
      glds16(agp[j] + k0, (char*)As + w * 4096 + j * 1024);
      glds16(bgp[j] + k0, (char*)Bs + w * 4096 + j * 1024);
    }
    __syncthreads();
#pragma unroll
    for (int kc = 0; kc < 2; ++kc) {
      bf16x8 af[4], bfr[4];
#pragma unroll
      for (int mi = 0; mi < 4; ++mi) {
        int row = wm * 64 + mi * 16 + l15;
        af[mi] = *(const bf16x8*)((const char*)As +
                   ((row * 128 + (kc * 32 + lg * 8) * 2) ^ ((row & 7) << 4)));
      }
#pragma unroll
      for (int ni = 0; ni < 4; ++ni) {
        int row = wn * 64 + ni * 16 + l15;
        bfr[ni] = *(const bf16x8*)((const char*)Bs +
                   ((row * 128 + (kc * 32 + lg * 8) * 2) ^ ((row & 7) << 4)));
      }
#pragma unroll
      for (int mi = 0; mi < 4; ++mi)
#pragma unroll
        for (int ni = 0; ni < 4; ++ni)
          acc[mi][ni] = __builtin_amdgcn_mfma_f32_16x16x32_bf16(af[mi], bfr[ni], acc[mi][ni], 0, 0, 0);
    }
    __syncthreads();
  }

#pragma unroll
  for (int mi = 0; mi < 4; ++mi)
#pragma unroll
    for (int rr = 0; rr < 4; ++rr) {
      int row = bm + wm * 64 + mi * 16 + lg * 4 + rr;
      bool v2 = (row < MOE_ROWS) && ((row < CAP) ? (row < c0) : ((row - CAP) < c1));
      if (v2) {
#pragma unroll
        for (int ni = 0; ni < 4; ++ni) {
          int col = bn + wn * 64 + ni * 16 + l15;
          hid[((size_t)e * MOE_ROWS + row) * FF + col] =
              f2bf(geluf(acc[mi][ni][rr] + b1all[e * FF + col]));
        }
      }
    }
}

// ---- MoE variant 2: out[tok] += topp * (hid @ w2T[e] + b2[e]) --------------
__global__ __launch_bounds__(256) void moe_mgemm2_kernel(const ushort_t* __restrict__ hid,
                                                         const ushort_t* __restrict__ w2T,
                                                         const float* __restrict__ b2all,
                                                         const int* __restrict__ list,
                                                         const int* __restrict__ cnt,
                                                         const float* __restrict__ topp,
                                                         ushort_t* __restrict__ out) {
  __shared__ ushort_t As[128 * 64];
  __shared__ ushort_t Bs[128 * 64];
  const int e = blockIdx.z;
  const int c0 = cnt[e * 2 + 0], c1 = cnt[e * 2 + 1];
  const ushort_t* Bw = w2T + (size_t)e * FF * Dd;   // [Dd][FF]
  const int tid = threadIdx.x;
  const int l = tid & 63, l15 = l & 15, lg = l >> 4;
  const int w = tid >> 6;
  const int wm = w >> 1, wn = w & 1;
  const int bm = blockIdx.x * 128, bn = blockIdx.y * 128;
  const int srow = w * 32 + (l >> 3);
  const int scc = ((l & 7) ^ (l >> 3)) * 8;

  f32x4 acc[4][4];
#pragma unroll
  for (int i = 0; i < 4; ++i)
#pragma unroll
    for (int j = 0; j < 4; ++j) acc[i][j] = (f32x4){0.f, 0.f, 0.f, 0.f};

  const ushort_t* agp[4];
  const ushort_t* bgp[4];
#pragma unroll
  for (int j = 0; j < 4; ++j) {
    int r = bm + srow + j * 8; if (r > MOE_ROWS - 1) r = MOE_ROWS - 1;
    agp[j] = hid + ((size_t)e * MOE_ROWS + r) * FF + scc;
    bgp[j] = Bw + (size_t)(bn + srow + j * 8) * FF + scc;
  }

  for (int k0 = 0; k0 < FF; k0 += 64) {
#pragma unroll
    for (int j = 0; j < 4; ++j) {
      glds16(agp[j] + k0, (char*)As + w * 4096 + j * 1024);
      glds16(bgp[j] + k0, (char*)Bs + w * 4096 + j * 1024);
    }
    __syncthreads();
#pragma unroll
    for (int kc = 0; kc < 2; ++kc) {
      bf16x8 af[4], bfr[4];
#pragma unroll
      for (int mi = 0; mi < 4; ++mi) {
        int row = wm * 64 + mi * 16 + l15;
        af[mi] = *(const bf16x8*)((const char*)As +
                   ((row * 128 + (kc * 32 + lg * 8) * 2) ^ ((row & 7) << 4)));
      }
#pragma unroll
      for (int ni = 0; ni < 4; ++ni) {
        int row = wn * 64 + ni * 16 + l15;
        bfr[ni] = *(const bf16x8*)((const char*)Bs +
                   ((row * 128 + (kc * 32 + lg * 8) * 2) ^ ((row & 7) << 4)));
      }
#pragma unroll
      for (int mi = 0; mi < 4; ++mi)
#pragma unroll
        for (int ni = 0; ni < 4; ++ni)
          acc[mi][ni] = __builtin_amdgcn_mfma_f32_16x16x32_bf16(af[mi], bfr[ni], acc[mi][ni], 0, 0, 0);
    }
    __syncthreads();
  }

#pragma unroll
  for (int mi = 0; mi < 4; ++mi)
#pragma unroll
    for (int rr = 0; rr < 4; ++rr) {
      int row = bm + wm * 64 + mi * 16 + lg * 4 + rr;
      bool v2 = (row < MOE_ROWS) && ((row < CAP) ? (row < c0) : ((row - CAP) < c1));
      if (v2) {
        int tok = list[e * MOE_ROWS + row];
        int b = tok >> 11, s = tok & (Ss - 1);
        float tp = topp[tok];
#pragma unroll
        for (int ni = 0; ni < 4; ++ni) {
          int col = bn + wn * 64 + ni * 16 + l15;
          size_t oidx = (size_t)(b * S1 + s + 1) * Dd + col;
          out[oidx] = f2bf(bf2f(out[oidx]) + tp * (acc[mi][ni][rr] + b2all[e * Dd + col]));
        }
      }
    }
}

// ---------------- assemble h = concat(cls, fc1_out) -------------------------
__global__ __launch_bounds__(256) void assemble_kernel(const ushort_t* __restrict__ fc1out,
                                                       const float* __restrict__ cls,
                                                       ushort_t* __restrict__ h) {
  int i = blockIdx.x * 256 + threadIdx.x;
  if (i >= RR * Dd / 8) return;
  int r = i >> 6, d8 = (i & 63) * 8;
  int b = r / S1, sl = r - b * S1;
  bf16x8 v;
  if (sl == 0) {
#pragma unroll
    for (int j = 0; j < 8; ++j) v[j] = (short)f2bf(cls[d8 + j]);
  } else {
    v = *(const bf16x8*)(fc1out + ((size_t)(b * Ss + sl - 1) << 9) + d8);
  }
  *(bf16x8*)(h + ((size_t)r << 9) + d8) = v;
}

// ---------------- wave-per-row LayerNorm (bf16 in/out, fp32 stats) ----------
template <int EPL>
__global__ __launch_bounds__(256) void ln_wave_kernel(const ushort_t* __restrict__ in,
                                                      const ushort_t* __restrict__ addv,
                                                      const float* __restrict__ g,
                                                      const float* __restrict__ bvec,
                                                      ushort_t* __restrict__ out,
                                                      ushort_t* __restrict__ out2,
                                                      int nrows) {
  constexpr int N = 64 * EPL;
  const int row = blockIdx.x * 4 + (threadIdx.x >> 6);
  const int lane = threadIdx.x & 63;
  if (row >= nrows) return;
  const size_t base = (size_t)row * N + lane * EPL;
  float xf[EPL];
  float s1 = 0.f, s2 = 0.f;
#pragma unroll
  for (int c = 0; c < EPL / 8; ++c) {
    bf16x8 x8 = *(const bf16x8*)(in + base + c * 8);
#pragma unroll
    for (int j = 0; j < 8; ++j) {
      float v = bf2f((ushort_t)x8[j]);
      xf[c * 8 + j] = v;
      s1 += v; s2 += v * v;
    }
  }
  s1 = wsum(s1); s2 = wsum(s2);
  float mean = s1 * (1.0f / N);
  float var = s2 * (1.0f / N) - mean * mean;
  float rstd = rsqrtf(var + 1e-5f);
#pragma unroll
  for (int c = 0; c < EPL / 8; ++c) {
    bf16x8 a8;
    if (addv) a8 = *(const bf16x8*)(addv + base + c * 8);
    bf16x8 o8;
#pragma unroll
    for (int j = 0; j < 8; ++j) {
      int col = lane * EPL + c * 8 + j;
      float v = (xf[c * 8 + j] - mean) * rstd * g[col] + bvec[col];
      if (addv) v += bf2f((ushort_t)a8[j]);
      o8[j] = (short)f2bf(v);
    }
    *(bf16x8*)(out + base + c * 8) = o8;
    if (out2) *(bf16x8*)(out2 + base + c * 8) = o8;
  }
}

// ---------------- MFMA bf16 flash attention (bf16 qkv) ----------------------
__global__ __launch_bounds__(256) void attn_mfma_kernel(const ushort_t* __restrict__ qkv,
                                                        ushort_t* __restrict__ o) {
  __shared__ ushort_t Ksh[64 * 64];
  __shared__ ushort_t Vt[64 * 64];
  __shared__ ushort_t Psh[4 * 16 * 64];
  const int tid = threadIdx.x;
  const int w = tid >> 6, l = tid & 63;
  const int l15 = l & 15, lg = l >> 4;
  const int hh = blockIdx.y, b = blockIdx.z;
  const int qblk = blockIdx.x * 64;
  const size_t rbase = (size_t)b * S1 * 1536;

  bf16x8 aq[2];
  {
    int qr = qblk + w * 16 + l15;
    const ushort_t* qp = qkv + rbase + (size_t)qr * 1536 + hh * 64;
#pragma unroll
    for (int dc = 0; dc < 2; ++dc) {
      if (qr < S1) aq[dc] = *(const bf16x8*)(qp + dc * 32 + lg * 8);
      else aq[dc] = (bf16x8){0, 0, 0, 0, 0, 0, 0, 0};
    }
  }

  f32x4 ovac[4];
#pragma unroll
  for (int dt = 0; dt < 4; ++dt) ovac[dt] = (f32x4){0.f, 0.f, 0.f, 0.f};
  float m_r[4], l_r[4];
#pragma unroll
  for (int r = 0; r < 4; ++r) { m_r[r] = -1e30f; l_r[r] = 0.f; }

  const int sk_r = tid >> 3, sk_c = tid & 7;
  const int sv_k0 = (tid & 31) * 2, sv_d0 = (tid >> 5) * 8;

  for (int c = 0; c < 33; ++c) {
#pragma unroll
    for (int pass = 0; pass < 2; ++pass) {
      int r = sk_r + pass * 32;
      int key = c * 64 + r;
      bf16x8 v;
      if (key < S1)
        v = *(const bf16x8*)(qkv + rbase + (size_t)key * 1536 + 512 + hh * 64 + sk_c * 8);
      else
        v = (bf16x8){0, 0, 0, 0, 0, 0, 0, 0};
      *(bf16x8*)((char*)Ksh + (((r * 64 + sk_c * 8) * 2) ^ ((r & 7) << 4))) = v;
    }
    {
      int key0 = c * 64 + sv_k0;
      const ushort_t* vp = qkv + rbase + (size_t)key0 * 1536 + 1024 + hh * 64 + sv_d0;
      bf16x8 va, vb;
      if (key0 < S1) va = *(const bf16x8*)(vp);
      else va = (bf16x8){0, 0, 0, 0, 0, 0, 0, 0};
      if (key0 + 1 < S1) vb = *(const bf16x8*)(vp + 1536);
      else vb = (bf16x8){0, 0, 0, 0, 0, 0, 0, 0};
#pragma unroll
      for (int i = 0; i < 8; ++i) {
        uint_t pk = (uint_t)(ushort_t)va[i] | ((uint_t)(ushort_t)vb[i] << 16);
        int d = sv_d0 + i;
        *(uint_t*)((char*)Vt + (((d * 64 + sv_k0) * 2) ^ ((d & 7) << 4))) = pk;
      }
    }
    __syncthreads();

    f32x4 s[4];
#pragma unroll
    for (int kt = 0; kt < 4; ++kt) {
      f32x4 acc = (f32x4){0.f, 0.f, 0.f, 0.f};
      const int krow = kt * 16 + l15;
      const int rswz = (krow & 7) << 4;
#pragma unroll
      for (int dc = 0; dc < 2; ++dc) {
        bf16x8 kb = *(const bf16x8*)((const char*)Ksh + (((krow * 64 + dc * 32 + lg * 8) * 2) ^ rswz));
        acc = __builtin_amdgcn_mfma_f32_16x16x32_bf16(aq[dc], kb, acc, 0, 0, 0);
      }
#pragma unroll
      for (int r = 0; r < 4; ++r) acc[r] *= 0.125f;
      if (c * 64 + kt * 16 + l15 >= S1) acc = (f32x4){-1e30f, -1e30f, -1e30f, -1e30f};
      s[kt] = acc;
    }

    float mx[4];
#pragma unroll
    for (int r = 0; r < 4; ++r)
      mx[r] = fmaxf(fmaxf(s[0][r], s[1][r]), fmaxf(s[2][r], s[3][r]));
#pragma unroll
    for (int off = 1; off < 16; off <<= 1)
#pragma unroll
      for (int r = 0; r < 4; ++r) mx[r] = fmaxf(mx[r], __shfl_xor(mx[r], off));
    float fac[4], rs[4];
#pragma unroll
    for (int r = 0; r < 4; ++r) {
      float mn = fmaxf(m_r[r], mx[r]);
      fac[r] = __expf(m_r[r] - mn);
      m_r[r] = mn;
      rs[r] = 0.f;
    }
#pragma unroll
    for (int kt = 0; kt < 4; ++kt)
#pragma unroll
      for (int r = 0; r < 4; ++r) {
        float p = __expf(s[kt][r] - m_r[r]);
        s[kt][r] = p;
        rs[r] += p;
      }
#pragma unroll
    for (int off = 1; off < 16; off <<= 1)
#pragma unroll
      for (int r = 0; r < 4; ++r) rs[r] += __shfl_xor(rs[r], off);
#pragma unroll
    for (int r = 0; r < 4; ++r) l_r[r] = l_r[r] * fac[r] + rs[r];

    {
      char* pb = (char*)Psh + w * 2048;
#pragma unroll
      for (int kt = 0; kt < 4; ++kt)
#pragma unroll
        for (int r = 0; r < 4; ++r) {
          int q = lg * 4 + r;
          *(ushort_t*)(pb + (((q * 64 + kt * 16 + l15) * 2) ^ ((q & 7) << 4))) =
              f2bf(s[kt][r]);
        }
    }

#pragma unroll
    for (int dt = 0; dt < 4; ++dt)
#pragma unroll
      for (int r = 0; r < 4; ++r) ovac[dt][r] *= fac[r];

    {
      const char* pb = (const char*)Psh + w * 2048;
      const int pswz = (l15 & 7) << 4;
#pragma unroll
      for (int kh = 0; kh < 2; ++kh) {
        bf16x8 pa = *(const bf16x8*)(pb + (((l15 * 64 + kh * 32 + lg * 8) * 2) ^ pswz));
#pragma unroll
        for (int dt = 0; dt < 4; ++dt) {
          bf16x8 vb = *(const bf16x8*)((const char*)Vt +
                        ((((dt * 16 + l15) * 64 + kh * 32 + lg * 8) * 2) ^ pswz));
          ovac[dt] = __builtin_amdgcn_mfma_f32_16x16x32_bf16(pa, vb, ovac[dt], 0, 0, 0);
        }
      }
    }
    __syncthreads();
  }

  float inv[4];
#pragma unroll
  for (int r = 0; r < 4; ++r) inv[r] = 1.0f / l_r[r];
#pragma unroll
  for (int r = 0; r < 4; ++r) {
    int qq = qblk + w * 16 + lg * 4 + r;
    if (qq < S1) {
      ushort_t* orow = o + (size_t)(b * S1 + qq) * Dd + hh * 64;
#pragma unroll
      for (int dt = 0; dt < 4; ++dt) orow[dt * 16 + l15] = f2bf(ovac[dt][r] * inv[r]);
    }
  }
}

// ---------------- gate softmax + top1 routing info (bf16 h) -----------------
__global__ __launch_bounds__(256) void gate_kernel(const ushort_t* __restrict__ h2,
                                                   const float* __restrict__ gw,
                                                   float* __restrict__ gate_out,
                                                   float* __restrict__ topp,
                                                   int* __restrict__ idx) {
  int t = blockIdx.x * 4 + (threadIdx.x >> 6);
  int lane = threadIdx.x & 63;
  if (t >= NTOK) return;
  int b = t >> 11, s = t & (Ss - 1);
  const ushort_t* hr = h2 + (size_t)(b * S1 + s + 1) * Dd;
  bf16x8 h8 = *(const bf16x8*)(hr + lane * 8);
  float acc[6] = {};
#pragma unroll
  for (int j = 0; j < 8; ++j) {
    int d = lane * 8 + j;
    float xv = bf2f((ushort_t)h8[j]);
    const float* g = gw + (size_t)d * Ee;
#pragma unroll
    for (int e = 0; e < 6; ++e) acc[e] += xv * g[e];
  }
#pragma unroll
  for (int e = 0; e < 6; ++e) acc[e] = wsum(acc[e]);
  if (lane == 0) {
    float mx = acc[0];
#pragma unroll
    for (int e = 1; e < 6; ++e) mx = fmaxf(mx, acc[e]);
    float ex[6], sum = 0.f;
#pragma unroll
    for (int e = 0; e < 6; ++e) { ex[e] = __expf(acc[e] - mx); sum += ex[e]; }
    float invs = 1.0f / sum;
    int best = 0; float bp = ex[0];
#pragma unroll
    for (int e = 1; e < 6; ++e) { if (ex[e] > bp) { bp = ex[e]; best = e; } }
#pragma unroll
    for (int e = 0; e < 6; ++e) gate_out[(size_t)t * Ee + e] = ex[e] * invs;
    topp[t] = bp * invs;
    idx[t] = best;
  }
}

// ---------------- capacity-limited top-1 router (parallel scan) -------------
__global__ __launch_bounds__(256) void route_kernel(const int* __restrict__ idx,
                                                    int* __restrict__ list,
                                                    int* __restrict__ cnt) {
  __shared__ int cnts[256];
  __shared__ int tot;
  const int e = blockIdx.x, b = blockIdx.y;
  const int tid = threadIdx.x;
  const int s0 = tid * 8;
  int loc[8];
  int c = 0;
#pragma unroll
  for (int j = 0; j < 8; ++j) {
    int t = b * Ss + s0 + j;
    if (idx[t] == e) loc[c++] = t;
  }
  cnts[tid] = c;
  __syncthreads();
  if (tid == 0) {
    int run = 0;
    for (int i = 0; i < 256; ++i) { int v = cnts[i]; cnts[i] = run; run += v; }
    tot = run;
  }
  __syncthreads();
  int base = cnts[tid];
  for (int j = 0; j < c; ++j) {
    int pos = base + j;
    if (pos < CAP) list[e * MOE_ROWS + b * CAP + pos] = loc[j];
  }
  if (tid == 0) cnt[e * Bb + b] = (tot < CAP) ? tot : CAP;
}

// ---------------- cls-token sub-LN FFN, parallelized over columns -----------
__global__ __launch_bounds__(256) void cls_ffn1_kernel(const ushort_t* __restrict__ h2,
                                                       const float* __restrict__ w1,
                                                       const float* __restrict__ b1,
                                                       float* __restrict__ chid) {
  __shared__ float hrow[Dd];
  const int b = blockIdx.y, tid = threadIdx.x;
  const int col = blockIdx.x * 256 + tid;
  const ushort_t* hr = h2 + (size_t)(b * S1) * Dd;
  hrow[tid] = bf2f(hr[tid]);
  hrow[tid + 256] = bf2f(hr[tid + 256]);
  __syncthreads();
  float acc = b1[col];
  for (int d = 0; d < Dd; ++d) acc += hrow[d] * w1[(size_t)d * FF + col];
  chid[b * FF + col] = geluf(acc);
}

__global__ __launch_bounds__(256) void cls_ffn2_kernel(const float* __restrict__ chid,
                                                       const float* __restrict__ lg,
                                                       const float* __restrict__ lb,
                                                       const float* __restrict__ w2,
                                                       const float* __restrict__ b2,
                                                       ushort_t* __restrict__ outbuf) {
  __shared__ float hln[FF];
  __shared__ float red[8];
  const int b = blockIdx.y, tid = threadIdx.x;
  const int col = blockIdx.x * 256 + tid;
  const float* hr = chid + b * FF;
  float hv[8];
  float s1 = 0.f, s2 = 0.f;
#pragma unroll
  for (int j = 0; j < 8; ++j) {
    hv[j] = hr[tid + j * 256];
    s1 += hv[j]; s2 += hv[j] * hv[j];
  }
  s1 = bsum(s1, red);
  s2 = bsum(s2, red);
  float mean = s1 * (1.0f / FF);
  float var = s2 * (1.0f / FF) - mean * mean;
  float rstd = rsqrtf(var + 1e-5f);
#pragma unroll
  for (int j = 0; j < 8; ++j) {
    int k = tid + j * 256;
    hln[k] = (hv[j] - mean) * rstd * lg[k] + lb[k];
  }
  __syncthreads();
  float acc = b2[col];
  for (int k = 0; k < FF; ++k) acc += hln[k] * w2[(size_t)k * Dd + col];
  size_t oidx = (size_t)(b * S1) * Dd + col;
  outbuf[oidx] = f2bf(bf2f(outbuf[oidx]) + acc);
}

// ---------------- loss ------------------------------------------------------
__global__ __launch_bounds__(256) void loss_part_kernel(const float* __restrict__ gate,
                                                        const int* __restrict__ lbl,
                                                        float* __restrict__ part) {
  __shared__ float red[8];
  int t = blockIdx.x * 256 + threadIdx.x;
  float v = 0.f;
  if (t < NTOK) {
    const float* p = gate + (size_t)t * Ee;
    float sum = p[0] + p[1] + p[2] + p[3];
    float pl = p[lbl[t]];
    v = -logf(pl / sum + 1e-9f);
  }
  v = bsum(v, red);
  if (threadIdx.x == 0) part[blockIdx.x] = v;
}

__global__ void loss_final_kernel(const float* __restrict__ part, float* __restrict__ out) {
  if (threadIdx.x == 0) {
    float s = 0.f;
    for (int i = 0; i < 16; ++i) s += part[i];
    out[NTOK * Ee + Bb * NCc] = s / (float)NTOK;
  }
}

// ---------------- final LN + logits ----------------------------------------
__global__ __launch_bounds__(256) void final_head_kernel(const ushort_t* __restrict__ h,
                                                         const float* __restrict__ g,
                                                         const float* __restrict__ bvec,
                                                         const float* __restrict__ w,
                                                         const float* __restrict__ fb,
                                                         float* __restrict__ out) {
  __shared__ float red[8];
  int b = blockIdx.x, tid = threadIdx.x;
  const ushort_t* hr = h + (size_t)(b * S1) * Dd;
  float x0 = bf2f(hr[tid]), x1 = bf2f(hr[tid + 256]);
  float s1 = bsum(x0 + x1, red);
  float s2 = bsum(x0 * x0 + x1 * x1, red);
  float mean = s1 * (1.0f / Dd);
  float var = s2 * (1.0f / Dd) - mean * mean;
  float rstd = rsqrtf(var + 1e-5f);
  float p0 = (x0 - mean) * rstd * g[tid] + bvec[tid];
  float p1 = (x1 - mean) * rstd * g[tid + 256] + bvec[tid + 256];
  float l0 = p0 * w[tid * 2 + 0] + p1 * w[(tid + 256) * 2 + 0];
  float l1 = p0 * w[tid * 2 + 1] + p1 * w[(tid + 256) * 2 + 1];
  l0 = bsum(l0, red);
  l1 = bsum(l1, red);
  if (tid == 0) {
    out[NTOK * Ee + b * NCc + 0] = l0 + fb[0];
    out[NTOK * Ee + b * NCc + 1] = l1 + fb[1];
  }
}

// ============================================================================
extern "C" void kernel_launch(void* const* d_in, const int* in_sizes, int n_in,
                              void* d_out, int out_size, void* d_ws, size_t ws_size,
                              hipStream_t stream) {
  (void)in_sizes; (void)n_in; (void)out_size; (void)ws_size;
  const float* x       = (const float*)d_in[0];
  const float* protos  = (const float*)d_in[1];
  const float* cls_tok = (const float*)d_in[2];
  const float* fc1_w   = (const float*)d_in[3];
  const float* fc1_b   = (const float*)d_in[4];
  const float* a0_in_w = (const float*)d_in[5];
  const float* a0_in_b = (const float*)d_in[6];
  const float* a0_out_w= (const float*)d_in[7];
  const float* a0_out_b= (const float*)d_in[8];
  const float* n1g0    = (const float*)d_in[9];
  const float* n1b0    = (const float*)d_in[10];
  const float* n2g0    = (const float*)d_in[11];
  const float* n2b0    = (const float*)d_in[12];
  const float* a1_in_w = (const float*)d_in[13];
  const float* a1_in_b = (const float*)d_in[14];
  const float* a1_out_w= (const float*)d_in[15];
  const float* a1_out_b= (const float*)d_in[16];
  const float* n1g1    = (const float*)d_in[17];
  const float* n1b1    = (const float*)d_in[18];
  const float* n2g1    = (const float*)d_in[19];
  const float* n2b1    = (const float*)d_in[20];
  const float* cw1     = (const float*)d_in[21];
  const float* cb1     = (const float*)d_in[22];
  const float* clg     = (const float*)d_in[23];
  const float* clb     = (const float*)d_in[24];
  const float* cw2     = (const float*)d_in[25];
  const float* cb2     = (const float*)d_in[26];
  const float* gate_w  = (const float*)d_in[27];
  const float* ew1     = (const float*)d_in[28];
  const float* eb1     = (const float*)d_in[29];
  const float* ew2     = (const float*)d_in[30];
  const float* eb2     = (const float*)d_in[31];
  const float* fw1     = (const float*)d_in[32];
  const float* fb1     = (const float*)d_in[33];
  const float* flg     = (const float*)d_in[34];
  const float* flb     = (const float*)d_in[35];
  const float* fw2     = (const float*)d_in[36];
  const float* fb2     = (const float*)d_in[37];
  const float* ng      = (const float*)d_in[38];
  const float* nb      = (const float*)d_in[39];
  const float* fc2_w   = (const float*)d_in[40];
  const float* fc2_b   = (const float*)d_in[41];
  float* out = (float*)d_out;

  char* base = (char*)d_ws;
  size_t o = 0;
  auto alloc = [&](size_t bytes) -> void* {
    void* p = base + o;
    o += (bytes + 255) & ~(size_t)255;
    return p;
  };
  ushort_t* UB0  = (ushort_t*)alloc((size_t)RR * Dd * 2);
  ushort_t* UB1  = (ushort_t*)alloc((size_t)RR * Dd * 2);
  ushort_t* UB2  = (ushort_t*)alloc((size_t)RR * Dd * 2);
  ushort_t* BIGU = (ushort_t*)alloc((size_t)RR * FF * 2);
  ushort_t* XB   = (ushort_t*)alloc((size_t)NTOK * DIN * 2);
  ushort_t* WQ0  = (ushort_t*)alloc((size_t)3 * Dd * Dd * 2);   // a0_in NxK bf16
  ushort_t* WO0  = (ushort_t*)alloc((size_t)Dd * Dd * 2);
  ushort_t* WQ1  = (ushort_t*)alloc((size_t)3 * Dd * Dd * 2);
  ushort_t* WO1  = (ushort_t*)alloc((size_t)Dd * Dd * 2);
  ushort_t* WF1T = (ushort_t*)alloc((size_t)Dd * DIN * 2);      // fc1^T  [512][1024]
  ushort_t* WE1T = (ushort_t*)alloc((size_t)Ee * FF * Dd * 2);  // e_w1^T [e][2048][512]
  ushort_t* WE2T = (ushort_t*)alloc((size_t)Ee * Dd * FF * 2);  // e_w2^T [e][512][2048]
  ushort_t* WFW1T= (ushort_t*)alloc((size_t)FF * Dd * 2);       // fw1^T  [2048][512]
  ushort_t* WFW2T= (ushort_t*)alloc((size_t)Dd * FF * 2);       // fw2^T  [512][2048]
  float* TOPP = (float*)alloc(NTOK * 4);
  float* PART = (float*)alloc(64 * 4);
  float* CHID = (float*)alloc(Bb * FF * 4);
  int* LBL  = (int*)alloc(NTOK * 4);
  int* IDX  = (int*)alloc(NTOK * 4);
  int* LIST = (int*)alloc(Ee * MOE_ROWS * 4);
  int* CNT  = (int*)alloc(Ee * Bb * 4);

  const int ln_grid = (RR + 3) / 4;

  // ---- one-shot conversions (bf16, unified NxK) ----
  cast_kernel<<<(NTOK * DIN / 8 + 255) / 256, 256, 0, stream>>>(x, XB, NTOK * DIN / 8);
  cast_kernel<<<(3 * Dd * Dd / 8 + 255) / 256, 256, 0, stream>>>(a0_in_w, WQ0, 3 * Dd * Dd / 8);
  cast_kernel<<<(Dd * Dd / 8 + 255) / 256, 256, 0, stream>>>(a0_out_w, WO0, Dd * Dd / 8);
  cast_kernel<<<(3 * Dd * Dd / 8 + 255) / 256, 256, 0, stream>>>(a1_in_w, WQ1, 3 * Dd * Dd / 8);
  cast_kernel<<<(Dd * Dd / 8 + 255) / 256, 256, 0, stream>>>(a1_out_w, WO1, Dd * Dd / 8);
  tpose_cast_kernel<<<dim3(DIN / 64, Dd / 64, 1), 256, 0, stream>>>(fc1_w, WF1T, DIN, Dd);
  tpose_cast_kernel<<<dim3(Dd / 64, FF / 64, Ee), 256, 0, stream>>>(ew1, WE1T, Dd, FF);
  tpose_cast_kernel<<<dim3(FF / 64, Dd / 64, Ee), 256, 0, stream>>>(ew2, WE2T, FF, Dd);
  tpose_cast_kernel<<<dim3(Dd / 64, FF / 64, 1), 256, 0, stream>>>(fw1, WFW1T, Dd, FF);
  tpose_cast_kernel<<<dim3(FF / 64, Dd / 64, 1), 256, 0, stream>>>(fw2, WFW2T, FF, Dd);

  // 1. labels
  labels_kernel<<<NTOK / 4, 256, 0, stream>>>(x, protos, LBL);
  // 2. fc1: (4096x1024)@(1024x512)^T' + b -> UB1
  mgemm_kernel<false><<<dim3(32, 4), 256, 0, stream>>>(
      XB, DIN, WF1T, DIN, fc1_b, nullptr, UB1, Dd, NTOK, Dd, DIN);
  // 3. h = concat(cls, fc1out) -> UB0
  assemble_kernel<<<(RR * Dd / 8 + 255) / 256, 256, 0, stream>>>(UB1, cls_tok, UB0);

  // ---- layer 0 attention ----
  mgemm_kernel<false><<<dim3(33, 12), 256, 0, stream>>>(
      UB0, Dd, WQ0, Dd, a0_in_b, nullptr, BIGU, 3 * Dd, RR, 3 * Dd, Dd);
  attn_mfma_kernel<<<dim3(33, Hh, Bb), 256, 0, stream>>>(BIGU, UB1);
  mgemm_kernel<false><<<dim3(33, 4), 256, 0, stream>>>(
      UB1, Dd, WO0, Dd, a0_out_b, nullptr, UB2, Dd, RR, Dd, Dd);
  ln_wave_kernel<8><<<ln_grid, 256, 0, stream>>>(UB0, UB2, n1g0, n1b0, UB1, nullptr, RR);
  ln_wave_kernel<8><<<ln_grid, 256, 0, stream>>>(UB1, nullptr, n2g0, n2b0, UB0, UB2, RR);

  // ---- cls ffn, gate, route, moe ----
  cls_ffn1_kernel<<<dim3(FF / 256, Bb), 256, 0, stream>>>(UB0, cw1, cb1, CHID);
  cls_ffn2_kernel<<<dim3(Dd / 256, Bb), 256, 0, stream>>>(CHID, clg, clb, cw2, cb2, UB2);
  gate_kernel<<<NTOK / 4, 256, 0, stream>>>(UB0, gate_w, out, TOPP, IDX);
  route_kernel<<<dim3(Ee, Bb), 256, 0, stream>>>(IDX, LIST, CNT);
  moe_mgemm1_kernel<<<dim3(6, 16, Ee), 256, 0, stream>>>(UB0, WE1T, eb1, LIST, CNT, BIGU);
  moe_mgemm2_kernel<<<dim3(6, 4, Ee), 256, 0, stream>>>(BIGU, WE2T, eb2, LIST, CNT, TOPP, UB2);
  loss_part_kernel<<<16, 256, 0, stream>>>(out, LBL, PART);
  loss_final_kernel<<<1, 64, 0, stream>>>(PART, out);

  // ---- layer 1 attention ----
  mgemm_kernel<false><<<dim3(33, 12), 256, 0, stream>>>(
      UB2, Dd, WQ1, Dd, a1_in_b, nullptr, BIGU, 3 * Dd, RR, 3 * Dd, Dd);
  attn_mfma_kernel<<<dim3(33, Hh, Bb), 256, 0, stream>>>(BIGU, UB1);
  mgemm_kernel<false><<<dim3(33, 4), 256, 0, stream>>>(
      UB1, Dd, WO1, Dd, a1_out_b, nullptr, UB0, Dd, RR, Dd, Dd);
  ln_wave_kernel<8><<<ln_grid, 256, 0, stream>>>(UB2, UB0, n1g1, n1b1, UB1, nullptr, RR);
  ln_wave_kernel<8><<<ln_grid, 256, 0, stream>>>(UB1, nullptr, n2g1, n2b1, UB2, nullptr, RR);

  // ---- layer 1 FFN (sub-LN) with residual ----
  mgemm_kernel<true><<<dim3(33, 16), 256, 0, stream>>>(
      UB2, Dd, WFW1T, Dd, fb1, nullptr, BIGU, FF, RR, FF, Dd);
  ln_wave_kernel<32><<<ln_grid, 256, 0, stream>>>(BIGU, nullptr, flg, flb, BIGU, nullptr, RR);
  mgemm_kernel<false><<<dim3(33, 4), 256, 0, stream>>>(
      BIGU, FF, WFW2T, FF, fb2, UB2, UB0, Dd, RR, Dd, FF);

  // ---- head ----
  final_head_kernel<<<Bb, 256, 0, stream>>>(UB0, ng, nb, fc2_w, fc2_b, out);
}

// Round 7
// 624.952 us; speedup vs baseline: 7.5208x; 1.0850x over previous
//
#include <hip/hip_runtime.h>
#include <cmath>

#define DEVINL __device__ __forceinline__

typedef unsigned short ushort_t;
typedef unsigned int uint_t;

constexpr int Bb   = 2;
constexpr int Ss   = 2048;
constexpr int S1   = 2049;
constexpr int DIN  = 1024;
constexpr int Dd   = 512;
constexpr int Hh   = 8;
constexpr int FF   = 2048;
constexpr int Ee   = 6;
constexpr int NCc  = 2;
constexpr int CAP  = 341;
constexpr int NTOK = Bb * Ss;     // 4096
constexpr int RR   = Bb * S1;     // 4098
constexpr int MOE_ROWS = Bb * CAP; // 682

typedef __attribute__((ext_vector_type(4))) float f32x4;
typedef __attribute__((ext_vector_type(8))) short bf16x8;

DEVINL float geluf(float x) { return 0.5f * x * (1.0f + erff(x * 0.7071067811865476f)); }

DEVINL ushort_t f2bf(float f) {
  uint_t u = __float_as_uint(f);
  u += 0x7FFFu + ((u >> 16) & 1u);
  return (ushort_t)(u >> 16);
}
DEVINL float bf2f(ushort_t u) { return __uint_as_float((uint_t)u << 16); }

// async global->LDS, 16B per lane; LDS dest = wave-uniform base + lane*16,
// global src per-lane (pre-swizzled).  [m97/m104/m173 pattern]
DEVINL void glds16(const ushort_t* g, void* lds) {
  __builtin_amdgcn_global_load_lds(
      (const __attribute__((address_space(1))) void*)g,
      (__attribute__((address_space(3))) void*)lds, 16, 0, 0);
}

DEVINL float wsum(float v) {
#pragma unroll
  for (int off = 32; off; off >>= 1) v += __shfl_xor(v, off);
  return v;
}
DEVINL float bsum(float v, float* red) {
  v = wsum(v);
  int w = threadIdx.x >> 6;
  if ((threadIdx.x & 63) == 0) red[w] = v;
  __syncthreads();
  float r = red[0] + red[1] + red[2] + red[3];
  __syncthreads();
  return r;
}

// ---------------- weight/input conversion ----------------------------------
__global__ __launch_bounds__(256) void cast_kernel(const float* __restrict__ in,
                                                   ushort_t* __restrict__ out, int n8) {
  int i = blockIdx.x * 256 + threadIdx.x;
  if (i >= n8) return;
  float4 a = *(const float4*)(in + (size_t)i * 8);
  float4 b = *(const float4*)(in + (size_t)i * 8 + 4);
  bf16x8 v;
  v[0] = (short)f2bf(a.x); v[1] = (short)f2bf(a.y);
  v[2] = (short)f2bf(a.z); v[3] = (short)f2bf(a.w);
  v[4] = (short)f2bf(b.x); v[5] = (short)f2bf(b.y);
  v[6] = (short)f2bf(b.z); v[7] = (short)f2bf(b.w);
  *(bf16x8*)(out + (size_t)i * 8) = v;
}

// KxN fp32 -> NxK bf16 (batched over z)
__global__ __launch_bounds__(256) void tpose_cast_kernel(const float* __restrict__ in,
                                                         ushort_t* __restrict__ outp,
                                                         int K, int N) {
  __shared__ float t[64][65];
  const int z = blockIdx.z;
  const float* src = in + (size_t)z * K * N;
  ushort_t* dst = outp + (size_t)z * K * N;
  const int k0 = blockIdx.x * 64, n0 = blockIdx.y * 64;
  const int tx = threadIdx.x & 15, ty = threadIdx.x >> 4;
#pragma unroll
  for (int p = 0; p < 4; ++p) {
    int k = ty + p * 16;
    float4 v = *(const float4*)(src + (size_t)(k0 + k) * N + n0 + tx * 4);
    t[k][tx * 4 + 0] = v.x; t[k][tx * 4 + 1] = v.y;
    t[k][tx * 4 + 2] = v.z; t[k][tx * 4 + 3] = v.w;
  }
  __syncthreads();
#pragma unroll
  for (int p = 0; p < 4; ++p) {
    int n = ty + p * 16;
    uint_t lo = (uint_t)f2bf(t[tx * 4 + 0][n]) | ((uint_t)f2bf(t[tx * 4 + 1][n]) << 16);
    uint_t hi = (uint_t)f2bf(t[tx * 4 + 2][n]) | ((uint_t)f2bf(t[tx * 4 + 3][n]) << 16);
    *(uint2*)(dst + (size_t)(n0 + n) * K + k0 + tx * 4) = make_uint2(lo, hi);
  }
}

// ---------------- labels: cosine-sim argmax over 4 protos -------------------
__global__ __launch_bounds__(256) void labels_kernel(const float* __restrict__ x,
                                                     const float* __restrict__ protos,
                                                     int* __restrict__ lbl) {
  int t = blockIdx.x * 4 + (threadIdx.x >> 6);
  int lane = threadIdx.x & 63;
  if (t >= NTOK) return;
  const float* xr = x + (size_t)t * DIN;
  float xv[16];
  float ss = 0.f;
#pragma unroll
  for (int i = 0; i < 16; ++i) { xv[i] = xr[lane + 64 * i]; ss += xv[i] * xv[i]; }
  ss = wsum(ss);
  float nx = sqrtf(ss) + 1e-8f;
  float best = -2e30f; int bi = 0;
  for (int p = 0; p < 4; ++p) {
    const float* pr = protos + (size_t)p * DIN;
    float dp = 0.f, pp = 0.f;
#pragma unroll
    for (int i = 0; i < 16; ++i) { float v = pr[lane + 64 * i]; dp += v * xv[i]; pp += v * v; }
    dp = wsum(dp); pp = wsum(pp);
    float sim = dp / (nx * (sqrtf(pp) + 1e-8f));
    if (sim > best) { best = sim; bi = p; }
  }
  if (lane == 0) lbl[t] = bi;
}

// ================= bf16 MFMA GEMM, global_load_lds staging ==================
// C(MxN) bf16 = act(A @ B^T + bias) [+ res].  A bf16 MxK row-major,
// B bf16 NxK row-major.  SHIFT: C row remap row -> row + row/2048 + 1
// (fc1 writes straight into the cls-shifted h layout).
template <bool ACT, bool SHIFT>
__global__ __launch_bounds__(256) void mgemm_kernel(const ushort_t* __restrict__ A, int lda,
                                                    const ushort_t* __restrict__ Bw, int ldb,
                                                    const float* __restrict__ bias,
                                                    const ushort_t* __restrict__ res,
                                                    ushort_t* __restrict__ C, int ldc,
                                                    int M, int N, int K) {
  __shared__ ushort_t As[128 * 64];
  __shared__ ushort_t Bs[128 * 64];
  const int tid = threadIdx.x;
  const int l = tid & 63, l15 = l & 15, lg = l >> 4;
  const int w = tid >> 6;
  const int wm = w >> 1, wn = w & 1;
  const int bm = blockIdx.x * 128, bn = blockIdx.y * 128;
  const int srow = w * 32 + (l >> 3);
  const int scc = ((l & 7) ^ (l >> 3)) * 8;

  f32x4 acc[4][4];
#pragma unroll
  for (int i = 0; i < 4; ++i)
#pragma unroll
    for (int j = 0; j < 4; ++j) acc[i][j] = (f32x4){0.f, 0.f, 0.f, 0.f};

  const ushort_t* agp[4];
  const ushort_t* bgp[4];
#pragma unroll
  for (int j = 0; j < 4; ++j) {
    int ar = bm + srow + j * 8; if (ar > M - 1) ar = M - 1;
    agp[j] = A + (size_t)ar * lda + scc;
    bgp[j] = Bw + (size_t)(bn + srow + j * 8) * ldb + scc;
  }

  for (int k0 = 0; k0 < K; k0 += 64) {
#pragma unroll
    for (int j = 0; j < 4; ++j) {
      glds16(agp[j] + k0, (char*)As + w * 4096 + j * 1024);
      glds16(bgp[j] + k0, (char*)Bs + w * 4096 + j * 1024);
    }
    __syncthreads();
#pragma unroll
    for (int kc = 0; kc < 2; ++kc) {
      bf16x8 af[4], bfr[4];
#pragma unroll
      for (int mi = 0; mi < 4; ++mi) {
        int row = wm * 64 + mi * 16 + l15;
        af[mi] = *(const bf16x8*)((const char*)As +
                   ((row * 128 + (kc * 32 + lg * 8) * 2) ^ ((row & 7) << 4)));
      }
#pragma unroll
      for (int ni = 0; ni < 4; ++ni) {
        int row = wn * 64 + ni * 16 + l15;
        bfr[ni] = *(const bf16x8*)((const char*)Bs +
                   ((row * 128 + (kc * 32 + lg * 8) * 2) ^ ((row & 7) << 4)));
      }
#pragma unroll
      for (int mi = 0; mi < 4; ++mi)
#pragma unroll
        for (int ni = 0; ni < 4; ++ni)
          acc[mi][ni] = __builtin_amdgcn_mfma_f32_16x16x32_bf16(af[mi], bfr[ni], acc[mi][ni], 0, 0, 0);
    }
    __syncthreads();
  }

#pragma unroll
  for (int mi = 0; mi < 4; ++mi)
#pragma unroll
    for (int r = 0; r < 4; ++r) {
      int row = bm + wm * 64 + mi * 16 + lg * 4 + r;
      if (row < M) {
        int orow = SHIFT ? (row + (row >> 11) + 1) : row;
#pragma unroll
        for (int ni = 0; ni < 4; ++ni) {
          int col = bn + wn * 64 + ni * 16 + l15;
          float t = acc[mi][ni][r];
          if (bias) t += bias[col];
          if (ACT) t = geluf(t);
          if (res) t += bf2f(res[(size_t)orow * ldc + col]);
          C[(size_t)orow * ldc + col] = f2bf(t);
        }
      }
    }
}

// ---- MoE variant 1: hid = gelu(h2[tok] @ w1T[e] + b1[e]) -------------------
__global__ __launch_bounds__(256) void moe_mgemm1_kernel(const ushort_t* __restrict__ h2,
                                                         const ushort_t* __restrict__ w1T,
                                                         const float* __restrict__ b1all,
                                                         const int* __restrict__ list,
                                                         const int* __restrict__ cnt,
                                                         ushort_t* __restrict__ hid) {
  __shared__ ushort_t As[128 * 64];
  __shared__ ushort_t Bs[128 * 64];
  const int e = blockIdx.z;
  const int c0 = cnt[e * 2 + 0], c1 = cnt[e * 2 + 1];
  const ushort_t* Bw = w1T + (size_t)e * Dd * FF;
  const int tid = threadIdx.x;
  const int l = tid & 63, l15 = l & 15, lg = l >> 4;
  const int w = tid >> 6;
  const int wm = w >> 1, wn = w & 1;
  const int bm = blockIdx.x * 128, bn = blockIdx.y * 128;
  const int srow = w * 32 + (l >> 3);
  const int scc = ((l & 7) ^ (l >> 3)) * 8;

  f32x4 acc[4][4];
#pragma unroll
  for (int i = 0; i < 4; ++i)
#pragma unroll
    for (int j = 0; j < 4; ++j) acc[i][j] = (f32x4){0.f, 0.f, 0.f, 0.f};

  const ushort_t* agp[4];
  const ushort_t* bgp[4];
#pragma unroll
  for (int j = 0; j < 4; ++j) {
    int r = bm + srow + j * 8; if (r > MOE_ROWS - 1) r = MOE_ROWS - 1;
    int tok = list[e * MOE_ROWS + r] & (NTOK - 1);
    int b = tok >> 11, s = tok & (Ss - 1);
    agp[j] = h2 + (size_t)(b * S1 + s + 1) * Dd + scc;
    bgp[j] = Bw + (size_t)(bn + srow + j * 8) * Dd + scc;
  }

  for (int k0 = 0; k0 < Dd; k0 += 64) {
#pragma unroll
    for (int j = 0; j < 4; ++j) {
      glds16(agp[j] + k0, (char*)As + w * 4096 + j * 1024);
      glds16(bgp[j] + k0, (char*)Bs + w * 4096 + j * 1024);
    }
    __syncthreads();
#pragma unroll
    for (int kc = 0; kc < 2; ++kc) {
      bf16x8 af[4], bfr[4];
#pragma unroll
      for (int mi = 0; mi < 4; ++mi) {
        int row = wm * 64 + mi * 16 + l15;
        af[mi] = *(const bf16x8*)((const char*)As +
                   ((row * 128 + (kc * 32 + lg * 8) * 2) ^ ((row & 7) << 4)));
      }
#pragma unroll
      for (int ni = 0; ni < 4; ++ni) {
        int row = wn * 64 + ni * 16 + l15;
        bfr[ni] = *(const bf16x8*)((const char*)Bs +
                   ((row * 128 + (kc * 32 + lg * 8) * 2) ^ ((row & 7) << 4)));
      }
#pragma unroll
      for (int mi = 0; mi < 4; ++mi)
#pragma unroll
        for (int ni = 0; ni < 4; ++ni)
          acc[mi][ni] = __builtin_amdgcn_mfma_f32_16x16x32_bf16(af[mi], bfr[ni], acc[mi][ni], 0, 0, 0);
    }
    __syncthreads();
  }

#pragma unroll
  for (int mi = 0; mi < 4; ++mi)
#pragma unroll
    for (int rr = 0; rr < 4; ++rr) {
      int row = bm + wm * 64 + mi * 16 + lg * 4 + rr;
      bool v2 = (row < MOE_ROWS) && ((row < CAP) ? (row < c0) : ((row - CAP) < c1));
      if (v2) {
#pragma unroll
        for (int ni = 0; ni < 4; ++ni) {
          int col = bn + wn * 64 + ni * 16 + l15;
          hid[((size_t)e * MOE_ROWS + row) * FF + col] =
              f2bf(geluf(acc[mi][ni][rr] + b1all[e * FF + col]));
        }
      }
    }
}

// ---- MoE variant 2: out[tok] += topp * (hid @ w2T[e] + b2[e]) --------------
__global__ __launch_bounds__(256) void moe_mgemm2_kernel(const ushort_t* __restrict__ hid,
                                                         const ushort_t* __restrict__ w2T,
                                                         const float* __restrict__ b2all,
                                                         const int* __restrict__ list,
                                                         const int* __restrict__ cnt,
                                                         const float* __restrict__ topp,
                                                         ushort_t* __restrict__ out) {
  __shared__ ushort_t As[128 * 64];
  __shared__ ushort_t Bs[128 * 64];
  const int e = blockIdx.z;
  const int c0 = cnt[e * 2 + 0], c1 = cnt[e * 2 + 1];
  const ushort_t* Bw = w2T + (size_t)e * FF * Dd;
  const int tid = threadIdx.x;
  const int l = tid & 63, l15 = l & 15, lg = l >> 4;
  const int w = tid >> 6;
  const int wm = w >> 1, wn = w & 1;
  const int bm = blockIdx.x * 128, bn = blockIdx.y * 128;
  const int srow = w * 32 + (l >> 3);
  const int scc = ((l & 7) ^ (l >> 3)) * 8;

  f32x4 acc[4][4];
#pragma unroll
  for (int i = 0; i < 4; ++i)
#pragma unroll
    for (int j = 0; j < 4; ++j) acc[i][j] = (f32x4){0.f, 0.f, 0.f, 0.f};

  const ushort_t* agp[4];
  const ushort_t* bgp[4];
#pragma unroll
  for (int j = 0; j < 4; ++j) {
    int r = bm + srow + j * 8; if (r > MOE_ROWS - 1) r = MOE_ROWS - 1;
    agp[j] = hid + ((size_t)e * MOE_ROWS + r) * FF + scc;
    bgp[j] = Bw + (size_t)(bn + srow + j * 8) * FF + scc;
  }

  for (int k0 = 0; k0 < FF; k0 += 64) {
#pragma unroll
    for (int j = 0; j < 4; ++j) {
      glds16(agp[j] + k0, (char*)As + w * 4096 + j * 1024);
      glds16(bgp[j] + k0, (char*)Bs + w * 4096 + j * 1024);
    }
    __syncthreads();
#pragma unroll
    for (int kc = 0; kc < 2; ++kc) {
      bf16x8 af[4], bfr[4];
#pragma unroll
      for (int mi = 0; mi < 4; ++mi) {
        int row = wm * 64 + mi * 16 + l15;
        af[mi] = *(const bf16x8*)((const char*)As +
                   ((row * 128 + (kc * 32 + lg * 8) * 2) ^ ((row & 7) << 4)));
      }
#pragma unroll
      for (int ni = 0; ni < 4; ++ni) {
        int row = wn * 64 + ni * 16 + l15;
        bfr[ni] = *(const bf16x8*)((const char*)Bs +
                   ((row * 128 + (kc * 32 + lg * 8) * 2) ^ ((row & 7) << 4)));
      }
#pragma unroll
      for (int mi = 0; mi < 4; ++mi)
#pragma unroll
        for (int ni = 0; ni < 4; ++ni)
          acc[mi][ni] = __builtin_amdgcn_mfma_f32_16x16x32_bf16(af[mi], bfr[ni], acc[mi][ni], 0, 0, 0);
    }
    __syncthreads();
  }

#pragma unroll
  for (int mi = 0; mi < 4; ++mi)
#pragma unroll
    for (int rr = 0; rr < 4; ++rr) {
      int row = bm + wm * 64 + mi * 16 + lg * 4 + rr;
      bool v2 = (row < MOE_ROWS) && ((row < CAP) ? (row < c0) : ((row - CAP) < c1));
      if (v2) {
        int tok = list[e * MOE_ROWS + row];
        int b = tok >> 11, s = tok & (Ss - 1);
        float tp = topp[tok];
#pragma unroll
        for (int ni = 0; ni < 4; ++ni) {
          int col = bn + wn * 64 + ni * 16 + l15;
          size_t oidx = (size_t)(b * S1 + s + 1) * Dd + col;
          out[oidx] = f2bf(bf2f(out[oidx]) + tp * (acc[mi][ni][rr] + b2all[e * Dd + col]));
        }
      }
    }
}

// ---------------- cls rows fill (rows 0 and S1) -----------------------------
__global__ __launch_bounds__(256) void cls_fill_kernel(const float* __restrict__ cls,
                                                       ushort_t* __restrict__ h) {
  int i = threadIdx.x;
  uint_t pk = (uint_t)f2bf(cls[i * 2]) | ((uint_t)f2bf(cls[i * 2 + 1]) << 16);
  *(uint_t*)(h + i * 2) = pk;
  *(uint_t*)(h + (size_t)S1 * Dd + i * 2) = pk;
}

// ---------------- wave-per-row LayerNorm (bf16 in/out, fp32 stats) ----------
template <int EPL>
__global__ __launch_bounds__(256) void ln_wave_kernel(const ushort_t* __restrict__ in,
                                                      const ushort_t* __restrict__ addv,
                                                      const float* __restrict__ g,
                                                      const float* __restrict__ bvec,
                                                      ushort_t* __restrict__ out,
                                                      ushort_t* __restrict__ out2,
                                                      int nrows) {
  constexpr int N = 64 * EPL;
  const int row = blockIdx.x * 4 + (threadIdx.x >> 6);
  const int lane = threadIdx.x & 63;
  if (row >= nrows) return;
  const size_t base = (size_t)row * N + lane * EPL;
  float xf[EPL];
  float s1 = 0.f, s2 = 0.f;
#pragma unroll
  for (int c = 0; c < EPL / 8; ++c) {
    bf16x8 x8 = *(const bf16x8*)(in + base + c * 8);
#pragma unroll
    for (int j = 0; j < 8; ++j) {
      float v = bf2f((ushort_t)x8[j]);
      xf[c * 8 + j] = v;
      s1 += v; s2 += v * v;
    }
  }
  s1 = wsum(s1); s2 = wsum(s2);
  float mean = s1 * (1.0f / N);
  float var = s2 * (1.0f / N) - mean * mean;
  float rstd = rsqrtf(var + 1e-5f);
#pragma unroll
  for (int c = 0; c < EPL / 8; ++c) {
    bf16x8 a8;
    if (addv) a8 = *(const bf16x8*)(addv + base + c * 8);
    bf16x8 o8;
#pragma unroll
    for (int j = 0; j < 8; ++j) {
      int col = lane * EPL + c * 8 + j;
      float v = (xf[c * 8 + j] - mean) * rstd * g[col] + bvec[col];
      if (addv) v += bf2f((ushort_t)a8[j]);
      o8[j] = (short)f2bf(v);
    }
    *(bf16x8*)(out + base + c * 8) = o8;
    if (out2) *(bf16x8*)(out2 + base + c * 8) = o8;
  }
}

// ---------------- fused double-LN: out = LN2(LN1(in)+addv) ------------------
// D=512: EPL=8.  Row stays in registers through both LNs (drops one bf16
// round-trip vs the two-kernel version).
__global__ __launch_bounds__(256) void ln2_wave_kernel(const ushort_t* __restrict__ in,
                                                       const ushort_t* __restrict__ addv,
                                                       const float* __restrict__ g1,
                                                       const float* __restrict__ b1,
                                                       const float* __restrict__ g2,
                                                       const float* __restrict__ b2,
                                                       ushort_t* __restrict__ out,
                                                       ushort_t* __restrict__ out2,
                                                       int nrows) {
  constexpr int N = 512;
  const int row = blockIdx.x * 4 + (threadIdx.x >> 6);
  const int lane = threadIdx.x & 63;
  if (row >= nrows) return;
  const size_t base = (size_t)row * N + lane * 8;
  bf16x8 x8 = *(const bf16x8*)(in + base);
  bf16x8 a8 = *(const bf16x8*)(addv + base);
  float xf[8];
  float s1 = 0.f, s2 = 0.f;
#pragma unroll
  for (int j = 0; j < 8; ++j) {
    float v = bf2f((ushort_t)x8[j]);
    xf[j] = v; s1 += v; s2 += v * v;
  }
  s1 = wsum(s1); s2 = wsum(s2);
  float mean = s1 * (1.0f / N);
  float rstd = rsqrtf(s2 * (1.0f / N) - mean * mean + 1e-5f);
  float vf[8];
  float t1 = 0.f, t2 = 0.f;
#pragma unroll
  for (int j = 0; j < 8; ++j) {
    int col = lane * 8 + j;
    float v = (xf[j] - mean) * rstd * g1[col] + b1[col] + bf2f((ushort_t)a8[j]);
    vf[j] = v; t1 += v; t2 += v * v;
  }
  t1 = wsum(t1); t2 = wsum(t2);
  float mean2 = t1 * (1.0f / N);
  float rstd2 = rsqrtf(t2 * (1.0f / N) - mean2 * mean2 + 1e-5f);
  bf16x8 o8;
#pragma unroll
  for (int j = 0; j < 8; ++j) {
    int col = lane * 8 + j;
    o8[j] = (short)f2bf((vf[j] - mean2) * rstd2 * g2[col] + b2[col]);
  }
  *(bf16x8*)(out + base) = o8;
  if (out2) *(bf16x8*)(out2 + base) = o8;
}

// ---------------- MFMA bf16 flash attention, swapped-QK ---------------------
// mfma(K,Q) -> S^T: lane owns q=l15; k = kt*16 + lg*4 + r across 16 regs.
// Row-reduce: 15-op tree + 2 shfl_xor.  P transposed to PV A-frags via 16
// ds_bpermute (packed bf16 pairs) + selects — no P LDS buffer.
// exp2 path folds the 1/sqrt(dh) scale: p = exp2(s*C - m*C), C=0.125*log2(e).
__global__ __launch_bounds__(256) void attn_mfma_kernel(const ushort_t* __restrict__ qkv,
                                                        ushort_t* __restrict__ o) {
  __shared__ ushort_t Ksh[64 * 64];   // [k][d], XOR-swizzled by (k&7)<<4
  __shared__ ushort_t Vt[64 * 64];    // [d][k], XOR-swizzled by (d&7)<<4
  const int tid = threadIdx.x;
  const int w = tid >> 6, l = tid & 63;
  const int l15 = l & 15, lg = l >> 4;
  const int hh = blockIdx.y, b = blockIdx.z;
  const int qblk = blockIdx.x * 64;
  const size_t rbase = (size_t)b * S1 * 1536;
  const float CEXP = 0.125f * 1.4426950408889634f;

  bf16x8 aq[2];
  {
    int qr = qblk + w * 16 + l15;
    const ushort_t* qp = qkv + rbase + (size_t)qr * 1536 + hh * 64;
#pragma unroll
    for (int dc = 0; dc < 2; ++dc)
      aq[dc] = (qr < S1) ? *(const bf16x8*)(qp + dc * 32 + lg * 8)
                         : (bf16x8){0, 0, 0, 0, 0, 0, 0, 0};
  }

  f32x4 ovac[4];
#pragma unroll
  for (int dt = 0; dt < 4; ++dt) ovac[dt] = (f32x4){0.f, 0.f, 0.f, 0.f};
  float m_r = -1e30f, l_r = 0.f;

  const int sk_r = tid >> 3, sk_c = tid & 7;
  const int sv_k0 = (tid & 31) * 2, sv_d0 = (tid >> 5) * 8;

  for (int c = 0; c < 33; ++c) {
    // ---- stage K ----
#pragma unroll
    for (int pass = 0; pass < 2; ++pass) {
      int r = sk_r + pass * 32;
      int key = c * 64 + r;
      bf16x8 v;
      if (key < S1)
        v = *(const bf16x8*)(qkv + rbase + (size_t)key * 1536 + 512 + hh * 64 + sk_c * 8);
      else
        v = (bf16x8){0, 0, 0, 0, 0, 0, 0, 0};
      *(bf16x8*)((char*)Ksh + (((r * 64 + sk_c * 8) * 2) ^ ((r & 7) << 4))) = v;
    }
    // ---- stage V transposed (pack key pairs) ----
    {
      int key0 = c * 64 + sv_k0;
      const ushort_t* vp = qkv + rbase + (size_t)key0 * 1536 + 1024 + hh * 64 + sv_d0;
      bf16x8 va, vb;
      if (key0 < S1) va = *(const bf16x8*)(vp);
      else va = (bf16x8){0, 0, 0, 0, 0, 0, 0, 0};
      if (key0 + 1 < S1) vb = *(const bf16x8*)(vp + 1536);
      else vb = (bf16x8){0, 0, 0, 0, 0, 0, 0, 0};
#pragma unroll
      for (int i = 0; i < 8; ++i) {
        uint_t pk = (uint_t)(ushort_t)va[i] | ((uint_t)(ushort_t)vb[i] << 16);
        int d = sv_d0 + i;
        *(uint_t*)((char*)Vt + (((d * 64 + sv_k0) * 2) ^ ((d & 7) << 4))) = pk;
      }
    }
    __syncthreads();

    // ---- S^T = K·Q^T ----
    f32x4 s[4];
    __builtin_amdgcn_s_setprio(1);
#pragma unroll
    for (int kt = 0; kt < 4; ++kt) {
      f32x4 acc = (f32x4){0.f, 0.f, 0.f, 0.f};
      const int krow = kt * 16 + l15;
      const int rswz = (krow & 7) << 4;
#pragma unroll
      for (int dc = 0; dc < 2; ++dc) {
        bf16x8 kb = *(const bf16x8*)((const char*)Ksh + (((krow * 64 + dc * 32 + lg * 8) * 2) ^ rswz));
        acc = __builtin_amdgcn_mfma_f32_16x16x32_bf16(kb, aq[dc], acc, 0, 0, 0);
      }
      s[kt] = acc;
    }
    __builtin_amdgcn_s_setprio(0);
    if (c == 32) {          // only the last chunk is partial (2048 valid keys before)
#pragma unroll
      for (int kt = 0; kt < 4; ++kt)
#pragma unroll
        for (int r = 0; r < 4; ++r)
          if (2048 + kt * 16 + lg * 4 + r >= S1) s[kt][r] = -1e30f;
    }

    // ---- online softmax (lane-local row) ----
    f32x4 m4 = (f32x4){fmaxf(s[0][0], s[1][0]), fmaxf(s[0][1], s[1][1]),
                       fmaxf(s[0][2], s[1][2]), fmaxf(s[0][3], s[1][3])};
#pragma unroll
    for (int r = 0; r < 4; ++r) m4[r] = fmaxf(m4[r], fmaxf(s[2][r], s[3][r]));
    float mx = fmaxf(fmaxf(m4[0], m4[1]), fmaxf(m4[2], m4[3]));
    mx = fmaxf(mx, __shfl_xor(mx, 16));
    mx = fmaxf(mx, __shfl_xor(mx, 32));
    float mn = fmaxf(m_r, mx);
    float fac = __builtin_amdgcn_exp2f((m_r - mn) * CEXP);
    m_r = mn;
    float mc = mn * CEXP;
    float p[4][4];
    float rs = 0.f;
#pragma unroll
    for (int kt = 0; kt < 4; ++kt)
#pragma unroll
      for (int r = 0; r < 4; ++r) {
        float pv = __builtin_amdgcn_exp2f(s[kt][r] * CEXP - mc);
        p[kt][r] = pv;
        rs += pv;
      }
    rs += __shfl_xor(rs, 16);
    rs += __shfl_xor(rs, 32);
    l_r = l_r * fac + rs;

    // ---- pack P to bf16 pairs (source layout) ----
    uint_t pk[4][2];
#pragma unroll
    for (int kt = 0; kt < 4; ++kt) {
      pk[kt][0] = (uint_t)f2bf(p[kt][0]) | ((uint_t)f2bf(p[kt][1]) << 16);
      pk[kt][1] = (uint_t)f2bf(p[kt][2]) | ((uint_t)f2bf(p[kt][3]) << 16);
    }

    // ---- rescale O (fac per ovac row q=lg*4+r, fetched from lane q) ----
    float facq[4];
#pragma unroll
    for (int r = 0; r < 4; ++r) facq[r] = __shfl(fac, lg * 4 + r);
#pragma unroll
    for (int dt = 0; dt < 4; ++dt)
#pragma unroll
      for (int r = 0; r < 4; ++r) ovac[dt][r] *= facq[r];

    // ---- in-register transpose: P -> PV A-frags ----
    bf16x8 pa[2];
#pragma unroll
    for (int kh = 0; kh < 2; ++kh) {
      union { uint_t u[4]; bf16x8 v; } cu;
#pragma unroll
      for (int wd = 0; wd < 4; ++wd) {
        int src = (((2 * lg + (wd >> 1)) & 3) << 4) + l15;
        uint_t c0 = (uint_t)__shfl((int)pk[kh * 2 + 0][wd & 1], src);
        uint_t c1 = (uint_t)__shfl((int)pk[kh * 2 + 1][wd & 1], src);
        cu.u[wd] = (lg & 2) ? c1 : c0;
      }
      pa[kh] = cu.v;
    }

    // ---- O += P @ V ----
    __builtin_amdgcn_s_setprio(1);
#pragma unroll
    for (int kh = 0; kh < 2; ++kh)
#pragma unroll
      for (int dt = 0; dt < 4; ++dt) {
        const int vrow = dt * 16 + l15;
        bf16x8 vb = *(const bf16x8*)((const char*)Vt +
                      (((vrow * 64 + kh * 32 + lg * 8) * 2) ^ ((vrow & 7) << 4)));
        ovac[dt] = __builtin_amdgcn_mfma_f32_16x16x32_bf16(pa[kh], vb, ovac[dt], 0, 0, 0);
      }
    __builtin_amdgcn_s_setprio(0);
    __syncthreads();
  }

  float invq[4];
#pragma unroll
  for (int r = 0; r < 4; ++r) invq[r] = 1.0f / __shfl(l_r, lg * 4 + r);
#pragma unroll
  for (int r = 0; r < 4; ++r) {
    int qq = qblk + w * 16 + lg * 4 + r;
    if (qq < S1) {
      ushort_t* orow = o + (size_t)(b * S1 + qq) * Dd + hh * 64;
#pragma unroll
      for (int dt = 0; dt < 4; ++dt) orow[dt * 16 + l15] = f2bf(ovac[dt][r] * invq[r]);
    }
  }
}

// ---------------- gate softmax + top1 routing info (bf16 h) -----------------
__global__ __launch_bounds__(256) void gate_kernel(const ushort_t* __restrict__ h2,
                                                   const float* __restrict__ gw,
                                                   float* __restrict__ gate_out,
                                                   float* __restrict__ topp,
                                                   int* __restrict__ idx) {
  int t = blockIdx.x * 4 + (threadIdx.x >> 6);
  int lane = threadIdx.x & 63;
  if (t >= NTOK) return;
  int b = t >> 11, s = t & (Ss - 1);
  const ushort_t* hr = h2 + (size_t)(b * S1 + s + 1) * Dd;
  bf16x8 h8 = *(const bf16x8*)(hr + lane * 8);
  float acc[6] = {};
#pragma unroll
  for (int j = 0; j < 8; ++j) {
    int d = lane * 8 + j;
    float xv = bf2f((ushort_t)h8[j]);
    const float* g = gw + (size_t)d * Ee;
#pragma unroll
    for (int e = 0; e < 6; ++e) acc[e] += xv * g[e];
  }
#pragma unroll
  for (int e = 0; e < 6; ++e) acc[e] = wsum(acc[e]);
  if (lane == 0) {
    float mx = acc[0];
#pragma unroll
    for (int e = 1; e < 6; ++e) mx = fmaxf(mx, acc[e]);
    float ex[6], sum = 0.f;
#pragma unroll
    for (int e = 0; e < 6; ++e) { ex[e] = __expf(acc[e] - mx); sum += ex[e]; }
    float invs = 1.0f / sum;
    int best = 0; float bp = ex[0];
#pragma unroll
    for (int e = 1; e < 6; ++e) { if (ex[e] > bp) { bp = ex[e]; best = e; } }
#pragma unroll
    for (int e = 0; e < 6; ++e) gate_out[(size_t)t * Ee + e] = ex[e] * invs;
    topp[t] = bp * invs;
    idx[t] = best;
  }
}

// ---------------- capacity-limited top-1 router (parallel scan) -------------
__global__ __launch_bounds__(256) void route_kernel(const int* __restrict__ idx,
                                                    int* __restrict__ list,
                                                    int* __restrict__ cnt) {
  __shared__ int cnts[256];
  __shared__ int tot;
  const int e = blockIdx.x, b = blockIdx.y;
  const int tid = threadIdx.x;
  const int s0 = tid * 8;
  int loc[8];
  int c = 0;
#pragma unroll
  for (int j = 0; j < 8; ++j) {
    int t = b * Ss + s0 + j;
    if (idx[t] == e) loc[c++] = t;
  }
  cnts[tid] = c;
  __syncthreads();
  if (tid == 0) {
    int run = 0;
    for (int i = 0; i < 256; ++i) { int v = cnts[i]; cnts[i] = run; run += v; }
    tot = run;
  }
  __syncthreads();
  int base = cnts[tid];
  for (int j = 0; j < c; ++j) {
    int pos = base + j;
    if (pos < CAP) list[e * MOE_ROWS + b * CAP + pos] = loc[j];
  }
  if (tid == 0) cnt[e * Bb + b] = (tot < CAP) ? tot : CAP;
}

// ---------------- cls-token sub-LN FFN, parallelized over columns -----------
__global__ __launch_bounds__(256) void cls_ffn1_kernel(const ushort_t* __restrict__ h2,
                                                       const float* __restrict__ w1,
                                                       const float* __restrict__ b1,
                                                       float* __restrict__ chid) {
  __shared__ float hrow[Dd];
  const int b = blockIdx.y, tid = threadIdx.x;
  const int col = blockIdx.x * 256 + tid;
  const ushort_t* hr = h2 + (size_t)(b * S1) * Dd;
  hrow[tid] = bf2f(hr[tid]);
  hrow[tid + 256] = bf2f(hr[tid + 256]);
  __syncthreads();
  float acc = b1[col];
  for (int d = 0; d < Dd; ++d) acc += hrow[d] * w1[(size_t)d * FF + col];
  chid[b * FF + col] = geluf(acc);
}

__global__ __launch_bounds__(256) void cls_ffn2_kernel(const float* __restrict__ chid,
                                                       const float* __restrict__ lg,
                                                       const float* __restrict__ lb,
                                                       const float* __restrict__ w2,
                                                       const float* __restrict__ b2,
                                                       ushort_t* __restrict__ outbuf) {
  __shared__ float hln[FF];
  __shared__ float red[8];
  const int b = blockIdx.y, tid = threadIdx.x;
  const int col = blockIdx.x * 256 + tid;
  const float* hr = chid + b * FF;
  float hv[8];
  float s1 = 0.f, s2 = 0.f;
#pragma unroll
  for (int j = 0; j < 8; ++j) {
    hv[j] = hr[tid + j * 256];
    s1 += hv[j]; s2 += hv[j] * hv[j];
  }
  s1 = bsum(s1, red);
  s2 = bsum(s2, red);
  float mean = s1 * (1.0f / FF);
  float var = s2 * (1.0f / FF) - mean * mean;
  float rstd = rsqrtf(var + 1e-5f);
#pragma unroll
  for (int j = 0; j < 8; ++j) {
    int k = tid + j * 256;
    hln[k] = (hv[j] - mean) * rstd * lg[k] + lb[k];
  }
  __syncthreads();
  float acc = b2[col];
  for (int k = 0; k < FF; ++k) acc += hln[k] * w2[(size_t)k * Dd + col];
  size_t oidx = (size_t)(b * S1) * Dd + col;
  outbuf[oidx] = f2bf(bf2f(outbuf[oidx]) + acc);
}

// ---------------- loss ------------------------------------------------------
__global__ __launch_bounds__(256) void loss_part_kernel(const float* __restrict__ gate,
                                                        const int* __restrict__ lbl,
                                                        float* __restrict__ part) {
  __shared__ float red[8];
  int t = blockIdx.x * 256 + threadIdx.x;
  float v = 0.f;
  if (t < NTOK) {
    const float* p = gate + (size_t)t * Ee;
    float sum = p[0] + p[1] + p[2] + p[3];
    float pl = p[lbl[t]];
    v = -logf(pl / sum + 1e-9f);
  }
  v = bsum(v, red);
  if (threadIdx.x == 0) part[blockIdx.x] = v;
}

__global__ void loss_final_kernel(const float* __restrict__ part, float* __restrict__ out) {
  if (threadIdx.x == 0) {
    float s = 0.f;
    for (int i = 0; i < 16; ++i) s += part[i];
    out[NTOK * Ee + Bb * NCc] = s / (float)NTOK;
  }
}

// ---------------- final LN + logits ----------------------------------------
__global__ __launch_bounds__(256) void final_head_kernel(const ushort_t* __restrict__ h,
                                                         const float* __restrict__ g,
                                                         const float* __restrict__ bvec,
                                                         const float* __restrict__ w,
                                                         const float* __restrict__ fb,
                                                         float* __restrict__ out) {
  __shared__ float red[8];
  int b = blockIdx.x, tid = threadIdx.x;
  const ushort_t* hr = h + (size_t)(b * S1) * Dd;
  float x0 = bf2f(hr[tid]), x1 = bf2f(hr[tid + 256]);
  float s1 = bsum(x0 + x1, red);
  float s2 = bsum(x0 * x0 + x1 * x1, red);
  float mean = s1 * (1.0f / Dd);
  float var = s2 * (1.0f / Dd) - mean * mean;
  float rstd = rsqrtf(var + 1e-5f);
  float p0 = (x0 - mean) * rstd * g[tid] + bvec[tid];
  float p1 = (x1 - mean) * rstd * g[tid + 256] + bvec[tid + 256];
  float l0 = p0 * w[tid * 2 + 0] + p1 * w[(tid + 256) * 2 + 0];
  float l1 = p0 * w[tid * 2 + 1] + p1 * w[(tid + 256) * 2 + 1];
  l0 = bsum(l0, red);
  l1 = bsum(l1, red);
  if (tid == 0) {
    out[NTOK * Ee + b * NCc + 0] = l0 + fb[0];
    out[NTOK * Ee + b * NCc + 1] = l1 + fb[1];
  }
}

// ============================================================================
extern "C" void kernel_launch(void* const* d_in, const int* in_sizes, int n_in,
                              void* d_out, int out_size, void* d_ws, size_t ws_size,
                              hipStream_t stream) {
  (void)in_sizes; (void)n_in; (void)out_size; (void)ws_size;
  const float* x       = (const float*)d_in[0];
  const float* protos  = (const float*)d_in[1];
  const float* cls_tok = (const float*)d_in[2];
  const float* fc1_w   = (const float*)d_in[3];
  const float* fc1_b   = (const float*)d_in[4];
  const float* a0_in_w = (const float*)d_in[5];
  const float* a0_in_b = (const float*)d_in[6];
  const float* a0_out_w= (const float*)d_in[7];
  const float* a0_out_b= (const float*)d_in[8];
  const float* n1g0    = (const float*)d_in[9];
  const float* n1b0    = (const float*)d_in[10];
  const float* n2g0    = (const float*)d_in[11];
  const float* n2b0    = (const float*)d_in[12];
  const float* a1_in_w = (const float*)d_in[13];
  const float* a1_in_b = (const float*)d_in[14];
  const float* a1_out_w= (const float*)d_in[15];
  const float* a1_out_b= (const float*)d_in[16];
  const float* n1g1    = (const float*)d_in[17];
  const float* n1b1    = (const float*)d_in[18];
  const float* n2g1    = (const float*)d_in[19];
  const float* n2b1    = (const float*)d_in[20];
  const float* cw1     = (const float*)d_in[21];
  const float* cb1     = (const float*)d_in[22];
  const float* clg     = (const float*)d_in[23];
  const float* clb     = (const float*)d_in[24];
  const float* cw2     = (const float*)d_in[25];
  const float* cb2     = (const float*)d_in[26];
  const float* gate_w  = (const float*)d_in[27];
  const float* ew1     = (const float*)d_in[28];
  const float* eb1     = (const float*)d_in[29];
  const float* ew2     = (const float*)d_in[30];
  const float* eb2     = (const float*)d_in[31];
  const float* fw1     = (const float*)d_in[32];
  const float* fb1     = (const float*)d_in[33];
  const float* flg     = (const float*)d_in[34];
  const float* flb     = (const float*)d_in[35];
  const float* fw2     = (const float*)d_in[36];
  const float* fb2     = (const float*)d_in[37];
  const float* ng      = (const float*)d_in[38];
  const float* nb      = (const float*)d_in[39];
  const float* fc2_w   = (const float*)d_in[40];
  const float* fc2_b   = (const float*)d_in[41];
  float* out = (float*)d_out;

  char* base = (char*)d_ws;
  size_t o = 0;
  auto alloc = [&](size_t bytes) -> void* {
    void* p = base + o;
    o += (bytes + 255) & ~(size_t)255;
    return p;
  };
  ushort_t* UB0  = (ushort_t*)alloc((size_t)RR * Dd * 2);
  ushort_t* UB1  = (ushort_t*)alloc((size_t)RR * Dd * 2);
  ushort_t* UB2  = (ushort_t*)alloc((size_t)RR * Dd * 2);
  ushort_t* BIGU = (ushort_t*)alloc((size_t)RR * FF * 2);
  ushort_t* XB   = (ushort_t*)alloc((size_t)NTOK * DIN * 2);
  ushort_t* WQ0  = (ushort_t*)alloc((size_t)3 * Dd * Dd * 2);
  ushort_t* WO0  = (ushort_t*)alloc((size_t)Dd * Dd * 2);
  ushort_t* WQ1  = (ushort_t*)alloc((size_t)3 * Dd * Dd * 2);
  ushort_t* WO1  = (ushort_t*)alloc((size_t)Dd * Dd * 2);
  ushort_t* WF1T = (ushort_t*)alloc((size_t)Dd * DIN * 2);
  ushort_t* WE1T = (ushort_t*)alloc((size_t)Ee * FF * Dd * 2);
  ushort_t* WE2T = (ushort_t*)alloc((size_t)Ee * Dd * FF * 2);
  ushort_t* WFW1T= (ushort_t*)alloc((size_t)FF * Dd * 2);
  ushort_t* WFW2T= (ushort_t*)alloc((size_t)Dd * FF * 2);
  float* TOPP = (float*)alloc(NTOK * 4);
  float* PART = (float*)alloc(64 * 4);
  float* CHID = (float*)alloc(Bb * FF * 4);
  int* LBL  = (int*)alloc(NTOK * 4);
  int* IDX  = (int*)alloc(NTOK * 4);
  int* LIST = (int*)alloc(Ee * MOE_ROWS * 4);
  int* CNT  = (int*)alloc(Ee * Bb * 4);

  const int ln_grid = (RR + 3) / 4;

  // ---- one-shot conversions (bf16, unified NxK) ----
  cast_kernel<<<(NTOK * DIN / 8 + 255) / 256, 256, 0, stream>>>(x, XB, NTOK * DIN / 8);
  cast_kernel<<<(3 * Dd * Dd / 8 + 255) / 256, 256, 0, stream>>>(a0_in_w, WQ0, 3 * Dd * Dd / 8);
  cast_kernel<<<(Dd * Dd / 8 + 255) / 256, 256, 0, stream>>>(a0_out_w, WO0, Dd * Dd / 8);
  cast_kernel<<<(3 * Dd * Dd / 8 + 255) / 256, 256, 0, stream>>>(a1_in_w, WQ1, 3 * Dd * Dd / 8);
  cast_kernel<<<(Dd * Dd / 8 + 255) / 256, 256, 0, stream>>>(a1_out_w, WO1, Dd * Dd / 8);
  tpose_cast_kernel<<<dim3(DIN / 64, Dd / 64, 1), 256, 0, stream>>>(fc1_w, WF1T, DIN, Dd);
  tpose_cast_kernel<<<dim3(Dd / 64, FF / 64, Ee), 256, 0, stream>>>(ew1, WE1T, Dd, FF);
  tpose_cast_kernel<<<dim3(FF / 64, Dd / 64, Ee), 256, 0, stream>>>(ew2, WE2T, FF, Dd);
  tpose_cast_kernel<<<dim3(Dd / 64, FF / 64, 1), 256, 0, stream>>>(fw1, WFW1T, Dd, FF);
  tpose_cast_kernel<<<dim3(FF / 64, Dd / 64, 1), 256, 0, stream>>>(fw2, WFW2T, FF, Dd);

  // 1. labels
  labels_kernel<<<NTOK / 4, 256, 0, stream>>>(x, protos, LBL);
  // 2. fc1 writes straight into shifted h layout (UB0); cls rows filled apart
  mgemm_kernel<false, true><<<dim3(32, 4), 256, 0, stream>>>(
      XB, DIN, WF1T, DIN, fc1_b, nullptr, UB0, Dd, NTOK, Dd, DIN);
  cls_fill_kernel<<<1, 256, 0, stream>>>(cls_tok, UB0);

  // ---- layer 0 attention ----
  mgemm_kernel<false, false><<<dim3(33, 12), 256, 0, stream>>>(
      UB0, Dd, WQ0, Dd, a0_in_b, nullptr, BIGU, 3 * Dd, RR, 3 * Dd, Dd);
  attn_mfma_kernel<<<dim3(33, Hh, Bb), 256, 0, stream>>>(BIGU, UB1);
  mgemm_kernel<false, false><<<dim3(33, 4), 256, 0, stream>>>(
      UB1, Dd, WO0, Dd, a0_out_b, nullptr, UB2, Dd, RR, Dd, Dd);
  // h2 = LN2(LN1(UB0)+UB2) -> UB0 (+UB2 as h_res), fused
  ln2_wave_kernel<<<ln_grid, 256, 0, stream>>>(UB0, UB2, n1g0, n1b0, n2g0, n2b0, UB0, UB2, RR);

  // ---- cls ffn, gate, route, moe ----
  cls_ffn1_kernel<<<dim3(FF / 256, Bb), 256, 0, stream>>>(UB0, cw1, cb1, CHID);
  cls_ffn2_kernel<<<dim3(Dd / 256, Bb), 256, 0, stream>>>(CHID, clg, clb, cw2, cb2, UB2);
  gate_kernel<<<NTOK / 4, 256, 0, stream>>>(UB0, gate_w, out, TOPP, IDX);
  route_kernel<<<dim3(Ee, Bb), 256, 0, stream>>>(IDX, LIST, CNT);
  moe_mgemm1_kernel<<<dim3(6, 16, Ee), 256, 0, stream>>>(UB0, WE1T, eb1, LIST, CNT, BIGU);
  moe_mgemm2_kernel<<<dim3(6, 4, Ee), 256, 0, stream>>>(BIGU, WE2T, eb2, LIST, CNT, TOPP, UB2);
  loss_part_kernel<<<16, 256, 0, stream>>>(out, LBL, PART);
  loss_final_kernel<<<1, 64, 0, stream>>>(PART, out);

  // ---- layer 1 attention ----
  mgemm_kernel<false, false><<<dim3(33, 12), 256, 0, stream>>>(
      UB2, Dd, WQ1, Dd, a1_in_b, nullptr, BIGU, 3 * Dd, RR, 3 * Dd, Dd);
  attn_mfma_kernel<<<dim3(33, Hh, Bb), 256, 0, stream>>>(BIGU, UB1);
  mgemm_kernel<false, false><<<dim3(33, 4), 256, 0, stream>>>(
      UB1, Dd, WO1, Dd, a1_out_b, nullptr, UB0, Dd, RR, Dd, Dd);
  // h = LN2(LN1(UB2)+UB0) -> UB2, fused
  ln2_wave_kernel<<<ln_grid, 256, 0, stream>>>(UB2, UB0, n1g1, n1b1, n2g1, n2b1, UB2, nullptr, RR);

  // ---- layer 1 FFN (sub-LN) with residual ----
  mgemm_kernel<true, false><<<dim3(33, 16), 256, 0, stream>>>(
      UB2, Dd, WFW1T, Dd, fb1, nullptr, BIGU, FF, RR, FF, Dd);
  ln_wave_kernel<32><<<ln_grid, 256, 0, stream>>>(BIGU, nullptr, flg, flb, BIGU, nullptr, RR);
  mgemm_kernel<false, false><<<dim3(33, 4), 256, 0, stream>>>(
      BIGU, FF, WFW2T, FF, fb2, UB2, UB0, Dd, RR, Dd, FF);

  // ---- head ----
  final_head_kernel<<<Bb, 256, 0, stream>>>(UB0, ng, nb, fc2_w, fc2_b, out);
}

// Round 8
// 572.202 us; speedup vs baseline: 8.2141x; 1.0922x over previous
//
#include <hip/hip_runtime.h>
#include <cmath>

#define DEVINL __device__ __forceinline__

typedef unsigned short ushort_t;
typedef unsigned int uint_t;

constexpr int Bb   = 2;
constexpr int Ss   = 2048;
constexpr int S1   = 2049;
constexpr int DIN  = 1024;
constexpr int Dd   = 512;
constexpr int Hh   = 8;
constexpr int FF   = 2048;
constexpr int Ee   = 6;
constexpr int NCc  = 2;
constexpr int CAP  = 341;
constexpr int NTOK = Bb * Ss;     // 4096
constexpr int RR   = Bb * S1;     // 4098
constexpr int MOE_ROWS = Bb * CAP; // 682

typedef __attribute__((ext_vector_type(4))) float f32x4;
typedef __attribute__((ext_vector_type(8))) short bf16x8;

DEVINL float geluf(float x) { return 0.5f * x * (1.0f + erff(x * 0.7071067811865476f)); }

DEVINL ushort_t f2bf(float f) {
  uint_t u = __float_as_uint(f);
  u += 0x7FFFu + ((u >> 16) & 1u);
  return (ushort_t)(u >> 16);
}
DEVINL float bf2f(ushort_t u) { return __uint_as_float((uint_t)u << 16); }

// async global->LDS, 16B per lane; LDS dest = wave-uniform base + lane*16,
// global src per-lane (pre-swizzled).  [m97/m104/m173 pattern]
DEVINL void glds16(const ushort_t* g, void* lds) {
  __builtin_amdgcn_global_load_lds(
      (const __attribute__((address_space(1))) void*)g,
      (__attribute__((address_space(3))) void*)lds, 16, 0, 0);
}

DEVINL float wsum(float v) {
#pragma unroll
  for (int off = 32; off; off >>= 1) v += __shfl_xor(v, off);
  return v;
}
DEVINL float bsum(float v, float* red) {
  v = wsum(v);
  int w = threadIdx.x >> 6;
  if ((threadIdx.x & 63) == 0) red[w] = v;
  __syncthreads();
  float r = red[0] + red[1] + red[2] + red[3];
  __syncthreads();
  return r;
}

// ---------------- weight/input conversion ----------------------------------
__global__ __launch_bounds__(256) void cast_kernel(const float* __restrict__ in,
                                                   ushort_t* __restrict__ out, int n8) {
  int i = blockIdx.x * 256 + threadIdx.x;
  if (i >= n8) return;
  float4 a = *(const float4*)(in + (size_t)i * 8);
  float4 b = *(const float4*)(in + (size_t)i * 8 + 4);
  bf16x8 v;
  v[0] = (short)f2bf(a.x); v[1] = (short)f2bf(a.y);
  v[2] = (short)f2bf(a.z); v[3] = (short)f2bf(a.w);
  v[4] = (short)f2bf(b.x); v[5] = (short)f2bf(b.y);
  v[6] = (short)f2bf(b.z); v[7] = (short)f2bf(b.w);
  *(bf16x8*)(out + (size_t)i * 8) = v;
}

// KxN fp32 -> NxK bf16 (batched over z)
__global__ __launch_bounds__(256) void tpose_cast_kernel(const float* __restrict__ in,
                                                         ushort_t* __restrict__ outp,
                                                         int K, int N) {
  __shared__ float t[64][65];
  const int z = blockIdx.z;
  const float* src = in + (size_t)z * K * N;
  ushort_t* dst = outp + (size_t)z * K * N;
  const int k0 = blockIdx.x * 64, n0 = blockIdx.y * 64;
  const int tx = threadIdx.x & 15, ty = threadIdx.x >> 4;
#pragma unroll
  for (int p = 0; p < 4; ++p) {
    int k = ty + p * 16;
    float4 v = *(const float4*)(src + (size_t)(k0 + k) * N + n0 + tx * 4);
    t[k][tx * 4 + 0] = v.x; t[k][tx * 4 + 1] = v.y;
    t[k][tx * 4 + 2] = v.z; t[k][tx * 4 + 3] = v.w;
  }
  __syncthreads();
#pragma unroll
  for (int p = 0; p < 4; ++p) {
    int n = ty + p * 16;
    uint_t lo = (uint_t)f2bf(t[tx * 4 + 0][n]) | ((uint_t)f2bf(t[tx * 4 + 1][n]) << 16);
    uint_t hi = (uint_t)f2bf(t[tx * 4 + 2][n]) | ((uint_t)f2bf(t[tx * 4 + 3][n]) << 16);
    *(uint2*)(dst + (size_t)(n0 + n) * K + k0 + tx * 4) = make_uint2(lo, hi);
  }
}

// ---------------- labels: cosine-sim argmax over 4 protos -------------------
__global__ __launch_bounds__(256) void labels_kernel(const float* __restrict__ x,
                                                     const float* __restrict__ protos,
                                                     int* __restrict__ lbl) {
  int t = blockIdx.x * 4 + (threadIdx.x >> 6);
  int lane = threadIdx.x & 63;
  if (t >= NTOK) return;
  const float* xr = x + (size_t)t * DIN;
  float xv[16];
  float ss = 0.f;
#pragma unroll
  for (int i = 0; i < 16; ++i) { xv[i] = xr[lane + 64 * i]; ss += xv[i] * xv[i]; }
  ss = wsum(ss);
  float nx = sqrtf(ss) + 1e-8f;
  float best = -2e30f; int bi = 0;
  for (int p = 0; p < 4; ++p) {
    const float* pr = protos + (size_t)p * DIN;
    float dp = 0.f, pp = 0.f;
#pragma unroll
    for (int i = 0; i < 16; ++i) { float v = pr[lane + 64 * i]; dp += v * xv[i]; pp += v * v; }
    dp = wsum(dp); pp = wsum(pp);
    float sim = dp / (nx * (sqrtf(pp) + 1e-8f));
    if (sim > best) { best = sim; bi = p; }
  }
  if (lane == 0) lbl[t] = bi;
}

// ================= bf16 MFMA GEMM, global_load_lds staging ==================
// C(MxN) bf16 = act(A @ B^T + bias) [+ res].  A bf16 MxK row-major,
// B bf16 NxK row-major.  SHIFT: C row remap row -> row + row/2048 + 1.
template <bool ACT, bool SHIFT>
__global__ __launch_bounds__(256) void mgemm_kernel(const ushort_t* __restrict__ A, int lda,
                                                    const ushort_t* __restrict__ Bw, int ldb,
                                                    const float* __restrict__ bias,
                                                    const ushort_t* __restrict__ res,
                                                    ushort_t* __restrict__ C, int ldc,
                                                    int M, int N, int K) {
  __shared__ ushort_t As[128 * 64];
  __shared__ ushort_t Bs[128 * 64];
  const int tid = threadIdx.x;
  const int l = tid & 63, l15 = l & 15, lg = l >> 4;
  const int w = tid >> 6;
  const int wm = w >> 1, wn = w & 1;
  const int bm = blockIdx.x * 128, bn = blockIdx.y * 128;
  const int srow = w * 32 + (l >> 3);
  const int scc = ((l & 7) ^ (l >> 3)) * 8;

  f32x4 acc[4][4];
#pragma unroll
  for (int i = 0; i < 4; ++i)
#pragma unroll
    for (int j = 0; j < 4; ++j) acc[i][j] = (f32x4){0.f, 0.f, 0.f, 0.f};

  const ushort_t* agp[4];
  const ushort_t* bgp[4];
#pragma unroll
  for (int j = 0; j < 4; ++j) {
    int ar = bm + srow + j * 8; if (ar > M - 1) ar = M - 1;
    agp[j] = A + (size_t)ar * lda + scc;
    bgp[j] = Bw + (size_t)(bn + srow + j * 8) * ldb + scc;
  }

  for (int k0 = 0; k0 < K; k0 += 64) {
#pragma unroll
    for (int j = 0; j < 4; ++j) {
      glds16(agp[j] + k0, (char*)As + w * 4096 + j * 1024);
      glds16(bgp[j] + k0, (char*)Bs + w * 4096 + j * 1024);
    }
    __syncthreads();
#pragma unroll
    for (int kc = 0; kc < 2; ++kc) {
      bf16x8 af[4], bfr[4];
#pragma unroll
      for (int mi = 0; mi < 4; ++mi) {
        int row = wm * 64 + mi * 16 + l15;
        af[mi] = *(const bf16x8*)((const char*)As +
                   ((row * 128 + (kc * 32 + lg * 8) * 2) ^ ((row & 7) << 4)));
      }
#pragma unroll
      for (int ni = 0; ni < 4; ++ni) {
        int row = wn * 64 + ni * 16 + l15;
        bfr[ni] = *(const bf16x8*)((const char*)Bs +
                   ((row * 128 + (kc * 32 + lg * 8) * 2) ^ ((row & 7) << 4)));
      }
#pragma unroll
      for (int mi = 0; mi < 4; ++mi)
#pragma unroll
        for (int ni = 0; ni < 4; ++ni)
          acc[mi][ni] = __builtin_amdgcn_mfma_f32_16x16x32_bf16(af[mi], bfr[ni], acc[mi][ni], 0, 0, 0);
    }
    __syncthreads();
  }

#pragma unroll
  for (int mi = 0; mi < 4; ++mi)
#pragma unroll
    for (int r = 0; r < 4; ++r) {
      int row = bm + wm * 64 + mi * 16 + lg * 4 + r;
      if (row < M) {
        int orow = SHIFT ? (row + (row >> 11) + 1) : row;
#pragma unroll
        for (int ni = 0; ni < 4; ++ni) {
          int col = bn + wn * 64 + ni * 16 + l15;
          float t = acc[mi][ni][r];
          if (bias) t += bias[col];
          if (ACT) t = geluf(t);
          if (res) t += bf2f(res[(size_t)orow * ldc + col]);
          C[(size_t)orow * ldc + col] = f2bf(t);
        }
      }
    }
}

// ---- MoE variant 1: hid = gelu(h2[tok] @ w1T[e] + b1[e]) -------------------
__global__ __launch_bounds__(256) void moe_mgemm1_kernel(const ushort_t* __restrict__ h2,
                                                         const ushort_t* __restrict__ w1T,
                                                         const float* __restrict__ b1all,
                                                         const int* __restrict__ list,
                                                         const int* __restrict__ cnt,
                                                         ushort_t* __restrict__ hid) {
  __shared__ ushort_t As[128 * 64];
  __shared__ ushort_t Bs[128 * 64];
  const int e = blockIdx.z;
  const int c0 = cnt[e * 2 + 0], c1 = cnt[e * 2 + 1];
  const ushort_t* Bw = w1T + (size_t)e * Dd * FF;
  const int tid = threadIdx.x;
  const int l = tid & 63, l15 = l & 15, lg = l >> 4;
  const int w = tid >> 6;
  const int wm = w >> 1, wn = w & 1;
  const int bm = blockIdx.x * 128, bn = blockIdx.y * 128;
  const int srow = w * 32 + (l >> 3);
  const int scc = ((l & 7) ^ (l >> 3)) * 8;

  f32x4 acc[4][4];
#pragma unroll
  for (int i = 0; i < 4; ++i)
#pragma unroll
    for (int j = 0; j < 4; ++j) acc[i][j] = (f32x4){0.f, 0.f, 0.f, 0.f};

  const ushort_t* agp[4];
  const ushort_t* bgp[4];
#pragma unroll
  for (int j = 0; j < 4; ++j) {
    int r = bm + srow + j * 8; if (r > MOE_ROWS - 1) r = MOE_ROWS - 1;
    int tok = list[e * MOE_ROWS + r] & (NTOK - 1);
    int b = tok >> 11, s = tok & (Ss - 1);
    agp[j] = h2 + (size_t)(b * S1 + s + 1) * Dd + scc;
    bgp[j] = Bw + (size_t)(bn + srow + j * 8) * Dd + scc;
  }

  for (int k0 = 0; k0 < Dd; k0 += 64) {
#pragma unroll
    for (int j = 0; j < 4; ++j) {
      glds16(agp[j] + k0, (char*)As + w * 4096 + j * 1024);
      glds16(bgp[j] + k0, (char*)Bs + w * 4096 + j * 1024);
    }
    __syncthreads();
#pragma unroll
    for (int kc = 0; kc < 2; ++kc) {
      bf16x8 af[4], bfr[4];
#pragma unroll
      for (int mi = 0; mi < 4; ++mi) {
        int row = wm * 64 + mi * 16 + l15;
        af[mi] = *(const bf16x8*)((const char*)As +
                   ((row * 128 + (kc * 32 + lg * 8) * 2) ^ ((row & 7) << 4)));
      }
#pragma unroll
      for (int ni = 0; ni < 4; ++ni) {
        int row = wn * 64 + ni * 16 + l15;
        bfr[ni] = *(const bf16x8*)((const char*)Bs +
                   ((row * 128 + (kc * 32 + lg * 8) * 2) ^ ((row & 7) << 4)));
      }
#pragma unroll
      for (int mi = 0; mi < 4; ++mi)
#pragma unroll
        for (int ni = 0; ni < 4; ++ni)
          acc[mi][ni] = __builtin_amdgcn_mfma_f32_16x16x32_bf16(af[mi], bfr[ni], acc[mi][ni], 0, 0, 0);
    }
    __syncthreads();
  }

#pragma unroll
  for (int mi = 0; mi < 4; ++mi)
#pragma unroll
    for (int rr = 0; rr < 4; ++rr) {
      int row = bm + wm * 64 + mi * 16 + lg * 4 + rr;
      bool v2 = (row < MOE_ROWS) && ((row < CAP) ? (row < c0) : ((row - CAP) < c1));
      if (v2) {
#pragma unroll
        for (int ni = 0; ni < 4; ++ni) {
          int col = bn + wn * 64 + ni * 16 + l15;
          hid[((size_t)e * MOE_ROWS + row) * FF + col] =
              f2bf(geluf(acc[mi][ni][rr] + b1all[e * FF + col]));
        }
      }
    }
}

// ---- MoE variant 2: out[tok] += topp * (hid @ w2T[e] + b2[e]) --------------
__global__ __launch_bounds__(256) void moe_mgemm2_kernel(const ushort_t* __restrict__ hid,
                                                         const ushort_t* __restrict__ w2T,
                                                         const float* __restrict__ b2all,
                                                         const int* __restrict__ list,
                                                         const int* __restrict__ cnt,
                                                         const float* __restrict__ topp,
                                                         ushort_t* __restrict__ out) {
  __shared__ ushort_t As[128 * 64];
  __shared__ ushort_t Bs[128 * 64];
  const int e = blockIdx.z;
  const int c0 = cnt[e * 2 + 0], c1 = cnt[e * 2 + 1];
  const ushort_t* Bw = w2T + (size_t)e * FF * Dd;
  const int tid = threadIdx.x;
  const int l = tid & 63, l15 = l & 15, lg = l >> 4;
  const int w = tid >> 6;
  const int wm = w >> 1, wn = w & 1;
  const int bm = blockIdx.x * 128, bn = blockIdx.y * 128;
  const int srow = w * 32 + (l >> 3);
  const int scc = ((l & 7) ^ (l >> 3)) * 8;

  f32x4 acc[4][4];
#pragma unroll
  for (int i = 0; i < 4; ++i)
#pragma unroll
    for (int j = 0; j < 4; ++j) acc[i][j] = (f32x4){0.f, 0.f, 0.f, 0.f};

  const ushort_t* agp[4];
  const ushort_t* bgp[4];
#pragma unroll
  for (int j = 0; j < 4; ++j) {
    int r = bm + srow + j * 8; if (r > MOE_ROWS - 1) r = MOE_ROWS - 1;
    agp[j] = hid + ((size_t)e * MOE_ROWS + r) * FF + scc;
    bgp[j] = Bw + (size_t)(bn + srow + j * 8) * FF + scc;
  }

  for (int k0 = 0; k0 < FF; k0 += 64) {
#pragma unroll
    for (int j = 0; j < 4; ++j) {
      glds16(agp[j] + k0, (char*)As + w * 4096 + j * 1024);
      glds16(bgp[j] + k0, (char*)Bs + w * 4096 + j * 1024);
    }
    __syncthreads();
#pragma unroll
    for (int kc = 0; kc < 2; ++kc) {
      bf16x8 af[4], bfr[4];
#pragma unroll
      for (int mi = 0; mi < 4; ++mi) {
        int row = wm * 64 + mi * 16 + l15;
        af[mi] = *(const bf16x8*)((const char*)As +
                   ((row * 128 + (kc * 32 + lg * 8) * 2) ^ ((row & 7) << 4)));
      }
#pragma unroll
      for (int ni = 0; ni < 4; ++ni) {
        int row = wn * 64 + ni * 16 + l15;
        bfr[ni] = *(const bf16x8*)((const char*)Bs +
                   ((row * 128 + (kc * 32 + lg * 8) * 2) ^ ((row & 7) << 4)));
      }
#pragma unroll
      for (int mi = 0; mi < 4; ++mi)
#pragma unroll
        for (int ni = 0; ni < 4; ++ni)
          acc[mi][ni] = __builtin_amdgcn_mfma_f32_16x16x32_bf16(af[mi], bfr[ni], acc[mi][ni], 0, 0, 0);
    }
    __syncthreads();
  }

#pragma unroll
  for (int mi = 0; mi < 4; ++mi)
#pragma unroll
    for (int rr = 0; rr < 4; ++rr) {
      int row = bm + wm * 64 + mi * 16 + lg * 4 + rr;
      bool v2 = (row < MOE_ROWS) && ((row < CAP) ? (row < c0) : ((row - CAP) < c1));
      if (v2) {
        int tok = list[e * MOE_ROWS + row];
        int b = tok >> 11, s = tok & (Ss - 1);
        float tp = topp[tok];
#pragma unroll
        for (int ni = 0; ni < 4; ++ni) {
          int col = bn + wn * 64 + ni * 16 + l15;
          size_t oidx = (size_t)(b * S1 + s + 1) * Dd + col;
          out[oidx] = f2bf(bf2f(out[oidx]) + tp * (acc[mi][ni][rr] + b2all[e * Dd + col]));
        }
      }
    }
}

// ---------------- cls rows fill (rows 0 and S1) -----------------------------
__global__ __launch_bounds__(256) void cls_fill_kernel(const float* __restrict__ cls,
                                                       ushort_t* __restrict__ h) {
  int i = threadIdx.x;
  uint_t pk = (uint_t)f2bf(cls[i * 2]) | ((uint_t)f2bf(cls[i * 2 + 1]) << 16);
  *(uint_t*)(h + i * 2) = pk;
  *(uint_t*)(h + (size_t)S1 * Dd + i * 2) = pk;
}

// ---------------- wave-per-row LayerNorm (bf16 in/out, fp32 stats) ----------
template <int EPL>
__global__ __launch_bounds__(256) void ln_wave_kernel(const ushort_t* __restrict__ in,
                                                      const ushort_t* __restrict__ addv,
                                                      const float* __restrict__ g,
                                                      const float* __restrict__ bvec,
                                                      ushort_t* __restrict__ out,
                                                      ushort_t* __restrict__ out2,
                                                      int nrows) {
  constexpr int N = 64 * EPL;
  const int row = blockIdx.x * 4 + (threadIdx.x >> 6);
  const int lane = threadIdx.x & 63;
  if (row >= nrows) return;
  const size_t base = (size_t)row * N + lane * EPL;
  float xf[EPL];
  float s1 = 0.f, s2 = 0.f;
#pragma unroll
  for (int c = 0; c < EPL / 8; ++c) {
    bf16x8 x8 = *(const bf16x8*)(in + base + c * 8);
#pragma unroll
    for (int j = 0; j < 8; ++j) {
      float v = bf2f((ushort_t)x8[j]);
      xf[c * 8 + j] = v;
      s1 += v; s2 += v * v;
    }
  }
  s1 = wsum(s1); s2 = wsum(s2);
  float mean = s1 * (1.0f / N);
  float var = s2 * (1.0f / N) - mean * mean;
  float rstd = rsqrtf(var + 1e-5f);
#pragma unroll
  for (int c = 0; c < EPL / 8; ++c) {
    bf16x8 a8;
    if (addv) a8 = *(const bf16x8*)(addv + base + c * 8);
    bf16x8 o8;
#pragma unroll
    for (int j = 0; j < 8; ++j) {
      int col = lane * EPL + c * 8 + j;
      float v = (xf[c * 8 + j] - mean) * rstd * g[col] + bvec[col];
      if (addv) v += bf2f((ushort_t)a8[j]);
      o8[j] = (short)f2bf(v);
    }
    *(bf16x8*)(out + base + c * 8) = o8;
    if (out2) *(bf16x8*)(out2 + base + c * 8) = o8;
  }
}

// ---------------- fused double-LN: out = LN2(LN1(in)+addv) ------------------
__global__ __launch_bounds__(256) void ln2_wave_kernel(const ushort_t* __restrict__ in,
                                                       const ushort_t* __restrict__ addv,
                                                       const float* __restrict__ g1,
                                                       const float* __restrict__ b1,
                                                       const float* __restrict__ g2,
                                                       const float* __restrict__ b2,
                                                       ushort_t* __restrict__ out,
                                                       ushort_t* __restrict__ out2,
                                                       int nrows) {
  constexpr int N = 512;
  const int row = blockIdx.x * 4 + (threadIdx.x >> 6);
  const int lane = threadIdx.x & 63;
  if (row >= nrows) return;
  const size_t base = (size_t)row * N + lane * 8;
  bf16x8 x8 = *(const bf16x8*)(in + base);
  bf16x8 a8 = *(const bf16x8*)(addv + base);
  float xf[8];
  float s1 = 0.f, s2 = 0.f;
#pragma unroll
  for (int j = 0; j < 8; ++j) {
    float v = bf2f((ushort_t)x8[j]);
    xf[j] = v; s1 += v; s2 += v * v;
  }
  s1 = wsum(s1); s2 = wsum(s2);
  float mean = s1 * (1.0f / N);
  float rstd = rsqrtf(s2 * (1.0f / N) - mean * mean + 1e-5f);
  float vf[8];
  float t1 = 0.f, t2 = 0.f;
#pragma unroll
  for (int j = 0; j < 8; ++j) {
    int col = lane * 8 + j;
    float v = (xf[j] - mean) * rstd * g1[col] + b1[col] + bf2f((ushort_t)a8[j]);
    vf[j] = v; t1 += v; t2 += v * v;
  }
  t1 = wsum(t1); t2 = wsum(t2);
  float mean2 = t1 * (1.0f / N);
  float rstd2 = rsqrtf(t2 * (1.0f / N) - mean2 * mean2 + 1e-5f);
  bf16x8 o8;
#pragma unroll
  for (int j = 0; j < 8; ++j) {
    int col = lane * 8 + j;
    o8[j] = (short)f2bf((vf[j] - mean2) * rstd2 * g2[col] + b2[col]);
  }
  *(bf16x8*)(out + base) = o8;
  if (out2) *(bf16x8*)(out2 + base) = o8;
}

// ---------------- MFMA bf16 flash attention, swapped-QK ---------------------
__global__ __launch_bounds__(256) void attn_mfma_kernel(const ushort_t* __restrict__ qkv,
                                                        ushort_t* __restrict__ o) {
  __shared__ ushort_t Ksh[64 * 64];   // [k][d], XOR-swizzled by (k&7)<<4
  __shared__ ushort_t Vt[64 * 64];    // [d][k], XOR-swizzled by (d&7)<<4
  const int tid = threadIdx.x;
  const int w = tid >> 6, l = tid & 63;
  const int l15 = l & 15, lg = l >> 4;
  const int hh = blockIdx.y, b = blockIdx.z;
  const int qblk = blockIdx.x * 64;
  const size_t rbase = (size_t)b * S1 * 1536;
  const float CEXP = 0.125f * 1.4426950408889634f;

  bf16x8 aq[2];
  {
    int qr = qblk + w * 16 + l15;
    const ushort_t* qp = qkv + rbase + (size_t)qr * 1536 + hh * 64;
#pragma unroll
    for (int dc = 0; dc < 2; ++dc)
      aq[dc] = (qr < S1) ? *(const bf16x8*)(qp + dc * 32 + lg * 8)
                         : (bf16x8){0, 0, 0, 0, 0, 0, 0, 0};
  }

  f32x4 ovac[4];
#pragma unroll
  for (int dt = 0; dt < 4; ++dt) ovac[dt] = (f32x4){0.f, 0.f, 0.f, 0.f};
  float m_r = -1e30f, l_r = 0.f;

  const int sk_r = tid >> 3, sk_c = tid & 7;
  const int sv_k0 = (tid & 31) * 2, sv_d0 = (tid >> 5) * 8;

  for (int c = 0; c < 33; ++c) {
    // ---- stage K ----
#pragma unroll
    for (int pass = 0; pass < 2; ++pass) {
      int r = sk_r + pass * 32;
      int key = c * 64 + r;
      bf16x8 v;
      if (key < S1)
        v = *(const bf16x8*)(qkv + rbase + (size_t)key * 1536 + 512 + hh * 64 + sk_c * 8);
      else
        v = (bf16x8){0, 0, 0, 0, 0, 0, 0, 0};
      *(bf16x8*)((char*)Ksh + (((r * 64 + sk_c * 8) * 2) ^ ((r & 7) << 4))) = v;
    }
    // ---- stage V transposed (pack key pairs) ----
    {
      int key0 = c * 64 + sv_k0;
      const ushort_t* vp = qkv + rbase + (size_t)key0 * 1536 + 1024 + hh * 64 + sv_d0;
      bf16x8 va, vb;
      if (key0 < S1) va = *(const bf16x8*)(vp);
      else va = (bf16x8){0, 0, 0, 0, 0, 0, 0, 0};
      if (key0 + 1 < S1) vb = *(const bf16x8*)(vp + 1536);
      else vb = (bf16x8){0, 0, 0, 0, 0, 0, 0, 0};
#pragma unroll
      for (int i = 0; i < 8; ++i) {
        uint_t pk = (uint_t)(ushort_t)va[i] | ((uint_t)(ushort_t)vb[i] << 16);
        int d = sv_d0 + i;
        *(uint_t*)((char*)Vt + (((d * 64 + sv_k0) * 2) ^ ((d & 7) << 4))) = pk;
      }
    }
    __syncthreads();

    // ---- S^T = K·Q^T ----
    f32x4 s[4];
    __builtin_amdgcn_s_setprio(1);
#pragma unroll
    for (int kt = 0; kt < 4; ++kt) {
      f32x4 acc = (f32x4){0.f, 0.f, 0.f, 0.f};
      const int krow = kt * 16 + l15;
      const int rswz = (krow & 7) << 4;
#pragma unroll
      for (int dc = 0; dc < 2; ++dc) {
        bf16x8 kb = *(const bf16x8*)((const char*)Ksh + (((krow * 64 + dc * 32 + lg * 8) * 2) ^ rswz));
        acc = __builtin_amdgcn_mfma_f32_16x16x32_bf16(kb, aq[dc], acc, 0, 0, 0);
      }
      s[kt] = acc;
    }
    __builtin_amdgcn_s_setprio(0);
    if (c == 32) {
#pragma unroll
      for (int kt = 0; kt < 4; ++kt)
#pragma unroll
        for (int r = 0; r < 4; ++r)
          if (2048 + kt * 16 + lg * 4 + r >= S1) s[kt][r] = -1e30f;
    }

    // ---- online softmax (lane-local row) ----
    f32x4 m4 = (f32x4){fmaxf(s[0][0], s[1][0]), fmaxf(s[0][1], s[1][1]),
                       fmaxf(s[0][2], s[1][2]), fmaxf(s[0][3], s[1][3])};
#pragma unroll
    for (int r = 0; r < 4; ++r) m4[r] = fmaxf(m4[r], fmaxf(s[2][r], s[3][r]));
    float mx = fmaxf(fmaxf(m4[0], m4[1]), fmaxf(m4[2], m4[3]));
    mx = fmaxf(mx, __shfl_xor(mx, 16));
    mx = fmaxf(mx, __shfl_xor(mx, 32));
    float mn = fmaxf(m_r, mx);
    float fac = __builtin_amdgcn_exp2f((m_r - mn) * CEXP);
    m_r = mn;
    float mc = mn * CEXP;
    float p[4][4];
    float rs = 0.f;
#pragma unroll
    for (int kt = 0; kt < 4; ++kt)
#pragma unroll
      for (int r = 0; r < 4; ++r) {
        float pv = __builtin_amdgcn_exp2f(s[kt][r] * CEXP - mc);
        p[kt][r] = pv;
        rs += pv;
      }
    rs += __shfl_xor(rs, 16);
    rs += __shfl_xor(rs, 32);
    l_r = l_r * fac + rs;

    // ---- pack P to bf16 pairs ----
    uint_t pk[4][2];
#pragma unroll
    for (int kt = 0; kt < 4; ++kt) {
      pk[kt][0] = (uint_t)f2bf(p[kt][0]) | ((uint_t)f2bf(p[kt][1]) << 16);
      pk[kt][1] = (uint_t)f2bf(p[kt][2]) | ((uint_t)f2bf(p[kt][3]) << 16);
    }

    // ---- rescale O ----
    float facq[4];
#pragma unroll
    for (int r = 0; r < 4; ++r) facq[r] = __shfl(fac, lg * 4 + r);
#pragma unroll
    for (int dt = 0; dt < 4; ++dt)
#pragma unroll
      for (int r = 0; r < 4; ++r) ovac[dt][r] *= facq[r];

    // ---- in-register transpose: P -> PV A-frags ----
    bf16x8 pa[2];
#pragma unroll
    for (int kh = 0; kh < 2; ++kh) {
      union { uint_t u[4]; bf16x8 v; } cu;
#pragma unroll
      for (int wd = 0; wd < 4; ++wd) {
        int src = (((2 * lg + (wd >> 1)) & 3) << 4) + l15;
        uint_t c0 = (uint_t)__shfl((int)pk[kh * 2 + 0][wd & 1], src);
        uint_t c1 = (uint_t)__shfl((int)pk[kh * 2 + 1][wd & 1], src);
        cu.u[wd] = (lg & 2) ? c1 : c0;
      }
      pa[kh] = cu.v;
    }

    // ---- O += P @ V ----
    __builtin_amdgcn_s_setprio(1);
#pragma unroll
    for (int kh = 0; kh < 2; ++kh)
#pragma unroll
      for (int dt = 0; dt < 4; ++dt) {
        const int vrow = dt * 16 + l15;
        bf16x8 vb = *(const bf16x8*)((const char*)Vt +
                      (((vrow * 64 + kh * 32 + lg * 8) * 2) ^ ((vrow & 7) << 4)));
        ovac[dt] = __builtin_amdgcn_mfma_f32_16x16x32_bf16(pa[kh], vb, ovac[dt], 0, 0, 0);
      }
    __builtin_amdgcn_s_setprio(0);
    __syncthreads();
  }

  float invq[4];
#pragma unroll
  for (int r = 0; r < 4; ++r) invq[r] = 1.0f / __shfl(l_r, lg * 4 + r);
#pragma unroll
  for (int r = 0; r < 4; ++r) {
    int qq = qblk + w * 16 + lg * 4 + r;
    if (qq < S1) {
      ushort_t* orow = o + (size_t)(b * S1 + qq) * Dd + hh * 64;
#pragma unroll
      for (int dt = 0; dt < 4; ++dt) orow[dt * 16 + l15] = f2bf(ovac[dt][r] * invq[r]);
    }
  }
}

// ---------------- gate softmax + top1 routing info (bf16 h) -----------------
__global__ __launch_bounds__(256) void gate_kernel(const ushort_t* __restrict__ h2,
                                                   const float* __restrict__ gw,
                                                   float* __restrict__ gate_out,
                                                   float* __restrict__ topp,
                                                   int* __restrict__ idx) {
  int t = blockIdx.x * 4 + (threadIdx.x >> 6);
  int lane = threadIdx.x & 63;
  if (t >= NTOK) return;
  int b = t >> 11, s = t & (Ss - 1);
  const ushort_t* hr = h2 + (size_t)(b * S1 + s + 1) * Dd;
  bf16x8 h8 = *(const bf16x8*)(hr + lane * 8);
  float acc[6] = {};
#pragma unroll
  for (int j = 0; j < 8; ++j) {
    int d = lane * 8 + j;
    float xv = bf2f((ushort_t)h8[j]);
    const float* g = gw + (size_t)d * Ee;
#pragma unroll
    for (int e = 0; e < 6; ++e) acc[e] += xv * g[e];
  }
#pragma unroll
  for (int e = 0; e < 6; ++e) acc[e] = wsum(acc[e]);
  if (lane == 0) {
    float mx = acc[0];
#pragma unroll
    for (int e = 1; e < 6; ++e) mx = fmaxf(mx, acc[e]);
    float ex[6], sum = 0.f;
#pragma unroll
    for (int e = 0; e < 6; ++e) { ex[e] = __expf(acc[e] - mx); sum += ex[e]; }
    float invs = 1.0f / sum;
    int best = 0; float bp = ex[0];
#pragma unroll
    for (int e = 1; e < 6; ++e) { if (ex[e] > bp) { bp = ex[e]; best = e; } }
#pragma unroll
    for (int e = 0; e < 6; ++e) gate_out[(size_t)t * Ee + e] = ex[e] * invs;
    topp[t] = bp * invs;
    idx[t] = best;
  }
}

// ---------------- capacity-limited top-1 router (parallel scan) -------------
__global__ __launch_bounds__(256) void route_kernel(const int* __restrict__ idx,
                                                    int* __restrict__ list,
                                                    int* __restrict__ cnt) {
  __shared__ int cnts[256];
  __shared__ int tot;
  const int e = blockIdx.x, b = blockIdx.y;
  const int tid = threadIdx.x;
  const int s0 = tid * 8;
  int loc[8];
  int c = 0;
#pragma unroll
  for (int j = 0; j < 8; ++j) {
    int t = b * Ss + s0 + j;
    if (idx[t] == e) loc[c++] = t;
  }
  cnts[tid] = c;
  __syncthreads();
  if (tid == 0) {
    int run = 0;
    for (int i = 0; i < 256; ++i) { int v = cnts[i]; cnts[i] = run; run += v; }
    tot = run;
  }
  __syncthreads();
  int base = cnts[tid];
  for (int j = 0; j < c; ++j) {
    int pos = base + j;
    if (pos < CAP) list[e * MOE_ROWS + b * CAP + pos] = loc[j];
  }
  if (tid == 0) cnt[e * Bb + b] = (tot < CAP) ? tot : CAP;
}

// ---------------- cls-token sub-LN FFN, split-K parallel --------------------
// ffn1: grid (FF/32, Bb), block 256 = 8 k-parts x 32 cols.
// chid[b][col] = gelu(h_cls[b]·w1[:,col] + b1[col])
__global__ __launch_bounds__(256) void cls_ffn1_kernel(const ushort_t* __restrict__ h2,
                                                       const float* __restrict__ w1,
                                                       const float* __restrict__ b1,
                                                       float* __restrict__ chid) {
  __shared__ float hrow[Dd];
  __shared__ float red[8][32];
  const int b = blockIdx.y, tid = threadIdx.x;
  const int cl = tid & 31, kp = tid >> 5;
  const int col = blockIdx.x * 32 + cl;
  const ushort_t* hr = h2 + (size_t)(b * S1) * Dd;
  hrow[tid] = bf2f(hr[tid]);
  hrow[tid + 256] = bf2f(hr[tid + 256]);
  __syncthreads();
  float acc = 0.f;
#pragma unroll 8
  for (int j = 0; j < 64; ++j) {
    int d = kp * 64 + j;
    acc += hrow[d] * w1[(size_t)d * FF + col];
  }
  red[kp][cl] = acc;
  __syncthreads();
  if (kp == 0) {
    float s = b1[col];
#pragma unroll
    for (int i = 0; i < 8; ++i) s += red[i][cl];
    chid[b * FF + col] = geluf(s);
  }
}

// LN of chid rows (2 x 2048) -> chln
__global__ __launch_bounds__(256) void cls_ln_kernel(const float* __restrict__ chid,
                                                     const float* __restrict__ lg,
                                                     const float* __restrict__ lb,
                                                     float* __restrict__ chln) {
  __shared__ float red[8];
  const int b = blockIdx.x, tid = threadIdx.x;
  const float* hr = chid + b * FF;
  float hv[8];
  float s1 = 0.f, s2 = 0.f;
#pragma unroll
  for (int j = 0; j < 8; ++j) {
    hv[j] = hr[tid + j * 256];
    s1 += hv[j]; s2 += hv[j] * hv[j];
  }
  s1 = bsum(s1, red);
  s2 = bsum(s2, red);
  float mean = s1 * (1.0f / FF);
  float rstd = rsqrtf(s2 * (1.0f / FF) - mean * mean + 1e-5f);
#pragma unroll
  for (int j = 0; j < 8; ++j) {
    int k = tid + j * 256;
    chln[b * FF + k] = (hv[j] - mean) * rstd * lg[k] + lb[k];
  }
}

// ffn2: grid (Dd/32, Bb), block 256 = 8 k-parts x 32 cols.
// outbuf[b*S1][col] += chln[b]·w2[:,col] + b2[col]   (bf16 RMW, cls row only)
__global__ __launch_bounds__(256) void cls_ffn2_kernel(const float* __restrict__ chln,
                                                       const float* __restrict__ w2,
                                                       const float* __restrict__ b2,
                                                       ushort_t* __restrict__ outbuf) {
  __shared__ float red[8][32];
  const int b = blockIdx.y, tid = threadIdx.x;
  const int cl = tid & 31, kp = tid >> 5;
  const int col = blockIdx.x * 32 + cl;
  const float* hr = chln + b * FF;
  float acc = 0.f;
#pragma unroll 8
  for (int j = 0; j < 256; ++j) {
    int k = kp * 256 + j;
    acc += hr[k] * w2[(size_t)k * Dd + col];
  }
  red[kp][cl] = acc;
  __syncthreads();
  if (kp == 0) {
    float s = b2[col];
#pragma unroll
    for (int i = 0; i < 8; ++i) s += red[i][cl];
    size_t oidx = (size_t)(b * S1) * Dd + col;
    outbuf[oidx] = f2bf(bf2f(outbuf[oidx]) + s);
  }
}

// ---------------- loss ------------------------------------------------------
__global__ __launch_bounds__(256) void loss_part_kernel(const float* __restrict__ gate,
                                                        const int* __restrict__ lbl,
                                                        float* __restrict__ part) {
  __shared__ float red[8];
  int t = blockIdx.x * 256 + threadIdx.x;
  float v = 0.f;
  if (t < NTOK) {
    const float* p = gate + (size_t)t * Ee;
    float sum = p[0] + p[1] + p[2] + p[3];
    float pl = p[lbl[t]];
    v = -logf(pl / sum + 1e-9f);
  }
  v = bsum(v, red);
  if (threadIdx.x == 0) part[blockIdx.x] = v;
}

__global__ void loss_final_kernel(const float* __restrict__ part, float* __restrict__ out) {
  if (threadIdx.x == 0) {
    float s = 0.f;
    for (int i = 0; i < 16; ++i) s += part[i];
    out[NTOK * Ee + Bb * NCc] = s / (float)NTOK;
  }
}

// ---------------- final LN + logits ----------------------------------------
__global__ __launch_bounds__(256) void final_head_kernel(const ushort_t* __restrict__ h,
                                                         const float* __restrict__ g,
                                                         const float* __restrict__ bvec,
                                                         const float* __restrict__ w,
                                                         const float* __restrict__ fb,
                                                         float* __restrict__ out) {
  __shared__ float red[8];
  int b = blockIdx.x, tid = threadIdx.x;
  const ushort_t* hr = h + (size_t)(b * S1) * Dd;
  float x0 = bf2f(hr[tid]), x1 = bf2f(hr[tid + 256]);
  float s1 = bsum(x0 + x1, red);
  float s2 = bsum(x0 * x0 + x1 * x1, red);
  float mean = s1 * (1.0f / Dd);
  float var = s2 * (1.0f / Dd) - mean * mean;
  float rstd = rsqrtf(var + 1e-5f);
  float p0 = (x0 - mean) * rstd * g[tid] + bvec[tid];
  float p1 = (x1 - mean) * rstd * g[tid + 256] + bvec[tid + 256];
  float l0 = p0 * w[tid * 2 + 0] + p1 * w[(tid + 256) * 2 + 0];
  float l1 = p0 * w[tid * 2 + 1] + p1 * w[(tid + 256) * 2 + 1];
  l0 = bsum(l0, red);
  l1 = bsum(l1, red);
  if (tid == 0) {
    out[NTOK * Ee + b * NCc + 0] = l0 + fb[0];
    out[NTOK * Ee + b * NCc + 1] = l1 + fb[1];
  }
}

// ============================================================================
extern "C" void kernel_launch(void* const* d_in, const int* in_sizes, int n_in,
                              void* d_out, int out_size, void* d_ws, size_t ws_size,
                              hipStream_t stream) {
  (void)in_sizes; (void)n_in; (void)out_size; (void)ws_size;
  const float* x       = (const float*)d_in[0];
  const float* protos  = (const float*)d_in[1];
  const float* cls_tok = (const float*)d_in[2];
  const float* fc1_w   = (const float*)d_in[3];
  const float* fc1_b   = (const float*)d_in[4];
  const float* a0_in_w = (const float*)d_in[5];
  const float* a0_in_b = (const float*)d_in[6];
  const float* a0_out_w= (const float*)d_in[7];
  const float* a0_out_b= (const float*)d_in[8];
  const float* n1g0    = (const float*)d_in[9];
  const float* n1b0    = (const float*)d_in[10];
  const float* n2g0    = (const float*)d_in[11];
  const float* n2b0    = (const float*)d_in[12];
  const float* a1_in_w = (const float*)d_in[13];
  const float* a1_in_b = (const float*)d_in[14];
  const float* a1_out_w= (const float*)d_in[15];
  const float* a1_out_b= (const float*)d_in[16];
  const float* n1g1    = (const float*)d_in[17];
  const float* n1b1    = (const float*)d_in[18];
  const float* n2g1    = (const float*)d_in[19];
  const float* n2b1    = (const float*)d_in[20];
  const float* cw1     = (const float*)d_in[21];
  const float* cb1     = (const float*)d_in[22];
  const float* clg     = (const float*)d_in[23];
  const float* clb     = (const float*)d_in[24];
  const float* cw2     = (const float*)d_in[25];
  const float* cb2     = (const float*)d_in[26];
  const float* gate_w  = (const float*)d_in[27];
  const float* ew1     = (const float*)d_in[28];
  const float* eb1     = (const float*)d_in[29];
  const float* ew2     = (const float*)d_in[30];
  const float* eb2     = (const float*)d_in[31];
  const float* fw1     = (const float*)d_in[32];
  const float* fb1     = (const float*)d_in[33];
  const float* flg     = (const float*)d_in[34];
  const float* flb     = (const float*)d_in[35];
  const float* fw2     = (const float*)d_in[36];
  const float* fb2     = (const float*)d_in[37];
  const float* ng      = (const float*)d_in[38];
  const float* nb      = (const float*)d_in[39];
  const float* fc2_w   = (const float*)d_in[40];
  const float* fc2_b   = (const float*)d_in[41];
  float* out = (float*)d_out;

  char* base = (char*)d_ws;
  size_t o = 0;
  auto alloc = [&](size_t bytes) -> void* {
    void* p = base + o;
    o += (bytes + 255) & ~(size_t)255;
    return p;
  };
  ushort_t* UB0  = (ushort_t*)alloc((size_t)RR * Dd * 2);
  ushort_t* UB1  = (ushort_t*)alloc((size_t)RR * Dd * 2);
  ushort_t* UB2  = (ushort_t*)alloc((size_t)RR * Dd * 2);
  ushort_t* BIGU = (ushort_t*)alloc((size_t)RR * FF * 2);
  ushort_t* XB   = (ushort_t*)alloc((size_t)NTOK * DIN * 2);
  ushort_t* WQ0  = (ushort_t*)alloc((size_t)3 * Dd * Dd * 2);
  ushort_t* WO0  = (ushort_t*)alloc((size_t)Dd * Dd * 2);
  ushort_t* WQ1  = (ushort_t*)alloc((size_t)3 * Dd * Dd * 2);
  ushort_t* WO1  = (ushort_t*)alloc((size_t)Dd * Dd * 2);
  ushort_t* WF1T = (ushort_t*)alloc((size_t)Dd * DIN * 2);
  ushort_t* WE1T = (ushort_t*)alloc((size_t)Ee * FF * Dd * 2);
  ushort_t* WE2T = (ushort_t*)alloc((size_t)Ee * Dd * FF * 2);
  ushort_t* WFW1T= (ushort_t*)alloc((size_t)FF * Dd * 2);
  ushort_t* WFW2T= (ushort_t*)alloc((size_t)Dd * FF * 2);
  float* TOPP = (float*)alloc(NTOK * 4);
  float* PART = (float*)alloc(64 * 4);
  float* CHID = (float*)alloc(Bb * FF * 4);
  float* CHLN = (float*)alloc(Bb * FF * 4);
  int* LBL  = (int*)alloc(NTOK * 4);
  int* IDX  = (int*)alloc(NTOK * 4);
  int* LIST = (int*)alloc(Ee * MOE_ROWS * 4);
  int* CNT  = (int*)alloc(Ee * Bb * 4);

  const int ln_grid = (RR + 3) / 4;

  // ---- one-shot conversions (bf16, unified NxK) ----
  cast_kernel<<<(NTOK * DIN / 8 + 255) / 256, 256, 0, stream>>>(x, XB, NTOK * DIN / 8);
  cast_kernel<<<(3 * Dd * Dd / 8 + 255) / 256, 256, 0, stream>>>(a0_in_w, WQ0, 3 * Dd * Dd / 8);
  cast_kernel<<<(Dd * Dd / 8 + 255) / 256, 256, 0, stream>>>(a0_out_w, WO0, Dd * Dd / 8);
  cast_kernel<<<(3 * Dd * Dd / 8 + 255) / 256, 256, 0, stream>>>(a1_in_w, WQ1, 3 * Dd * Dd / 8);
  cast_kernel<<<(Dd * Dd / 8 + 255) / 256, 256, 0, stream>>>(a1_out_w, WO1, Dd * Dd / 8);
  tpose_cast_kernel<<<dim3(DIN / 64, Dd / 64, 1), 256, 0, stream>>>(fc1_w, WF1T, DIN, Dd);
  tpose_cast_kernel<<<dim3(Dd / 64, FF / 64, Ee), 256, 0, stream>>>(ew1, WE1T, Dd, FF);
  tpose_cast_kernel<<<dim3(FF / 64, Dd / 64, Ee), 256, 0, stream>>>(ew2, WE2T, FF, Dd);
  tpose_cast_kernel<<<dim3(Dd / 64, FF / 64, 1), 256, 0, stream>>>(fw1, WFW1T, Dd, FF);
  tpose_cast_kernel<<<dim3(FF / 64, Dd / 64, 1), 256, 0, stream>>>(fw2, WFW2T, FF, Dd);

  // 1. labels
  labels_kernel<<<NTOK / 4, 256, 0, stream>>>(x, protos, LBL);
  // 2. fc1 writes straight into shifted h layout (UB0); cls rows filled apart
  mgemm_kernel<false, true><<<dim3(32, 4), 256, 0, stream>>>(
      XB, DIN, WF1T, DIN, fc1_b, nullptr, UB0, Dd, NTOK, Dd, DIN);
  cls_fill_kernel<<<1, 256, 0, stream>>>(cls_tok, UB0);

  // ---- layer 0 attention ----
  mgemm_kernel<false, false><<<dim3(33, 12), 256, 0, stream>>>(
      UB0, Dd, WQ0, Dd, a0_in_b, nullptr, BIGU, 3 * Dd, RR, 3 * Dd, Dd);
  attn_mfma_kernel<<<dim3(33, Hh, Bb), 256, 0, stream>>>(BIGU, UB1);
  mgemm_kernel<false, false><<<dim3(33, 4), 256, 0, stream>>>(
      UB1, Dd, WO0, Dd, a0_out_b, nullptr, UB2, Dd, RR, Dd, Dd);
  // h2 = LN2(LN1(UB0)+UB2) -> UB0 (+UB2 as h_res), fused
  ln2_wave_kernel<<<ln_grid, 256, 0, stream>>>(UB0, UB2, n1g0, n1b0, n2g0, n2b0, UB0, UB2, RR);

  // ---- cls ffn (split-K), gate, route, moe ----
  cls_ffn1_kernel<<<dim3(FF / 32, Bb), 256, 0, stream>>>(UB0, cw1, cb1, CHID);
  cls_ln_kernel<<<Bb, 256, 0, stream>>>(CHID, clg, clb, CHLN);
  cls_ffn2_kernel<<<dim3(Dd / 32, Bb), 256, 0, stream>>>(CHLN, cw2, cb2, UB2);
  gate_kernel<<<NTOK / 4, 256, 0, stream>>>(UB0, gate_w, out, TOPP, IDX);
  route_kernel<<<dim3(Ee, Bb), 256, 0, stream>>>(IDX, LIST, CNT);
  moe_mgemm1_kernel<<<dim3(6, 16, Ee), 256, 0, stream>>>(UB0, WE1T, eb1, LIST, CNT, BIGU);
  moe_mgemm2_kernel<<<dim3(6, 4, Ee), 256, 0, stream>>>(BIGU, WE2T, eb2, LIST, CNT, TOPP, UB2);
  loss_part_kernel<<<16, 256, 0, stream>>>(out, LBL, PART);
  loss_final_kernel<<<1, 64, 0, stream>>>(PART, out);

  // ---- layer 1 attention ----
  mgemm_kernel<false, false><<<dim3(33, 12), 256, 0, stream>>>(
      UB2, Dd, WQ1, Dd, a1_in_b, nullptr, BIGU, 3 * Dd, RR, 3 * Dd, Dd);
  attn_mfma_kernel<<<dim3(33, Hh, Bb), 256, 0, stream>>>(BIGU, UB1);
  mgemm_kernel<false, false><<<dim3(33, 4), 256, 0, stream>>>(
      UB1, Dd, WO1, Dd, a1_out_b, nullptr, UB0, Dd, RR, Dd, Dd);
  // h = LN2(LN1(UB2)+UB0) -> UB2, fused
  ln2_wave_kernel<<<ln_grid, 256, 0, stream>>>(UB2, UB0, n1g1, n1b1, n2g1, n2b1, UB2, nullptr, RR);

  // ---- layer 1 FFN (sub-LN) with residual ----
  mgemm_kernel<true, false><<<dim3(33, 16), 256, 0, stream>>>(
      UB2, Dd, WFW1T, Dd, fb1, nullptr, BIGU, FF, RR, FF, Dd);
  ln_wave_kernel<32><<<ln_grid, 256, 0, stream>>>(BIGU, nullptr, flg, flb, BIGU, nullptr, RR);
  mgemm_kernel<false, false><<<dim3(33, 4), 256, 0, stream>>>(
      BIGU, FF, WFW2T, FF, fb2, UB2, UB0, Dd, RR, Dd, FF);

  // ---- head ----
  final_head_kernel<<<Bb, 256, 0, stream>>>(UB0, ng, nb, fc2_w, fc2_b, out);
}